// Round 6
// baseline (597.213 us; speedup 1.0000x reference)
//
#include <hip/hip_runtime.h>
#include <cmath>

// Problem constants (fixed by the reference file)
#define B_   8
#define N_   512
#define D_   1024
#define H_   16
#define HD_  64
#define NI_  4
#define BN_  (B_*N_)      // 4096 rows when [B,N,*] is flattened
#define KVLEN (NI_*N_)    // 2048 keys per attention group

typedef __attribute__((ext_vector_type(8)))  short  bf16x8;   // 8 bf16 bit patterns
typedef __attribute__((ext_vector_type(8)))  __bf16 bf16x8_t; // builtin operand type
typedef __attribute__((ext_vector_type(16))) float  f32x16;
typedef __attribute__((ext_vector_type(4)))  short  s16x4;

// round-to-nearest-even bf16 conversion (bit trick)
__device__ __forceinline__ short bf16_rn(float x) {
  unsigned u = __float_as_uint(x);
  unsigned r = (u + 0x7FFFu + ((u >> 16) & 1u)) >> 16;
  return (short)r;
}

// RN hi/lo split: x = hi + lo + eps, |eps| <~ 2^-18 |x|.
__device__ __forceinline__ void split2(float x, short& hi, short& lo) {
  hi = bf16_rn(x);
  float h = __uint_as_float(((unsigned)(unsigned short)hi) << 16);
  float r = x - h;              // exact (Dekker-style split)
  lo = bf16_rn(r);
}

__device__ __forceinline__ f32x16 mfma_bf16(bf16x8 a, bf16x8 b, f32x16 c) {
  return __builtin_amdgcn_mfma_f32_32x32x16_bf16(
      __builtin_bit_cast(bf16x8_t, a), __builtin_bit_cast(bf16x8_t, b), c, 0, 0, 0);
}

#define GLOAD16(gp, lp) __builtin_amdgcn_global_load_lds( \
  (const __attribute__((address_space(1))) unsigned*)(gp), \
  (__attribute__((address_space(3))) unsigned*)(lp), 16, 0, 0)

// =====================================================================
// Weight transpose + hi/lo split: W[K][C] fp32 -> T[C][K] bf16 hi/lo.
// =====================================================================
__global__ __launch_bounds__(256) void wsplitT(const float* __restrict__ W,
                                               short* __restrict__ Thi,
                                               short* __restrict__ Tlo)
{
  __shared__ float tile[64][65];
  const int t  = threadIdx.x;
  const int kb = blockIdx.y * 64;
  const int cb = blockIdx.x * 64;
  const int r0 = t >> 4;
  const int c4 = t & 15;
  #pragma unroll
  for (int i = 0; i < 4; i++) {
    const int r = r0 + i * 16;
    *(float4*)&tile[r][c4 * 4] = *(const float4*)&W[(long)(kb + r) * D_ + cb + c4 * 4];
  }
  __syncthreads();
  #pragma unroll
  for (int i = 0; i < 4; i++) {
    const int c = r0 + i * 16;
    short hi[4], lo[4];
    #pragma unroll
    for (int e = 0; e < 4; e++)
      split2(tile[c4 * 4 + e][c], hi[e], lo[e]);
    *(s16x4*)&Thi[(long)(cb + c) * D_ + kb + c4 * 4] = *(s16x4*)hi;
    *(s16x4*)&Tlo[(long)(cb + c) * D_ + kb + c4 * 4] = *(s16x4*)lo;
  }
}

// Fused 3-weight version for Wq/Wk/Wv -> combined [3072][1024] hi/lo.
__global__ __launch_bounds__(256) void wsplit3(
    const float* __restrict__ W0, const float* __restrict__ W1,
    const float* __restrict__ W2, short* __restrict__ Thi,
    short* __restrict__ Tlo)
{
  __shared__ float tile[64][65];
  const int z = blockIdx.z;
  const float* W = (z == 0) ? W0 : (z == 1) ? W1 : W2;
  const int t  = threadIdx.x;
  const int kb = blockIdx.y * 64;
  const int cb = blockIdx.x * 64;
  const int r0 = t >> 4;
  const int c4 = t & 15;
  #pragma unroll
  for (int i = 0; i < 4; i++) {
    const int r = r0 + i * 16;
    *(float4*)&tile[r][c4 * 4] = *(const float4*)&W[(long)(kb + r) * D_ + cb + c4 * 4];
  }
  __syncthreads();
  #pragma unroll
  for (int i = 0; i < 4; i++) {
    const int c = r0 + i * 16;
    short hi[4], lo[4];
    #pragma unroll
    for (int e = 0; e < 4; e++)
      split2(tile[c4 * 4 + e][c], hi[e], lo[e]);
    const long orow = (long)(z * D_ + cb + c) * D_ + kb + c4 * 4;
    *(s16x4*)&Thi[orow] = *(s16x4*)hi;
    *(s16x4*)&Tlo[orow] = *(s16x4*)lo;
  }
}

// =====================================================================
// Elementwise fp32 -> hi/lo bf16 split (for x).
// =====================================================================
__global__ __launch_bounds__(256) void asplit(const float* __restrict__ in,
                                              short* __restrict__ hi,
                                              short* __restrict__ lo)
{
  const long i4 = ((long)blockIdx.x * 256 + threadIdx.x) * 4;
  float4 v = *(const float4*)&in[i4];
  short h[4], l[4];
  split2(v.x, h[0], l[0]);
  split2(v.y, h[1], l[1]);
  split2(v.z, h[2], l[2]);
  split2(v.w, h[3], l[3]);
  *(s16x4*)&hi[i4] = *(s16x4*)h;
  *(s16x4*)&lo[i4] = *(s16x4*)l;
}

// =====================================================================
// Split-bf16 MFMA GEMM v2 — all operands pre-split bf16, staged with
// global_load_lds (width 16) into linear [k-octet][row][8] chunks,
// double-buffered LDS with counted vmcnt(8) (never drained in-loop).
// 128x128 tile, BK=32, 4 waves; wave w stages operand buffer w
// (0:Ahi 1:Alo 2:Bhi 3:Blo), 8 gloads/wave/K-step.
// 3 MFMAs per pair: Al*Bh + Ah*Bl + Ah*Bh.
// MODE 0: C[bz*sC + row*1024 + col] = A@B + bias(bz)   (QKV fused, z=0..2)
// MODE 1: Chi/Clo bf16 = A@B + bias                    (iq, ik)
// MODE 2: C = gate(row)*(A@B) + bias, gate = 1 + sum8(part_in[row])/512
// MODE 3: part_out[(bz*N_+row)*8 + bx*2 + wc] = per-wave 64-col partial
//         row sum of sigmoid(acc*SCALE/H)              (gate scores)
// =====================================================================
template<int MODE>
__global__ __launch_bounds__(256) void mfgemm2(
    const short* __restrict__ Ahi, const short* __restrict__ Alo,
    const short* __restrict__ Bhi, const short* __restrict__ Blo,
    const float* __restrict__ b0, const float* __restrict__ b1,
    const float* __restrict__ b2,
    float* __restrict__ C, short* __restrict__ Chi, short* __restrict__ Clo,
    int K, long sA, long sB, long sC,
    const float* __restrict__ part_in, float* __restrict__ part_out)
{
  __shared__ short lds[2][4][512 * 8];   // 64 KB: dbuf x 4 operands x 512 chunks x 16B
  const int t = threadIdx.x, w = t >> 6, lane = t & 63;
  const int bx = blockIdx.x, by = blockIdx.y, bz = blockIdx.z;
  const int rowBase = by * 128;
  const int colBase = bx * 128;
  const long aoff = (long)bz * sA + (long)rowBase * K;
  const long boff = (long)bz * sB + (long)colBase * K;
  const short* mySrc = (w == 0) ? Ahi + aoff : (w == 1) ? Alo + aoff
                     : (w == 2) ? Bhi + boff : Blo + boff;

  auto stage = [&](int buf, int k0) {
    #pragma unroll
    for (int i = 0; i < 8; i++) {
      const int q = i * 64 + lane;          // chunk id 0..511 = kq*128 + row
      const int kq = q >> 7, row = q & 127;
      const short* g = mySrc + (long)row * K + k0 + kq * 8;
      GLOAD16(g, &lds[buf][w][i * 512]);
    }
  };

  const int wr = w >> 1, wc = w & 1;
  const int lrow = lane & 31, lk = lane >> 5;

  f32x16 acc[2][2] = {};

  auto compute = [&](int buf) {
    #pragma unroll
    for (int kh = 0; kh < 2; kh++) {
      const int kq = 2 * kh + lk;
      bf16x8 ah[2], al[2], bh[2], bl[2];
      #pragma unroll
      for (int m = 0; m < 2; m++) {
        const int r = wr * 64 + m * 32 + lrow;
        ah[m] = *(const bf16x8*)&lds[buf][0][(kq * 128 + r) * 8];
        al[m] = *(const bf16x8*)&lds[buf][1][(kq * 128 + r) * 8];
      }
      #pragma unroll
      for (int n = 0; n < 2; n++) {
        const int c = wc * 64 + n * 32 + lrow;
        bh[n] = *(const bf16x8*)&lds[buf][2][(kq * 128 + c) * 8];
        bl[n] = *(const bf16x8*)&lds[buf][3][(kq * 128 + c) * 8];
      }
      #pragma unroll
      for (int m = 0; m < 2; m++)
        #pragma unroll
        for (int n = 0; n < 2; n++) {
          acc[m][n] = mfma_bf16(al[m], bh[n], acc[m][n]);
          acc[m][n] = mfma_bf16(ah[m], bl[n], acc[m][n]);
          acc[m][n] = mfma_bf16(ah[m], bh[n], acc[m][n]);
        }
    }
  };

  const int NT = K / 32;
  stage(0, 0);
  for (int tt = 0; tt < NT - 1; ++tt) {
    stage((tt + 1) & 1, (tt + 1) * 32);          // issue next-tile loads
    asm volatile("s_waitcnt vmcnt(8)" ::: "memory");  // old 8 landed; new 8 in flight
    __builtin_amdgcn_s_barrier();
    __builtin_amdgcn_sched_barrier(0);
    compute(tt & 1);
    __builtin_amdgcn_s_barrier();                // all waves done reading this buf
  }
  asm volatile("s_waitcnt vmcnt(0)" ::: "memory");
  __builtin_amdgcn_s_barrier();
  __builtin_amdgcn_sched_barrier(0);
  compute((NT - 1) & 1);

  // ---------------- epilogue ----------------
  if (MODE == 3) {
    const float sc = 0.125f / 16.f;   // SCALE/H
    #pragma unroll
    for (int m = 0; m < 2; m++)
      #pragma unroll
      for (int r = 0; r < 16; r++) {
        const int row = rowBase + wr * 64 + m * 32 + (r & 3) + 8 * (r >> 2) + 4 * lk;
        float v = 1.f / (1.f + __expf(-acc[m][0][r] * sc))
                + 1.f / (1.f + __expf(-acc[m][1][r] * sc));
        v += __shfl_xor(v, 1);  v += __shfl_xor(v, 2);  v += __shfl_xor(v, 4);
        v += __shfl_xor(v, 8);  v += __shfl_xor(v, 16);
        if (lrow == 0)
          part_out[(long)(bz * N_ + row) * 8 + bx * 2 + wc] = v;
      }
    return;
  }

  const float* bias = (bz == 1) ? b1 : (bz == 2) ? b2 : b0;
  float bcol[2];
  #pragma unroll
  for (int n = 0; n < 2; n++)
    bcol[n] = bias[colBase + wc * 64 + n * 32 + lrow];

  float* Cb = C + (long)bz * sC;

  #pragma unroll
  for (int m = 0; m < 2; m++) {
    #pragma unroll
    for (int r = 0; r < 16; r++) {
      const int row = rowBase + wr * 64 + m * 32 + (r & 3) + 8 * (r >> 2) + 4 * lk;
      float g = 1.f;
      if (MODE == 2) {
        const float4 p0 = *(const float4*)&part_in[(long)row * 8];
        const float4 p1 = *(const float4*)&part_in[(long)row * 8 + 4];
        g = 1.f + (p0.x + p0.y + p0.z + p0.w + p1.x + p1.y + p1.z + p1.w)
                  * (1.f / 512.f);
      }
      #pragma unroll
      for (int n = 0; n < 2; n++) {
        const int col = colBase + wc * 64 + n * 32 + lrow;
        const float val = acc[m][n][r] * g + bcol[n];
        if (MODE == 1) {
          short hi, lo;
          split2(val, hi, lo);
          Chi[(long)row * D_ + col] = hi;
          Clo[(long)row * D_ + col] = lo;
        } else {
          Cb[(long)row * D_ + col] = val;
        }
      }
    }
  }
}

// =====================================================================
// MFMA grouped flash attention, bf16 compute, fp32 softmax state.
// grid (N/128, H, B), 256 thr = 4 waves; wave owns 32 q rows.
// Swapped QK^T, static softmax max (|s*SCALE|<=8 from RMS-normed q,k),
// fused QK-RMSNorm, K LDS XOR-swizzle, V^T LDS (stride-40 shorts).
// NEW: T14 prefetch — next tile's K/V loads issue before the MFMA
// section (reg ping-pong, manual 2x unroll); output emitted as split
// bf16 hi/lo (feeds iq/final GEMMs directly).
// =====================================================================
__global__ __launch_bounds__(256) void attn_mfma(
    const float* __restrict__ q, const float* __restrict__ k,
    const float* __restrict__ v, const float* __restrict__ qnw,
    const float* __restrict__ knw, short* __restrict__ ohi,
    short* __restrict__ olo)
{
  const int b  = blockIdx.z, h = blockIdx.y, qb = blockIdx.x;
  const int g  = b >> 2;
  const int t  = threadIdx.x;
  const int w  = t >> 6;
  const int lane = t & 63;
  const int l31 = lane & 31, hi = lane >> 5;

  __shared__ short Ks[32 * 64];   // [kv][hd] bf16, swizzled
  __shared__ short Vs[64 * 40];   // [d][kv] bf16, stride 40 shorts

  // ---- Q: load + RMSNorm + B-operand frags ----
  const int qrow = qb * 128 + w * 32 + l31;
  const float* qp = q + ((long)b * N_ + qrow) * D_ + h * HD_ + hi * 8;
  float qv[4][8];
  float ss = 0.f;
  #pragma unroll
  for (int c = 0; c < 4; c++) {
    *(float4*)&qv[c][0] = *(const float4*)&qp[c * 16];
    *(float4*)&qv[c][4] = *(const float4*)&qp[c * 16 + 4];
    #pragma unroll
    for (int j = 0; j < 8; j++) ss += qv[c][j] * qv[c][j];
  }
  ss += __shfl_xor(ss, 32);
  const float qr = rsqrtf(ss * (1.f / 64.f) + 1e-6f);
  bf16x8 qf[4];
  #pragma unroll
  for (int c = 0; c < 4; c++)
    #pragma unroll
    for (int j = 0; j < 8; j++)
      qf[c][j] = bf16_rn(qv[c][j] * qr * qnw[c * 16 + hi * 8 + j]);

  // staging maps
  const int skv = t >> 3, sg = t & 7;
  const int vkv = t & 31, vg = t >> 5;
  float kw[8];
  #pragma unroll
  for (int j = 0; j < 8; j++) kw[j] = knw[sg * 8 + j];

  f32x16 oacc[2] = {};
  float l = 0.f;

  auto loadKV = [&](int kt, float* kf, float* vf) {
    const int inst = (kt * 32) >> 9;
    const int nn0  = (kt * 32) & (N_ - 1);
    const long rowK = ((long)(g * NI_ + inst) * N_ + nn0 + skv) * D_ + h * HD_ + sg * 8;
    const long rowV = ((long)(g * NI_ + inst) * N_ + nn0 + vkv) * D_ + h * HD_ + vg * 8;
    *(float4*)&kf[0] = *(const float4*)&k[rowK];
    *(float4*)&kf[4] = *(const float4*)&k[rowK + 4];
    *(float4*)&vf[0] = *(const float4*)&v[rowV];
    *(float4*)&vf[4] = *(const float4*)&v[rowV + 4];
  };

  auto tilestep = [&](int kt, float* kf, float* vf, float* kfn, float* vfn) {
    // K-RMS across the 8 lanes sharing row skv
    float ks2 = 0.f;
    #pragma unroll
    for (int j = 0; j < 8; j++) ks2 += kf[j] * kf[j];
    ks2 += __shfl_xor(ks2, 1);
    ks2 += __shfl_xor(ks2, 2);
    ks2 += __shfl_xor(ks2, 4);
    const float kr = rsqrtf(ks2 * (1.f / 64.f) + 1e-6f);

    __syncthreads();   // previous tile fully consumed
    bf16x8 kb_;
    #pragma unroll
    for (int j = 0; j < 8; j++) kb_[j] = bf16_rn(kf[j] * kr * kw[j]);
    *(bf16x8*)&Ks[skv * 64 + ((sg * 8) ^ ((skv & 7) << 3))] = kb_;
    #pragma unroll
    for (int e = 0; e < 8; e++)
      Vs[(vg * 8 + e) * 40 + vkv] = bf16_rn(vf[e]);
    __syncthreads();

    if (kt + 1 < KVLEN / 32) loadKV(kt + 1, kfn, vfn);   // T14: hide under MFMA

    // ---- QK^T ----
    f32x16 sc = {};
    #pragma unroll
    for (int c = 0; c < 4; c++) {
      bf16x8 kfr = *(const bf16x8*)&Ks[l31 * 64 + (((2 * c + hi) * 8) ^ ((l31 & 7) << 3))];
      sc = mfma_bf16(kfr, qf[c], sc);
    }
    // ---- softmax, static max 8 ----
    float p[16];
    #pragma unroll
    for (int r = 0; r < 16; r++) { p[r] = __expf(sc[r] * 0.125f - 8.f); l += p[r]; }
    // ---- PV A-frags via packed bf16 + half swap ----
    unsigned wd[8], sw[8];
    #pragma unroll
    for (int i = 0; i < 8; i++)
      wd[i] = ((unsigned)(unsigned short)bf16_rn(p[2 * i + 1]) << 16)
            | (unsigned short)bf16_rn(p[2 * i]);
    #pragma unroll
    for (int i = 0; i < 8; i++) sw[i] = __shfl_xor(wd[i], 32);
    int4 f0 = { (int)(hi ? sw[2] : wd[0]), (int)(hi ? sw[3] : wd[1]),
                (int)(hi ? wd[2] : sw[0]), (int)(hi ? wd[3] : sw[1]) };
    int4 f1 = { (int)(hi ? sw[6] : wd[4]), (int)(hi ? sw[7] : wd[5]),
                (int)(hi ? wd[6] : sw[4]), (int)(hi ? wd[7] : sw[5]) };
    #pragma unroll
    for (int n = 0; n < 2; n++) {
      bf16x8 v0 = *(const bf16x8*)&Vs[(n * 32 + l31) * 40 + hi * 8];
      bf16x8 v1 = *(const bf16x8*)&Vs[(n * 32 + l31) * 40 + 16 + hi * 8];
      oacc[n] = mfma_bf16(__builtin_bit_cast(bf16x8, f0), v0, oacc[n]);
      oacc[n] = mfma_bf16(__builtin_bit_cast(bf16x8, f1), v1, oacc[n]);
    }
  };

  float ka[8], va[8], kb2[8], vb2[8];
  loadKV(0, ka, va);
  for (int kt = 0; kt < KVLEN / 32; kt += 2) {
    tilestep(kt,     ka,  va,  kb2, vb2);
    tilestep(kt + 1, kb2, vb2, ka,  va);
  }

  // ---- epilogue: divide by l, split to bf16 hi/lo, store ----
  l += __shfl_xor(l, 32);
  const float linv = 1.f / l;
  float lr[16];
  #pragma unroll
  for (int r = 0; r < 16; r++)
    lr[r] = __shfl(linv, (r & 3) + 8 * (r >> 2) + 4 * hi);
  #pragma unroll
  for (int r = 0; r < 16; r++) {
    const int qg = qb * 128 + w * 32 + (r & 3) + 8 * (r >> 2) + 4 * hi;
    const long off = ((long)b * N_ + qg) * D_ + h * HD_ + l31;
    short h0, l0, h1, l1;
    split2(oacc[0][r] * lr[r], h0, l0);
    split2(oacc[1][r] * lr[r], h1, l1);
    ohi[off]      = h0;  olo[off]      = l0;
    ohi[off + 32] = h1;  olo[off + 32] = l1;
  }
}

// =====================================================================
// inst_feat split: mask @ embed -> hi/lo bf16 [B*N][D]
// =====================================================================
__global__ __launch_bounds__(256) void instfeat_split(
    const float* __restrict__ mask, const float* __restrict__ emb,
    short* __restrict__ ofh, short* __restrict__ ofl)
{
  const long idx = (long)blockIdx.x * 256 + threadIdx.x;
  const int  d4  = (int)(idx & (D_ / 4 - 1));
  const long bn  = idx >> 8;
  const float* mk = mask + bn * NI_;
  float4 acc = {0.f, 0.f, 0.f, 0.f};
  #pragma unroll
  for (int i = 0; i < NI_; i++) {
    const float mm = mk[i];
    const float4 e = *(const float4*)&emb[(long)i * D_ + d4 * 4];
    acc.x = fmaf(mm, e.x, acc.x);
    acc.y = fmaf(mm, e.y, acc.y);
    acc.z = fmaf(mm, e.z, acc.z);
    acc.w = fmaf(mm, e.w, acc.w);
  }
  short h[4], l[4];
  split2(acc.x, h[0], l[0]);
  split2(acc.y, h[1], l[1]);
  split2(acc.z, h[2], l[2]);
  split2(acc.w, h[3], l[3]);
  *(s16x4*)&ofh[bn * D_ + d4 * 4] = *(s16x4*)h;
  *(s16x4*)&ofl[bn * D_ + d4 * 4] = *(s16x4*)l;
}

// =====================================================================
extern "C" void kernel_launch(void* const* d_in, const int* in_sizes, int n_in,
                              void* d_out, int out_size, void* d_ws, size_t ws_size,
                              hipStream_t stream)
{
  const float* x    = (const float*)d_in[0];
  const float* mask = (const float*)d_in[1];
  const float* Wq   = (const float*)d_in[2];
  const float* bq   = (const float*)d_in[3];
  const float* Wk   = (const float*)d_in[4];
  const float* bk   = (const float*)d_in[5];
  const float* Wv   = (const float*)d_in[6];
  const float* bv   = (const float*)d_in[7];
  const float* Wo   = (const float*)d_in[8];
  const float* bo   = (const float*)d_in[9];
  const float* Wiq  = (const float*)d_in[10];
  const float* biq  = (const float*)d_in[11];
  const float* Wik  = (const float*)d_in[12];
  const float* bik  = (const float*)d_in[13];
  const float* emb  = (const float*)d_in[14];
  const float* qnw  = (const float*)d_in[15];
  const float* knw  = (const float*)d_in[16];
  float* out = (float*)d_out;

  // Workspace (~96.6 MB):
  // [0,SZ)     qbuf fp32   -> post-attn: iqh/iql bf16
  // [SZ,2SZ)   kbuf fp32   -> post-attn: ifh/ifl bf16
  // [2SZ,3SZ)  vbuf fp32   -> post-attn: ikh/ikl bf16
  // [3SZ,4SZ)  ohi/olo bf16 (attention split output)
  // [4SZ,5SZ)  xhi/xlo bf16
  // then Wbig hi/lo [3072][1024] bf16 (QKV) -> later reused as 1024-row W slot
  // then part [B*N][8] fp32
  float* ws = (float*)d_ws;
  const size_t SZ = (size_t)BN_ * D_;
  float* qbuf = ws;
  float* kbuf = qbuf + SZ;
  float* vbuf = kbuf + SZ;
  short* ohi  = (short*)(vbuf + SZ);
  short* olo  = ohi + SZ;
  short* xhi  = (short*)(ws + 4 * SZ);
  short* xlo  = xhi + SZ;
  short* Wbig_hi = (short*)(ws + 5 * SZ);
  short* Wbig_lo = Wbig_hi + (size_t)3 * D_ * D_;
  float* part = (float*)(Wbig_lo + (size_t)3 * D_ * D_);
  short* iqh = (short*)qbuf;  short* iql = iqh + SZ;
  short* ifh = (short*)kbuf;  short* ifl = ifh + SZ;
  short* ikh = (short*)vbuf;  short* ikl = ikh + SZ;
  short* Wsl_hi = Wbig_hi;    short* Wsl_lo = Wbig_hi + (size_t)D_ * D_;

  const dim3 blk(256);

  // 1) weight prep + x split
  wsplit3<<<dim3(16, 16, 3), blk, 0, stream>>>(Wq, Wk, Wv, Wbig_hi, Wbig_lo);
  asplit<<<(BN_ * D_ / 4) / 256, blk, 0, stream>>>(x, xhi, xlo);

  // 2) fused QKV projection: grid 8x32x3 = 768 blocks (3 blocks/CU)
  mfgemm2<0><<<dim3(8, 32, 3), blk, 0, stream>>>(
      xhi, xlo, Wbig_hi, Wbig_lo, bq, bk, bv,
      qbuf, nullptr, nullptr, D_, 0, (long)D_ * D_, (long)SZ, nullptr, nullptr);

  // 3) attention (fused QK-RMSNorm) -> split bf16 output
  attn_mfma<<<dim3(N_ / 128, H_, B_), blk, 0, stream>>>(
      qbuf, kbuf, vbuf, qnw, knw, ohi, olo);

  // 4) IQ = o@Wiq+biq, split output (overwrites qbuf slot)
  wsplitT<<<dim3(16, 16), blk, 0, stream>>>(Wiq, Wsl_hi, Wsl_lo);
  mfgemm2<1><<<dim3(8, 32, 1), blk, 0, stream>>>(
      ohi, olo, Wsl_hi, Wsl_lo, biq, nullptr, nullptr,
      nullptr, iqh, iql, D_, 0, 0, 0, nullptr, nullptr);

  // 5) inst_feat split (overwrites kbuf slot)
  instfeat_split<<<(BN_ * D_ / 4) / 256, blk, 0, stream>>>(mask, emb, ifh, ifl);

  // 6) IK = inst_feat@Wik+bik, split output (overwrites vbuf slot)
  wsplitT<<<dim3(16, 16), blk, 0, stream>>>(Wik, Wsl_hi, Wsl_lo);
  mfgemm2<1><<<dim3(8, 32, 1), blk, 0, stream>>>(
      ifh, ifl, Wsl_hi, Wsl_lo, bik, nullptr, nullptr,
      nullptr, ikh, ikl, D_, 0, 0, 0, nullptr, nullptr);

  // 7) gate partials: per-batch IQ[b] @ IK[b]^T, sigmoid, per-wave partials
  mfgemm2<3><<<dim3(4, 4, 8), blk, 0, stream>>>(
      iqh, iql, ikh, ikl, nullptr, nullptr, nullptr,
      nullptr, nullptr, nullptr, D_, (long)N_ * D_, (long)N_ * D_, 0,
      nullptr, part);

  // 8) final: gate(row)*(o@Wo) + bo -> d_out
  wsplitT<<<dim3(16, 16), blk, 0, stream>>>(Wo, Wsl_hi, Wsl_lo);
  mfgemm2<2><<<dim3(8, 32, 1), blk, 0, stream>>>(
      ohi, olo, Wsl_hi, Wsl_lo, bo, nullptr, nullptr,
      out, nullptr, nullptr, D_, 0, 0, 0, part, nullptr);
}

// Round 7
// 349.636 us; speedup vs baseline: 1.7081x; 1.7081x over previous
//
#include <hip/hip_runtime.h>
#include <cmath>

// Problem constants (fixed by the reference file)
#define B_   8
#define N_   512
#define D_   1024
#define H_   16
#define HD_  64
#define NI_  4
#define BN_  (B_*N_)      // 4096 rows when [B,N,*] is flattened
#define KVLEN (NI_*N_)    // 2048 keys per attention group

typedef __attribute__((ext_vector_type(8)))  short  bf16x8;   // 8 bf16 bit patterns
typedef __attribute__((ext_vector_type(8)))  __bf16 bf16x8_t; // builtin operand type
typedef __attribute__((ext_vector_type(16))) float  f32x16;
typedef __attribute__((ext_vector_type(4)))  short  s16x4;

// round-to-nearest-even bf16 conversion (bit trick)
__device__ __forceinline__ short bf16_rn(float x) {
  unsigned u = __float_as_uint(x);
  unsigned r = (u + 0x7FFFu + ((u >> 16) & 1u)) >> 16;
  return (short)r;
}

// RN hi/lo split: x = hi + lo + eps, |eps| <~ 2^-18 |x|.
__device__ __forceinline__ void split2(float x, short& hi, short& lo) {
  hi = bf16_rn(x);
  float h = __uint_as_float(((unsigned)(unsigned short)hi) << 16);
  float r = x - h;              // exact (Dekker-style split)
  lo = bf16_rn(r);
}

__device__ __forceinline__ f32x16 mfma_bf16(bf16x8 a, bf16x8 b, f32x16 c) {
  return __builtin_amdgcn_mfma_f32_32x32x16_bf16(
      __builtin_bit_cast(bf16x8_t, a), __builtin_bit_cast(bf16x8_t, b), c, 0, 0, 0);
}

#define GLOAD16(gp, lp) __builtin_amdgcn_global_load_lds( \
  (const __attribute__((address_space(1))) unsigned*)(gp), \
  (__attribute__((address_space(3))) unsigned*)(lp), 16, 0, 0)

// TILED-SPLIT layout for all bf16 GEMM operands (K = 1024 always):
// addr(row,k) = (((row>>7)*128 + (k>>3))*128 + (row&127))*8 + (k&7).
// This makes GEMM staging a LINEAR copy (chunk c = tt*512 + i*64 + lane),
// i.e. consecutive lanes load consecutive 16B -> fully coalesced
// global_load_lds. (Round-6 lesson: the [k-octet][row] chunk map with
// row varying per lane was a 64-way 2KB-strided gather -> 198MB FETCH,
// MfmaUtil 15%, VALUBusy 6%: pure latency stall.)
__device__ __forceinline__ long tiled_off(int row, int k) {
  return ((((long)(row >> 7) * 128 + (k >> 3)) * 128 + (row & 127)) * 8 + (k & 7));
}

// =====================================================================
// Weight transpose + hi/lo split: W[K][C] fp32 -> tiled-split T[C][K].
// =====================================================================
__global__ __launch_bounds__(256) void wsplitT(const float* __restrict__ W,
                                               short* __restrict__ Thi,
                                               short* __restrict__ Tlo)
{
  __shared__ float tile[64][65];
  const int t  = threadIdx.x;
  const int kb = blockIdx.y * 64;
  const int cb = blockIdx.x * 64;
  const int r0 = t >> 4;
  const int c4 = t & 15;
  #pragma unroll
  for (int i = 0; i < 4; i++) {
    const int r = r0 + i * 16;
    *(float4*)&tile[r][c4 * 4] = *(const float4*)&W[(long)(kb + r) * D_ + cb + c4 * 4];
  }
  __syncthreads();
  #pragma unroll
  for (int i = 0; i < 4; i++) {
    const int c = r0 + i * 16;
    short hi[4], lo[4];
    #pragma unroll
    for (int e = 0; e < 4; e++)
      split2(tile[c4 * 4 + e][c], hi[e], lo[e]);
    const long o = tiled_off(cb + c, kb + c4 * 4);
    *(s16x4*)&Thi[o] = *(s16x4*)hi;
    *(s16x4*)&Tlo[o] = *(s16x4*)lo;
  }
}

// Fused 3-weight version for Wq/Wk/Wv -> combined [3072][1024] tiled.
__global__ __launch_bounds__(256) void wsplit3(
    const float* __restrict__ W0, const float* __restrict__ W1,
    const float* __restrict__ W2, short* __restrict__ Thi,
    short* __restrict__ Tlo)
{
  __shared__ float tile[64][65];
  const int z = blockIdx.z;
  const float* W = (z == 0) ? W0 : (z == 1) ? W1 : W2;
  const int t  = threadIdx.x;
  const int kb = blockIdx.y * 64;
  const int cb = blockIdx.x * 64;
  const int r0 = t >> 4;
  const int c4 = t & 15;
  #pragma unroll
  for (int i = 0; i < 4; i++) {
    const int r = r0 + i * 16;
    *(float4*)&tile[r][c4 * 4] = *(const float4*)&W[(long)(kb + r) * D_ + cb + c4 * 4];
  }
  __syncthreads();
  #pragma unroll
  for (int i = 0; i < 4; i++) {
    const int c = r0 + i * 16;
    short hi[4], lo[4];
    #pragma unroll
    for (int e = 0; e < 4; e++)
      split2(tile[c4 * 4 + e][c], hi[e], lo[e]);
    const long o = tiled_off(z * D_ + cb + c, kb + c4 * 4);
    *(s16x4*)&Thi[o] = *(s16x4*)hi;
    *(s16x4*)&Tlo[o] = *(s16x4*)lo;
  }
}

// =====================================================================
// Elementwise fp32 -> tiled-split hi/lo bf16 (for x).
// =====================================================================
__global__ __launch_bounds__(256) void asplit(const float* __restrict__ in,
                                              short* __restrict__ hi,
                                              short* __restrict__ lo)
{
  const long i4 = ((long)blockIdx.x * 256 + threadIdx.x) * 4;
  const int row = (int)(i4 >> 10);
  const int kk  = (int)(i4 & 1023);
  float4 v = *(const float4*)&in[i4];
  short h[4], l[4];
  split2(v.x, h[0], l[0]);
  split2(v.y, h[1], l[1]);
  split2(v.z, h[2], l[2]);
  split2(v.w, h[3], l[3]);
  const long o = tiled_off(row, kk);
  *(s16x4*)&hi[o] = *(s16x4*)h;
  *(s16x4*)&lo[o] = *(s16x4*)l;
}

// =====================================================================
// Split-bf16 MFMA GEMM v2 — all operands pre-split TILED bf16, staged
// with linear global_load_lds (width 16), double-buffered, counted
// vmcnt(8). 128x128 tile, BK=32, 4 waves; wave w stages operand w
// (0:Ahi 1:Alo 2:Bhi 3:Blo) = 8 linear gloads per K-step.
// 3 MFMAs per pair: Al*Bh + Ah*Bl + Ah*Bh.
// MODE 0: C[bz*sC + row*1024 + col] = A@B + bias(bz)   (QKV fused)
// MODE 1: Chi/Clo tiled bf16 = A@B + bias              (iq, ik)
// MODE 2: C = gate(row)*(A@B) + bias, gate = 1 + sum8(part_in[row])/512
// MODE 3: part_out[(bz*N_+row)*8 + bx*2 + wc] = per-wave 64-col partial
//         row sum of sigmoid(acc*SCALE/H)              (gate scores)
// aBlk/bBlk: row-block strides per bz (in 128-row units).
// =====================================================================
template<int MODE>
__global__ __launch_bounds__(256) void mfgemm2(
    const short* __restrict__ Ahi, const short* __restrict__ Alo,
    const short* __restrict__ Bhi, const short* __restrict__ Blo,
    const float* __restrict__ b0, const float* __restrict__ b1,
    const float* __restrict__ b2,
    float* __restrict__ C, short* __restrict__ Chi, short* __restrict__ Clo,
    int aBlk, int bBlk, long sC,
    const float* __restrict__ part_in, float* __restrict__ part_out)
{
  __shared__ short lds[2][4][4096];   // 64 KB: dbuf x 4 operands x 512 chunks x 16B
  const int t = threadIdx.x, w = t >> 6, lane = t & 63;
  const int bx = blockIdx.x, by = blockIdx.y, bz = blockIdx.z;
  const int rowBase = by * 128;
  const int colBase = bx * 128;
  const long aoff = (long)(bz * aBlk + by) * 131072;   // 128 oct * 128 rows * 8
  const long boff = (long)(bz * bBlk + bx) * 131072;
  const short* mySrc = (w == 0) ? Ahi + aoff : (w == 1) ? Alo + aoff
                     : (w == 2) ? Bhi + boff : Blo + boff;

  auto stage = [&](int buf, int tt) {
    const short* g = mySrc + ((long)tt * 512 + lane) * 8;
    #pragma unroll
    for (int i = 0; i < 8; i++)
      GLOAD16(g + i * 512, &lds[buf][w][i * 512]);
  };

  const int wr = w >> 1, wc = w & 1;
  const int lrow = lane & 31, lk = lane >> 5;

  f32x16 acc[2][2] = {};

  auto compute = [&](int buf) {
    #pragma unroll
    for (int kh = 0; kh < 2; kh++) {
      const int kq = 2 * kh + lk;
      bf16x8 ah[2], al[2], bh[2], bl[2];
      #pragma unroll
      for (int m = 0; m < 2; m++) {
        const int r = wr * 64 + m * 32 + lrow;
        ah[m] = *(const bf16x8*)&lds[buf][0][(kq * 128 + r) * 8];
        al[m] = *(const bf16x8*)&lds[buf][1][(kq * 128 + r) * 8];
      }
      #pragma unroll
      for (int n = 0; n < 2; n++) {
        const int c = wc * 64 + n * 32 + lrow;
        bh[n] = *(const bf16x8*)&lds[buf][2][(kq * 128 + c) * 8];
        bl[n] = *(const bf16x8*)&lds[buf][3][(kq * 128 + c) * 8];
      }
      #pragma unroll
      for (int m = 0; m < 2; m++)
        #pragma unroll
        for (int n = 0; n < 2; n++) {
          acc[m][n] = mfma_bf16(al[m], bh[n], acc[m][n]);
          acc[m][n] = mfma_bf16(ah[m], bl[n], acc[m][n]);
          acc[m][n] = mfma_bf16(ah[m], bh[n], acc[m][n]);
        }
    }
  };

  const int NT = 32;   // K=1024 / BK=32
  stage(0, 0);
  for (int tt = 0; tt < NT - 1; ++tt) {
    stage((tt + 1) & 1, tt + 1);                      // issue next-tile loads
    asm volatile("s_waitcnt vmcnt(8)" ::: "memory");  // old 8 landed; new 8 in flight
    __builtin_amdgcn_s_barrier();
    __builtin_amdgcn_sched_barrier(0);
    compute(tt & 1);
    __builtin_amdgcn_s_barrier();                     // all waves done with this buf
  }
  asm volatile("s_waitcnt vmcnt(0)" ::: "memory");
  __builtin_amdgcn_s_barrier();
  __builtin_amdgcn_sched_barrier(0);
  compute((NT - 1) & 1);

  // ---------------- epilogue ----------------
  if (MODE == 3) {
    const float sc = 0.125f / 16.f;   // SCALE/H
    #pragma unroll
    for (int m = 0; m < 2; m++)
      #pragma unroll
      for (int r = 0; r < 16; r++) {
        const int row = rowBase + wr * 64 + m * 32 + (r & 3) + 8 * (r >> 2) + 4 * lk;
        float v = 1.f / (1.f + __expf(-acc[m][0][r] * sc))
                + 1.f / (1.f + __expf(-acc[m][1][r] * sc));
        v += __shfl_xor(v, 1);  v += __shfl_xor(v, 2);  v += __shfl_xor(v, 4);
        v += __shfl_xor(v, 8);  v += __shfl_xor(v, 16);
        if (lrow == 0)
          part_out[(long)(bz * N_ + row) * 8 + bx * 2 + wc] = v;
      }
    return;
  }

  const float* bias = (bz == 1) ? b1 : (bz == 2) ? b2 : b0;
  float bcol[2];
  #pragma unroll
  for (int n = 0; n < 2; n++)
    bcol[n] = bias[colBase + wc * 64 + n * 32 + lrow];

  float* Cb = C + (long)bz * sC;

  #pragma unroll
  for (int m = 0; m < 2; m++) {
    #pragma unroll
    for (int r = 0; r < 16; r++) {
      const int row = rowBase + wr * 64 + m * 32 + (r & 3) + 8 * (r >> 2) + 4 * lk;
      float g = 1.f;
      if (MODE == 2) {
        const float4 p0 = *(const float4*)&part_in[(long)row * 8];
        const float4 p1 = *(const float4*)&part_in[(long)row * 8 + 4];
        g = 1.f + (p0.x + p0.y + p0.z + p0.w + p1.x + p1.y + p1.z + p1.w)
                  * (1.f / 512.f);
      }
      #pragma unroll
      for (int n = 0; n < 2; n++) {
        const int col = colBase + wc * 64 + n * 32 + lrow;
        const float val = acc[m][n][r] * g + bcol[n];
        if (MODE == 1) {
          short hi, lo;
          split2(val, hi, lo);
          const long o = tiled_off(row, col);
          Chi[o] = hi;
          Clo[o] = lo;
        } else {
          Cb[(long)row * D_ + col] = val;
        }
      }
    }
  }
}

// =====================================================================
// MFMA grouped flash attention, bf16 compute, fp32 softmax state.
// grid (N/128, H, B), 256 thr = 4 waves; wave owns 32 q rows.
// Swapped QK^T, static softmax max (|s*SCALE|<=8 from RMS-normed q,k),
// fused QK-RMSNorm, K LDS XOR-swizzle, V^T LDS, T14 K/V reg prefetch.
// Output: split bf16 hi/lo in TILED layout (feeds iq/final GEMMs).
// =====================================================================
__global__ __launch_bounds__(256) void attn_mfma(
    const float* __restrict__ q, const float* __restrict__ k,
    const float* __restrict__ v, const float* __restrict__ qnw,
    const float* __restrict__ knw, short* __restrict__ ohi,
    short* __restrict__ olo)
{
  const int b  = blockIdx.z, h = blockIdx.y, qb = blockIdx.x;
  const int g  = b >> 2;
  const int t  = threadIdx.x;
  const int w  = t >> 6;
  const int lane = t & 63;
  const int l31 = lane & 31, hi = lane >> 5;

  __shared__ short Ks[32 * 64];   // [kv][hd] bf16, swizzled
  __shared__ short Vs[64 * 40];   // [d][kv] bf16, stride 40 shorts

  // ---- Q: load + RMSNorm + B-operand frags ----
  const int qrow = qb * 128 + w * 32 + l31;
  const float* qp = q + ((long)b * N_ + qrow) * D_ + h * HD_ + hi * 8;
  float qv[4][8];
  float ss = 0.f;
  #pragma unroll
  for (int c = 0; c < 4; c++) {
    *(float4*)&qv[c][0] = *(const float4*)&qp[c * 16];
    *(float4*)&qv[c][4] = *(const float4*)&qp[c * 16 + 4];
    #pragma unroll
    for (int j = 0; j < 8; j++) ss += qv[c][j] * qv[c][j];
  }
  ss += __shfl_xor(ss, 32);
  const float qr = rsqrtf(ss * (1.f / 64.f) + 1e-6f);
  bf16x8 qf[4];
  #pragma unroll
  for (int c = 0; c < 4; c++)
    #pragma unroll
    for (int j = 0; j < 8; j++)
      qf[c][j] = bf16_rn(qv[c][j] * qr * qnw[c * 16 + hi * 8 + j]);

  // staging maps
  const int skv = t >> 3, sg = t & 7;
  const int vkv = t & 31, vg = t >> 5;
  float kw[8];
  #pragma unroll
  for (int j = 0; j < 8; j++) kw[j] = knw[sg * 8 + j];

  f32x16 oacc[2] = {};
  float l = 0.f;

  auto loadKV = [&](int kt, float* kf, float* vf) {
    const int inst = (kt * 32) >> 9;
    const int nn0  = (kt * 32) & (N_ - 1);
    const long rowK = ((long)(g * NI_ + inst) * N_ + nn0 + skv) * D_ + h * HD_ + sg * 8;
    const long rowV = ((long)(g * NI_ + inst) * N_ + nn0 + vkv) * D_ + h * HD_ + vg * 8;
    *(float4*)&kf[0] = *(const float4*)&k[rowK];
    *(float4*)&kf[4] = *(const float4*)&k[rowK + 4];
    *(float4*)&vf[0] = *(const float4*)&v[rowV];
    *(float4*)&vf[4] = *(const float4*)&v[rowV + 4];
  };

  auto tilestep = [&](int kt, float* kf, float* vf, float* kfn, float* vfn) {
    float ks2 = 0.f;
    #pragma unroll
    for (int j = 0; j < 8; j++) ks2 += kf[j] * kf[j];
    ks2 += __shfl_xor(ks2, 1);
    ks2 += __shfl_xor(ks2, 2);
    ks2 += __shfl_xor(ks2, 4);
    const float kr = rsqrtf(ks2 * (1.f / 64.f) + 1e-6f);

    __syncthreads();   // previous tile fully consumed
    bf16x8 kb_;
    #pragma unroll
    for (int j = 0; j < 8; j++) kb_[j] = bf16_rn(kf[j] * kr * kw[j]);
    *(bf16x8*)&Ks[skv * 64 + ((sg * 8) ^ ((skv & 7) << 3))] = kb_;
    #pragma unroll
    for (int e = 0; e < 8; e++)
      Vs[(vg * 8 + e) * 40 + vkv] = bf16_rn(vf[e]);
    __syncthreads();

    if (kt + 1 < KVLEN / 32) loadKV(kt + 1, kfn, vfn);   // T14 prefetch

    f32x16 sc = {};
    #pragma unroll
    for (int c = 0; c < 4; c++) {
      bf16x8 kfr = *(const bf16x8*)&Ks[l31 * 64 + (((2 * c + hi) * 8) ^ ((l31 & 7) << 3))];
      sc = mfma_bf16(kfr, qf[c], sc);
    }
    float p[16];
    #pragma unroll
    for (int r = 0; r < 16; r++) { p[r] = __expf(sc[r] * 0.125f - 8.f); l += p[r]; }
    unsigned wd[8], sw[8];
    #pragma unroll
    for (int i = 0; i < 8; i++)
      wd[i] = ((unsigned)(unsigned short)bf16_rn(p[2 * i + 1]) << 16)
            | (unsigned short)bf16_rn(p[2 * i]);
    #pragma unroll
    for (int i = 0; i < 8; i++) sw[i] = __shfl_xor(wd[i], 32);
    int4 f0 = { (int)(hi ? sw[2] : wd[0]), (int)(hi ? sw[3] : wd[1]),
                (int)(hi ? wd[2] : sw[0]), (int)(hi ? wd[3] : sw[1]) };
    int4 f1 = { (int)(hi ? sw[6] : wd[4]), (int)(hi ? sw[7] : wd[5]),
                (int)(hi ? wd[6] : sw[4]), (int)(hi ? wd[7] : sw[5]) };
    #pragma unroll
    for (int n = 0; n < 2; n++) {
      bf16x8 v0 = *(const bf16x8*)&Vs[(n * 32 + l31) * 40 + hi * 8];
      bf16x8 v1 = *(const bf16x8*)&Vs[(n * 32 + l31) * 40 + 16 + hi * 8];
      oacc[n] = mfma_bf16(__builtin_bit_cast(bf16x8, f0), v0, oacc[n]);
      oacc[n] = mfma_bf16(__builtin_bit_cast(bf16x8, f1), v1, oacc[n]);
    }
  };

  float ka[8], va[8], kb2[8], vb2[8];
  loadKV(0, ka, va);
  for (int kt = 0; kt < KVLEN / 32; kt += 2) {
    tilestep(kt,     ka,  va,  kb2, vb2);
    tilestep(kt + 1, kb2, vb2, ka,  va);
  }

  // ---- epilogue: divide by l, split to tiled bf16 hi/lo ----
  l += __shfl_xor(l, 32);
  const float linv = 1.f / l;
  float lr[16];
  #pragma unroll
  for (int r = 0; r < 16; r++)
    lr[r] = __shfl(linv, (r & 3) + 8 * (r >> 2) + 4 * hi);
  #pragma unroll
  for (int r = 0; r < 16; r++) {
    const int qg = qb * 128 + w * 32 + (r & 3) + 8 * (r >> 2) + 4 * hi;
    const int grow = b * N_ + qg;
    short h0, l0, h1, l1;
    split2(oacc[0][r] * lr[r], h0, l0);
    split2(oacc[1][r] * lr[r], h1, l1);
    const long o0 = tiled_off(grow, h * HD_ + l31);
    const long o1 = tiled_off(grow, h * HD_ + l31 + 32);
    ohi[o0] = h0;  olo[o0] = l0;
    ohi[o1] = h1;  olo[o1] = l1;
  }
}

// =====================================================================
// inst_feat split: mask @ embed -> tiled hi/lo bf16 [B*N][D]
// =====================================================================
__global__ __launch_bounds__(256) void instfeat_split(
    const float* __restrict__ mask, const float* __restrict__ emb,
    short* __restrict__ ofh, short* __restrict__ ofl)
{
  const long idx = (long)blockIdx.x * 256 + threadIdx.x;
  const int  d4  = (int)(idx & (D_ / 4 - 1));
  const long bn  = idx >> 8;
  const float* mk = mask + bn * NI_;
  float4 acc = {0.f, 0.f, 0.f, 0.f};
  #pragma unroll
  for (int i = 0; i < NI_; i++) {
    const float mm = mk[i];
    const float4 e = *(const float4*)&emb[(long)i * D_ + d4 * 4];
    acc.x = fmaf(mm, e.x, acc.x);
    acc.y = fmaf(mm, e.y, acc.y);
    acc.z = fmaf(mm, e.z, acc.z);
    acc.w = fmaf(mm, e.w, acc.w);
  }
  short h[4], l[4];
  split2(acc.x, h[0], l[0]);
  split2(acc.y, h[1], l[1]);
  split2(acc.z, h[2], l[2]);
  split2(acc.w, h[3], l[3]);
  const long o = tiled_off((int)bn, d4 * 4);
  *(s16x4*)&ofh[o] = *(s16x4*)h;
  *(s16x4*)&ofl[o] = *(s16x4*)l;
}

// =====================================================================
extern "C" void kernel_launch(void* const* d_in, const int* in_sizes, int n_in,
                              void* d_out, int out_size, void* d_ws, size_t ws_size,
                              hipStream_t stream)
{
  const float* x    = (const float*)d_in[0];
  const float* mask = (const float*)d_in[1];
  const float* Wq   = (const float*)d_in[2];
  const float* bq   = (const float*)d_in[3];
  const float* Wk   = (const float*)d_in[4];
  const float* bk   = (const float*)d_in[5];
  const float* Wv   = (const float*)d_in[6];
  const float* bv   = (const float*)d_in[7];
  const float* Wo   = (const float*)d_in[8];
  const float* bo   = (const float*)d_in[9];
  const float* Wiq  = (const float*)d_in[10];
  const float* biq  = (const float*)d_in[11];
  const float* Wik  = (const float*)d_in[12];
  const float* bik  = (const float*)d_in[13];
  const float* emb  = (const float*)d_in[14];
  const float* qnw  = (const float*)d_in[15];
  const float* knw  = (const float*)d_in[16];
  float* out = (float*)d_out;

  float* ws = (float*)d_ws;
  const size_t SZ = (size_t)BN_ * D_;
  float* qbuf = ws;
  float* kbuf = qbuf + SZ;
  float* vbuf = kbuf + SZ;
  short* ohi  = (short*)(vbuf + SZ);
  short* olo  = ohi + SZ;
  short* xhi  = (short*)(ws + 4 * SZ);
  short* xlo  = xhi + SZ;
  short* Wbig_hi = (short*)(ws + 5 * SZ);
  short* Wbig_lo = Wbig_hi + (size_t)3 * D_ * D_;
  float* part = (float*)(Wbig_lo + (size_t)3 * D_ * D_);
  short* iqh = (short*)qbuf;  short* iql = iqh + SZ;
  short* ifh = (short*)kbuf;  short* ifl = ifh + SZ;
  short* ikh = (short*)vbuf;  short* ikl = ikh + SZ;
  short* Wsl_hi = Wbig_hi;    short* Wsl_lo = Wbig_hi + (size_t)D_ * D_;

  const dim3 blk(256);

  // 1) weight prep + x split (all into tiled-split layout)
  wsplit3<<<dim3(16, 16, 3), blk, 0, stream>>>(Wq, Wk, Wv, Wbig_hi, Wbig_lo);
  asplit<<<(BN_ * D_ / 4) / 256, blk, 0, stream>>>(x, xhi, xlo);

  // 2) fused QKV projection: grid 8x32x3 = 768 blocks
  mfgemm2<0><<<dim3(8, 32, 3), blk, 0, stream>>>(
      xhi, xlo, Wbig_hi, Wbig_lo, bq, bk, bv,
      qbuf, nullptr, nullptr, /*aBlk=*/0, /*bBlk=*/8, (long)SZ, nullptr, nullptr);

  // 3) attention (fused QK-RMSNorm) -> tiled split bf16 output
  attn_mfma<<<dim3(N_ / 128, H_, B_), blk, 0, stream>>>(
      qbuf, kbuf, vbuf, qnw, knw, ohi, olo);

  // 4) IQ = o@Wiq+biq, tiled split output (overwrites qbuf slot)
  wsplitT<<<dim3(16, 16), blk, 0, stream>>>(Wiq, Wsl_hi, Wsl_lo);
  mfgemm2<1><<<dim3(8, 32, 1), blk, 0, stream>>>(
      ohi, olo, Wsl_hi, Wsl_lo, biq, nullptr, nullptr,
      nullptr, iqh, iql, 0, 0, 0, nullptr, nullptr);

  // 5) inst_feat split (overwrites kbuf slot)
  instfeat_split<<<(BN_ * D_ / 4) / 256, blk, 0, stream>>>(mask, emb, ifh, ifl);

  // 6) IK = inst_feat@Wik+bik, tiled split output (overwrites vbuf slot)
  wsplitT<<<dim3(16, 16), blk, 0, stream>>>(Wik, Wsl_hi, Wsl_lo);
  mfgemm2<1><<<dim3(8, 32, 1), blk, 0, stream>>>(
      ifh, ifl, Wsl_hi, Wsl_lo, bik, nullptr, nullptr,
      nullptr, ikh, ikl, 0, 0, 0, nullptr, nullptr);

  // 7) gate partials: per-batch IQ[b] @ IK[b]^T, sigmoid, per-wave partials
  mfgemm2<3><<<dim3(4, 4, 8), blk, 0, stream>>>(
      iqh, iql, ikh, ikl, nullptr, nullptr, nullptr,
      nullptr, nullptr, nullptr, /*aBlk=*/4, /*bBlk=*/4, 0,
      nullptr, part);

  // 8) final: gate(row)*(o@Wo) + bo -> d_out
  wsplitT<<<dim3(16, 16), blk, 0, stream>>>(Wo, Wsl_hi, Wsl_lo);
  mfgemm2<2><<<dim3(8, 32, 1), blk, 0, stream>>>(
      ohi, olo, Wsl_hi, Wsl_lo, bo, nullptr, nullptr,
      out, nullptr, nullptr, 0, 0, 0, part, nullptr);
}

// Round 9
// 302.738 us; speedup vs baseline: 1.9727x; 1.1549x over previous
//
#include <hip/hip_runtime.h>
#include <cmath>

// Problem constants (fixed by the reference file)
#define B_   8
#define N_   512
#define D_   1024
#define H_   16
#define HD_  64
#define NI_  4
#define BN_  (B_*N_)      // 4096 rows when [B,N,*] is flattened
#define KVLEN (NI_*N_)    // 2048 keys per attention group

typedef __attribute__((ext_vector_type(8)))  short  bf16x8;   // 8 bf16 bit patterns
typedef __attribute__((ext_vector_type(8)))  __bf16 bf16x8_t; // builtin operand type
typedef __attribute__((ext_vector_type(16))) float  f32x16;
typedef __attribute__((ext_vector_type(4)))  short  s16x4;

// round-to-nearest-even bf16 conversion (bit trick)
__device__ __forceinline__ short bf16_rn(float x) {
  unsigned u = __float_as_uint(x);
  unsigned r = (u + 0x7FFFu + ((u >> 16) & 1u)) >> 16;
  return (short)r;
}

// RN hi/lo split: x = hi + lo + eps, |eps| <~ 2^-18 |x|.
__device__ __forceinline__ void split2(float x, short& hi, short& lo) {
  hi = bf16_rn(x);
  float h = __uint_as_float(((unsigned)(unsigned short)hi) << 16);
  float r = x - h;              // exact (Dekker-style split)
  lo = bf16_rn(r);
}

__device__ __forceinline__ f32x16 mfma_bf16(bf16x8 a, bf16x8 b, f32x16 c) {
  return __builtin_amdgcn_mfma_f32_32x32x16_bf16(
      __builtin_bit_cast(bf16x8_t, a), __builtin_bit_cast(bf16x8_t, b), c, 0, 0, 0);
}

#define GLOAD16(gp, lp) __builtin_amdgcn_global_load_lds( \
  (const __attribute__((address_space(1))) unsigned*)(gp), \
  (__attribute__((address_space(3))) unsigned*)(lp), 16, 0, 0)

// TILED-SPLIT layout for all bf16 GEMM operands (K = 1024):
// addr(row,k) = (((row>>7)*128 + (k>>3))*128 + (row&127))*8 + (k&7).
// GEMM staging is then a LINEAR copy -> fully coalesced global_load_lds.
__device__ __forceinline__ long tiled_off(int row, int k) {
  return ((((long)(row >> 7) * 128 + (k >> 3)) * 128 + (row & 127)) * 8 + (k & 7));
}

// =====================================================================
// Weight transpose + hi/lo split: W[K][C] fp32 -> tiled-split T[C][K].
// WLO=0 skips the lo plane (for plain-bf16 consumers: Wiq, Wik).
// =====================================================================
template<int WLO>
__global__ __launch_bounds__(256) void wsplitT(const float* __restrict__ W,
                                               short* __restrict__ Thi,
                                               short* __restrict__ Tlo)
{
  __shared__ float tile[64][65];
  const int t  = threadIdx.x;
  const int kb = blockIdx.y * 64;
  const int cb = blockIdx.x * 64;
  const int r0 = t >> 4;
  const int c4 = t & 15;
  #pragma unroll
  for (int i = 0; i < 4; i++) {
    const int r = r0 + i * 16;
    *(float4*)&tile[r][c4 * 4] = *(const float4*)&W[(long)(kb + r) * D_ + cb + c4 * 4];
  }
  __syncthreads();
  #pragma unroll
  for (int i = 0; i < 4; i++) {
    const int c = r0 + i * 16;
    short hi[4], lo[4];
    #pragma unroll
    for (int e = 0; e < 4; e++)
      split2(tile[c4 * 4 + e][c], hi[e], lo[e]);
    const long o = tiled_off(cb + c, kb + c4 * 4);
    *(s16x4*)&Thi[o] = *(s16x4*)hi;
    if (WLO) *(s16x4*)&Tlo[o] = *(s16x4*)lo;
  }
}

// Fused 3-weight version for Wq/Wk/Wv -> combined [3072][1024] tiled.
__global__ __launch_bounds__(256) void wsplit3(
    const float* __restrict__ W0, const float* __restrict__ W1,
    const float* __restrict__ W2, short* __restrict__ Thi,
    short* __restrict__ Tlo)
{
  __shared__ float tile[64][65];
  const int z = blockIdx.z;
  const float* W = (z == 0) ? W0 : (z == 1) ? W1 : W2;
  const int t  = threadIdx.x;
  const int kb = blockIdx.y * 64;
  const int cb = blockIdx.x * 64;
  const int r0 = t >> 4;
  const int c4 = t & 15;
  #pragma unroll
  for (int i = 0; i < 4; i++) {
    const int r = r0 + i * 16;
    *(float4*)&tile[r][c4 * 4] = *(const float4*)&W[(long)(kb + r) * D_ + cb + c4 * 4];
  }
  __syncthreads();
  #pragma unroll
  for (int i = 0; i < 4; i++) {
    const int c = r0 + i * 16;
    short hi[4], lo[4];
    #pragma unroll
    for (int e = 0; e < 4; e++)
      split2(tile[c4 * 4 + e][c], hi[e], lo[e]);
    const long o = tiled_off(z * D_ + cb + c, kb + c4 * 4);
    *(s16x4*)&Thi[o] = *(s16x4*)hi;
    *(s16x4*)&Tlo[o] = *(s16x4*)lo;
  }
}

// =====================================================================
// Elementwise fp32 -> tiled-split hi/lo bf16 (for x).
// =====================================================================
__global__ __launch_bounds__(256) void asplit(const float* __restrict__ in,
                                              short* __restrict__ hi,
                                              short* __restrict__ lo)
{
  const long i4 = ((long)blockIdx.x * 256 + threadIdx.x) * 4;
  const int row = (int)(i4 >> 10);
  const int kk  = (int)(i4 & 1023);
  float4 v = *(const float4*)&in[i4];
  short h[4], l[4];
  split2(v.x, h[0], l[0]);
  split2(v.y, h[1], l[1]);
  split2(v.z, h[2], l[2]);
  split2(v.w, h[3], l[3]);
  const long o = tiled_off(row, kk);
  *(s16x4*)&hi[o] = *(s16x4*)h;
  *(s16x4*)&lo[o] = *(s16x4*)l;
}

// =====================================================================
// MFMA GEMM v3. Tiled bf16 operands, linear global_load_lds staging,
// double-buffered LDS, counted vmcnt.
// SPLIT=1: hi/lo split inputs (3 MFMAs/pair, fp32-like accuracy);
//          wave w stages operand w (Ahi,Alo,Bhi,Blo), vmcnt(8).
// SPLIT=0: plain bf16 (1 MFMA/pair); waves 0,1 stage A halves,
//          waves 2,3 stage B halves, vmcnt(4). (gate path only: errors
//          attenuated by sigmoid'/4 and the /512 mean -> <1e-6 in gate.)
// MODE 0: C[bz*sC + row*D + col] = A@B + bias(bz)     (QKV fused)
// MODE 1: Chi tiled bf16 = A@B + bias                 (iq, ik)
// MODE 2: C = gate(row)*(A@B) + bias, gate = 1 + sum8(part_in[row])/512
// MODE 3: part_out[(bz*N+row)*8 + bx*2 + wc] = per-wave 64-col partial
//         row sum of sigmoid(acc*SCALE/H).
//         ROUND-8 LESSON: the gate GEMM must NOT be K-split — sigmoid
//         sits between the K-reduction and the m-sum, and
//         sigmoid(z1)+sigmoid(z2) != sigmoid(z1+z2). Full K per block.
// =====================================================================
template<int MODE, int SPLIT>
__global__ __launch_bounds__(256) void mfgemm2(
    const short* __restrict__ Ahi, const short* __restrict__ Alo,
    const short* __restrict__ Bhi, const short* __restrict__ Blo,
    const float* __restrict__ b0, const float* __restrict__ b1,
    const float* __restrict__ b2,
    float* __restrict__ C, short* __restrict__ Chi, short* __restrict__ Clo,
    int aBlk, int bBlk, long sC,
    const float* __restrict__ part_in, float* __restrict__ part_out)
{
  constexpr int NOPS = SPLIT ? 4 : 2;
  __shared__ short lds[2][NOPS][4096];
  const int t = threadIdx.x, w = t >> 6, lane = t & 63;
  const int bx = blockIdx.x, by = blockIdx.y, bz = blockIdx.z;
  const int rowBase = by * 128;
  const int colBase = bx * 128;
  const long aoff = (long)(bz * aBlk + by) * 131072;   // 128 oct * 128 rows * 8
  const long boff = (long)(bz * bBlk + bx) * 131072;

  const short* mySrc;
  int op, half;
  if (SPLIT) {
    op = w; half = 0;
    mySrc = (w == 0) ? Ahi + aoff : (w == 1) ? Alo + aoff
          : (w == 2) ? Bhi + boff : Blo + boff;
  } else {
    op = w >> 1; half = w & 1;
    mySrc = op ? Bhi + boff : Ahi + aoff;
  }

  auto stage = [&](int buf, int tt) {
    if (SPLIT) {
      const short* g = mySrc + ((long)tt * 512 + lane) * 8;
      #pragma unroll
      for (int i = 0; i < 8; i++)
        GLOAD16(g + i * 512, &lds[buf][op][i * 512]);
    } else {
      const short* g = mySrc + ((long)tt * 512 + half * 256 + lane) * 8;
      #pragma unroll
      for (int i = 0; i < 4; i++)
        GLOAD16(g + i * 512, &lds[buf][op][(half * 256 + i * 64) * 8]);
    }
  };

  const int wr = w >> 1, wc = w & 1;
  const int lrow = lane & 31, lk = lane >> 5;

  f32x16 acc[2][2] = {};

  auto compute = [&](int buf) {
    #pragma unroll
    for (int kh = 0; kh < 2; kh++) {
      const int kq = 2 * kh + lk;
      bf16x8 ah[2], bh[2];
      #pragma unroll
      for (int m = 0; m < 2; m++)
        ah[m] = *(const bf16x8*)&lds[buf][0][(kq * 128 + wr * 64 + m * 32 + lrow) * 8];
      #pragma unroll
      for (int n = 0; n < 2; n++)
        bh[n] = *(const bf16x8*)&lds[buf][SPLIT ? 2 : 1][(kq * 128 + wc * 64 + n * 32 + lrow) * 8];
      if (SPLIT) {
        bf16x8 al[2], bl[2];
        #pragma unroll
        for (int m = 0; m < 2; m++)
          al[m] = *(const bf16x8*)&lds[buf][1][(kq * 128 + wr * 64 + m * 32 + lrow) * 8];
        #pragma unroll
        for (int n = 0; n < 2; n++)
          bl[n] = *(const bf16x8*)&lds[buf][3][(kq * 128 + wc * 64 + n * 32 + lrow) * 8];
        #pragma unroll
        for (int m = 0; m < 2; m++)
          #pragma unroll
          for (int n = 0; n < 2; n++) {
            acc[m][n] = mfma_bf16(al[m], bh[n], acc[m][n]);
            acc[m][n] = mfma_bf16(ah[m], bl[n], acc[m][n]);
            acc[m][n] = mfma_bf16(ah[m], bh[n], acc[m][n]);
          }
      } else {
        #pragma unroll
        for (int m = 0; m < 2; m++)
          #pragma unroll
          for (int n = 0; n < 2; n++)
            acc[m][n] = mfma_bf16(ah[m], bh[n], acc[m][n]);
      }
    }
  };

  const int NT = 32;   // K=1024 / BK=32 (always full K — see MODE 3 note)
  stage(0, 0);
  for (int tt = 0; tt < NT - 1; ++tt) {
    stage((tt + 1) & 1, tt + 1);
    if (SPLIT) asm volatile("s_waitcnt vmcnt(8)" ::: "memory");
    else       asm volatile("s_waitcnt vmcnt(4)" ::: "memory");
    __builtin_amdgcn_s_barrier();
    __builtin_amdgcn_sched_barrier(0);
    compute(tt & 1);
    __builtin_amdgcn_s_barrier();
  }
  asm volatile("s_waitcnt vmcnt(0)" ::: "memory");
  __builtin_amdgcn_s_barrier();
  __builtin_amdgcn_sched_barrier(0);
  compute((NT - 1) & 1);

  // ---------------- epilogue ----------------
  if (MODE == 3) {
    const float sc = 0.125f / 16.f;   // SCALE/H
    #pragma unroll
    for (int m = 0; m < 2; m++)
      #pragma unroll
      for (int r = 0; r < 16; r++) {
        const int row = rowBase + wr * 64 + m * 32 + (r & 3) + 8 * (r >> 2) + 4 * lk;
        float v = 1.f / (1.f + __expf(-acc[m][0][r] * sc))
                + 1.f / (1.f + __expf(-acc[m][1][r] * sc));
        v += __shfl_xor(v, 1);  v += __shfl_xor(v, 2);  v += __shfl_xor(v, 4);
        v += __shfl_xor(v, 8);  v += __shfl_xor(v, 16);
        if (lrow == 0)
          part_out[(long)(bz * N_ + row) * 8 + bx * 2 + wc] = v;
      }
    return;
  }

  const float* bias = (bz == 1) ? b1 : (bz == 2) ? b2 : b0;
  float bcol[2];
  #pragma unroll
  for (int n = 0; n < 2; n++)
    bcol[n] = bias[colBase + wc * 64 + n * 32 + lrow];

  float* Cb = C + (long)bz * sC;

  #pragma unroll
  for (int m = 0; m < 2; m++) {
    #pragma unroll
    for (int r = 0; r < 16; r++) {
      const int row = rowBase + wr * 64 + m * 32 + (r & 3) + 8 * (r >> 2) + 4 * lk;
      float g = 1.f;
      if (MODE == 2) {
        const float4 p0 = *(const float4*)&part_in[(long)row * 8];
        const float4 p1 = *(const float4*)&part_in[(long)row * 8 + 4];
        g = 1.f + (p0.x + p0.y + p0.z + p0.w + p1.x + p1.y + p1.z + p1.w)
                  * (1.f / 512.f);
      }
      #pragma unroll
      for (int n = 0; n < 2; n++) {
        const int col = colBase + wc * 64 + n * 32 + lrow;
        const float val = acc[m][n][r] * g + bcol[n];
        if (MODE == 1) {
          Chi[tiled_off(row, col)] = bf16_rn(val);
        } else {
          Cb[(long)row * D_ + col] = val;
        }
      }
    }
  }
}

// =====================================================================
// KV prep: per GROUP (g = b>>2), head h, 32-kv tile:
//  - K: RMSNorm (+knw) -> bf16, stored [g][h][m][64] with per-row chunk
//    XOR swizzle (chunk c -> c ^ (m&7)): attention reads conflict-free.
//  - V: transposed tiles [g][h][tile][d][32kv] bf16, chunk swizzle
//    (kv-octet o -> o ^ ((d>>1)&3)): 4-way-max conflict on b128 reads.
// Both layouts are LINEAR per 4KB tile -> attention stages them with
// coalesced global_load_lds (no VALU in the attention hot loop).
// =====================================================================
__global__ __launch_bounds__(256) void kvprep(
    const float* __restrict__ kf, const float* __restrict__ vf,
    const float* __restrict__ knw, short* __restrict__ Knb,
    short* __restrict__ Vtb)
{
  const int tile = blockIdx.x, h = blockIdx.y, g = blockIdx.z;
  const int t = threadIdx.x;
  // ---- K ----
  const int skv = t >> 3, sg = t & 7;
  const int m  = tile * 32 + skv;
  const int bb = g * NI_ + (m >> 9), nn = m & (N_ - 1);
  const float* kp = kf + ((long)(bb * N_ + nn)) * D_ + h * HD_ + sg * 8;
  float k8[8];
  *(float4*)&k8[0] = *(const float4*)&kp[0];
  *(float4*)&k8[4] = *(const float4*)&kp[4];
  float ks2 = 0.f;
  #pragma unroll
  for (int j = 0; j < 8; j++) ks2 += k8[j] * k8[j];
  ks2 += __shfl_xor(ks2, 1);
  ks2 += __shfl_xor(ks2, 2);
  ks2 += __shfl_xor(ks2, 4);
  const float kr = rsqrtf(ks2 * (1.f / 64.f) + 1e-6f);
  bf16x8 kb;
  #pragma unroll
  for (int j = 0; j < 8; j++) kb[j] = bf16_rn(k8[j] * kr * knw[sg * 8 + j]);
  *(bf16x8*)&Knb[((long)(g * H_ + h) * KVLEN + m) * 64 + ((sg ^ (m & 7)) * 8)] = kb;
  // ---- V ----
  const int vkv = t & 31, vg = t >> 5;
  const int m2  = tile * 32 + vkv;
  const int bb2 = g * NI_ + (m2 >> 9), nn2 = m2 & (N_ - 1);
  const float* vp = vf + ((long)(bb2 * N_ + nn2)) * D_ + h * HD_ + vg * 8;
  float v8[8];
  *(float4*)&v8[0] = *(const float4*)&vp[0];
  *(float4*)&v8[4] = *(const float4*)&vp[4];
  const long vbase = ((long)(g * H_ + h) * 64 + tile) * 2048;
  #pragma unroll
  for (int e = 0; e < 8; e++) {
    const int d = vg * 8 + e;
    Vtb[vbase + d * 32 + (((vkv >> 3) ^ ((d >> 1) & 3)) * 8) + (vkv & 7)] = bf16_rn(v8[e]);
  }
}

// =====================================================================
// MFMA grouped flash attention v2. grid (N/128, H, B), 4 waves.
// K/V pre-normalized bf16 (kvprep) staged via linear global_load_lds,
// double-buffered, counted vmcnt(2). Swapped QK^T; STATIC softmax max
// (RMS-normed q,k => |s*SCALE| <= 8); exp2-folded softmax; cvt_pk P
// packing; fused Q-RMSNorm; split bf16 tiled output.
// =====================================================================
__global__ __launch_bounds__(256) void attn2(
    const float* __restrict__ q, const short* __restrict__ Knb,
    const short* __restrict__ Vtb, const float* __restrict__ qnw,
    short* __restrict__ ohi, short* __restrict__ olo)
{
  const int b  = blockIdx.z, h = blockIdx.y, qb = blockIdx.x;
  const int g  = b >> 2;
  const int t  = threadIdx.x;
  const int w  = t >> 6;
  const int lane = t & 63;
  const int l31 = lane & 31, hi = lane >> 5;

  __shared__ short Kt[2][2048];
  __shared__ short Vt[2][2048];

  // ---- Q: load + RMSNorm + B-operand frags ----
  const int qrow = qb * 128 + w * 32 + l31;
  const float* qp = q + ((long)b * N_ + qrow) * D_ + h * HD_ + hi * 8;
  float qv[4][8];
  float ss = 0.f;
  #pragma unroll
  for (int c = 0; c < 4; c++) {
    *(float4*)&qv[c][0] = *(const float4*)&qp[c * 16];
    *(float4*)&qv[c][4] = *(const float4*)&qp[c * 16 + 4];
    #pragma unroll
    for (int j = 0; j < 8; j++) ss += qv[c][j] * qv[c][j];
  }
  ss += __shfl_xor(ss, 32);
  const float qr = rsqrtf(ss * (1.f / 64.f) + 1e-6f);
  bf16x8 qf[4];
  #pragma unroll
  for (int c = 0; c < 4; c++)
    #pragma unroll
    for (int j = 0; j < 8; j++)
      qf[c][j] = bf16_rn(qv[c][j] * qr * qnw[c * 16 + hi * 8 + j]);

  const short* Kg = Knb + (long)(g * H_ + h) * KVLEN * 64;
  const short* Vg = Vtb + (long)(g * H_ + h) * 64 * 2048;

  auto stage = [&](int buf, int kt) {
    GLOAD16(Kg + (long)kt * 2048 + t * 8, &Kt[buf][w * 512]);
    GLOAD16(Vg + (long)kt * 2048 + t * 8, &Vt[buf][w * 512]);
  };

  f32x16 oacc[2] = {};
  float l = 0.f;

  stage(0, 0);
  for (int kt = 0; kt < KVLEN / 32; ++kt) {
    const int buf = kt & 1;
    if (kt + 1 < KVLEN / 32) {
      stage(buf ^ 1, kt + 1);
      asm volatile("s_waitcnt vmcnt(2)" ::: "memory");
    } else {
      asm volatile("s_waitcnt vmcnt(0)" ::: "memory");
    }
    __builtin_amdgcn_s_barrier();
    __builtin_amdgcn_sched_barrier(0);

    // ---- QK^T: scores[kv][q] ----
    f32x16 sc = {};
    #pragma unroll
    for (int c = 0; c < 4; c++) {
      bf16x8 kfr = *(const bf16x8*)&Kt[buf][l31 * 64 + (((2 * c + hi) * 8) ^ ((l31 & 7) << 3))];
      sc = mfma_bf16(kfr, qf[c], sc);
    }
    // ---- softmax, static max: p = exp2(s*0.125*log2e - 8*log2e) ----
    float p[16];
    #pragma unroll
    for (int r = 0; r < 16; r++) {
      p[r] = exp2f(fmaf(sc[r], 0.1803368801111244f, -11.541560327111961f));
      l += p[r];
    }
    // ---- pack P pairs to bf16 (cvt_pk), swap kv halves across lanes ----
    unsigned wd[8], sw[8];
    #pragma unroll
    for (int i = 0; i < 8; i++)
      asm("v_cvt_pk_bf16_f32 %0, %1, %2" : "=v"(wd[i]) : "v"(p[2 * i]), "v"(p[2 * i + 1]));
    #pragma unroll
    for (int i = 0; i < 8; i++) sw[i] = __shfl_xor(wd[i], 32);
    int4 f0 = { (int)(hi ? sw[2] : wd[0]), (int)(hi ? sw[3] : wd[1]),
                (int)(hi ? wd[2] : sw[0]), (int)(hi ? wd[3] : sw[1]) };
    int4 f1 = { (int)(hi ? sw[6] : wd[4]), (int)(hi ? sw[7] : wd[5]),
                (int)(hi ? wd[6] : sw[4]), (int)(hi ? wd[7] : sw[5]) };
    // ---- PV ----
    #pragma unroll
    for (int n = 0; n < 2; n++) {
      const int d = n * 32 + l31;
      const int fd = (d >> 1) & 3;
      bf16x8 v0 = *(const bf16x8*)&Vt[buf][d * 32 + ((hi ^ fd) * 8)];
      bf16x8 v1 = *(const bf16x8*)&Vt[buf][d * 32 + (((2 | hi) ^ fd) * 8)];
      oacc[n] = mfma_bf16(__builtin_bit_cast(bf16x8, f0), v0, oacc[n]);
      oacc[n] = mfma_bf16(__builtin_bit_cast(bf16x8, f1), v1, oacc[n]);
    }
    __builtin_amdgcn_s_barrier();
  }

  // ---- epilogue: divide by l, split to tiled bf16 hi/lo ----
  l += __shfl_xor(l, 32);
  const float linv = 1.f / l;
  float lr[16];
  #pragma unroll
  for (int r = 0; r < 16; r++)
    lr[r] = __shfl(linv, (r & 3) + 8 * (r >> 2) + 4 * hi);
  #pragma unroll
  for (int r = 0; r < 16; r++) {
    const int qg = qb * 128 + w * 32 + (r & 3) + 8 * (r >> 2) + 4 * hi;
    const int grow = b * N_ + qg;
    short h0, l0, h1, l1;
    split2(oacc[0][r] * lr[r], h0, l0);
    split2(oacc[1][r] * lr[r], h1, l1);
    const long o0 = tiled_off(grow, h * HD_ + l31);
    const long o1 = tiled_off(grow, h * HD_ + l31 + 32);
    ohi[o0] = h0;  olo[o0] = l0;
    ohi[o1] = h1;  olo[o1] = l1;
  }
}

// =====================================================================
// inst_feat: mask @ embed -> tiled bf16 (hi only; feeds plain-bf16 ik)
// =====================================================================
__global__ __launch_bounds__(256) void instfeat_split(
    const float* __restrict__ mask, const float* __restrict__ emb,
    short* __restrict__ ofh)
{
  const long idx = (long)blockIdx.x * 256 + threadIdx.x;
  const int  d4  = (int)(idx & (D_ / 4 - 1));
  const long bn  = idx >> 8;
  const float* mk = mask + bn * NI_;
  float4 acc = {0.f, 0.f, 0.f, 0.f};
  #pragma unroll
  for (int i = 0; i < NI_; i++) {
    const float mm = mk[i];
    const float4 e = *(const float4*)&emb[(long)i * D_ + d4 * 4];
    acc.x = fmaf(mm, e.x, acc.x);
    acc.y = fmaf(mm, e.y, acc.y);
    acc.z = fmaf(mm, e.z, acc.z);
    acc.w = fmaf(mm, e.w, acc.w);
  }
  short h[4];
  h[0] = bf16_rn(acc.x);  h[1] = bf16_rn(acc.y);
  h[2] = bf16_rn(acc.z);  h[3] = bf16_rn(acc.w);
  *(s16x4*)&ofh[tiled_off((int)bn, d4 * 4)] = *(s16x4*)h;
}

// =====================================================================
extern "C" void kernel_launch(void* const* d_in, const int* in_sizes, int n_in,
                              void* d_out, int out_size, void* d_ws, size_t ws_size,
                              hipStream_t stream)
{
  const float* x    = (const float*)d_in[0];
  const float* mask = (const float*)d_in[1];
  const float* Wq   = (const float*)d_in[2];
  const float* bq   = (const float*)d_in[3];
  const float* Wk   = (const float*)d_in[4];
  const float* bk   = (const float*)d_in[5];
  const float* Wv   = (const float*)d_in[6];
  const float* bv   = (const float*)d_in[7];
  const float* Wo   = (const float*)d_in[8];
  const float* bo   = (const float*)d_in[9];
  const float* Wiq  = (const float*)d_in[10];
  const float* biq  = (const float*)d_in[11];
  const float* Wik  = (const float*)d_in[12];
  const float* bik  = (const float*)d_in[13];
  const float* emb  = (const float*)d_in[14];
  const float* qnw  = (const float*)d_in[15];
  const float* knw  = (const float*)d_in[16];
  float* out = (float*)d_out;

  float* ws = (float*)d_ws;
  const size_t SZ = (size_t)BN_ * D_;
  float* qbuf = ws;                     // fp32 q (attn reads)
  float* kbuf = qbuf + SZ;              // fp32 k (kvprep reads)
  float* vbuf = kbuf + SZ;              // fp32 v (kvprep reads)
  short* ohi  = (short*)(vbuf + SZ);    // attn split output (tiled)
  short* olo  = ohi + SZ;
  short* xhi  = (short*)(ws + 4 * SZ);  // x split; dead after QKV ->
  short* xlo  = xhi + SZ;               //   reused as Knb / Vtb
  short* Knb  = xhi;                    // [2][16][2048][64] bf16
  short* Vtb  = xlo;                    // [2][16][64][64][32] bf16
  short* Wbig_hi = (short*)(ws + 5 * SZ);
  short* Wbig_lo = Wbig_hi + (size_t)3 * D_ * D_;
  float* part = (float*)(Wbig_lo + (size_t)3 * D_ * D_);  // [BN][8]
  short* iqh = (short*)qbuf;            // aliases (post-attention)
  short* ifh = (short*)kbuf;
  short* ikh = (short*)vbuf;
  short* Wsl_hi = Wbig_hi;
  short* Wsl_lo = Wbig_hi + (size_t)D_ * D_;

  const dim3 blk(256);

  // 1) weight prep + x split
  wsplit3<<<dim3(16, 16, 3), blk, 0, stream>>>(Wq, Wk, Wv, Wbig_hi, Wbig_lo);
  asplit<<<(BN_ * D_ / 4) / 256, blk, 0, stream>>>(x, xhi, xlo);

  // 2) fused QKV projection (split, 3-MFMA)
  mfgemm2<0, 1><<<dim3(8, 32, 3), blk, 0, stream>>>(
      xhi, xlo, Wbig_hi, Wbig_lo, bq, bk, bv,
      qbuf, nullptr, nullptr, 0, 8, (long)SZ, nullptr, nullptr);

  // 3) KV prep (norm K, transpose V, bf16, swizzled; group-indexed)
  kvprep<<<dim3(KVLEN / 32, H_, 2), blk, 0, stream>>>(kbuf, vbuf, knw, Knb, Vtb);

  // 4) attention -> tiled split bf16 output
  attn2<<<dim3(N_ / 128, H_, B_), blk, 0, stream>>>(qbuf, Knb, Vtb, qnw, ohi, olo);

  // 5) IQ = o@Wiq+biq, plain bf16 (gate path)
  wsplitT<0><<<dim3(16, 16), blk, 0, stream>>>(Wiq, Wsl_hi, nullptr);
  mfgemm2<1, 0><<<dim3(8, 32, 1), blk, 0, stream>>>(
      ohi, nullptr, Wsl_hi, nullptr, biq, nullptr, nullptr,
      nullptr, iqh, nullptr, 0, 0, 0, nullptr, nullptr);

  // 6) inst_feat (hi only)
  instfeat_split<<<(BN_ * D_ / 4) / 256, blk, 0, stream>>>(mask, emb, ifh);

  // 7) IK = inst_feat@Wik+bik, plain bf16
  wsplitT<0><<<dim3(16, 16), blk, 0, stream>>>(Wik, Wsl_hi, nullptr);
  mfgemm2<1, 0><<<dim3(8, 32, 1), blk, 0, stream>>>(
      ifh, nullptr, Wsl_hi, nullptr, bik, nullptr, nullptr,
      nullptr, ikh, nullptr, 0, 0, 0, nullptr, nullptr);

  // 8) gate partials: plain bf16, FULL K per block (see MODE 3 note)
  mfgemm2<3, 0><<<dim3(4, 4, 8), blk, 0, stream>>>(
      iqh, nullptr, ikh, nullptr, nullptr, nullptr, nullptr,
      nullptr, nullptr, nullptr, 4, 4, 0, nullptr, part);

  // 9) final: gate(row)*(o@Wo) + bo -> d_out (split, 3-MFMA)
  wsplitT<1><<<dim3(16, 16), blk, 0, stream>>>(Wo, Wsl_hi, Wsl_lo);
  mfgemm2<2, 1><<<dim3(8, 32, 1), blk, 0, stream>>>(
      ohi, olo, Wsl_hi, Wsl_lo, bo, nullptr, nullptr,
      out, nullptr, nullptr, 0, 0, 0, part, nullptr);
}

// Round 11
// 290.356 us; speedup vs baseline: 2.0568x; 1.0426x over previous
//
#include <hip/hip_runtime.h>
#include <cmath>

// Problem constants (fixed by the reference file)
#define B_   8
#define N_   512
#define D_   1024
#define H_   16
#define HD_  64
#define NI_  4
#define BN_  (B_*N_)      // 4096 rows when [B,N,*] is flattened
#define KVLEN (NI_*N_)    // 2048 keys per attention group

typedef __attribute__((ext_vector_type(8)))  short  bf16x8;   // 8 bf16 bit patterns
typedef __attribute__((ext_vector_type(8)))  __bf16 bf16x8_t; // builtin operand type
typedef __attribute__((ext_vector_type(16))) float  f32x16;
typedef __attribute__((ext_vector_type(4)))  short  s16x4;

// round-to-nearest-even bf16 conversion (bit trick)
__device__ __forceinline__ short bf16_rn(float x) {
  unsigned u = __float_as_uint(x);
  unsigned r = (u + 0x7FFFu + ((u >> 16) & 1u)) >> 16;
  return (short)r;
}

// RN hi/lo split: x = hi + lo + eps, |eps| <~ 2^-18 |x|.
__device__ __forceinline__ void split2(float x, short& hi, short& lo) {
  hi = bf16_rn(x);
  float h = __uint_as_float(((unsigned)(unsigned short)hi) << 16);
  float r = x - h;              // exact (Dekker-style split)
  lo = bf16_rn(r);
}

__device__ __forceinline__ f32x16 mfma_bf16(bf16x8 a, bf16x8 b, f32x16 c) {
  return __builtin_amdgcn_mfma_f32_32x32x16_bf16(
      __builtin_bit_cast(bf16x8_t, a), __builtin_bit_cast(bf16x8_t, b), c, 0, 0, 0);
}

#define GLOAD16(gp, lp) __builtin_amdgcn_global_load_lds( \
  (const __attribute__((address_space(1))) unsigned*)(gp), \
  (__attribute__((address_space(3))) unsigned*)(lp), 16, 0, 0)

// TILED-SPLIT layout for all bf16 GEMM operands (K = 1024):
// addr(row,k) = (((row>>7)*128 + (k>>3))*128 + (row&127))*8 + (k&7).
// GEMM staging is then a LINEAR copy -> fully coalesced global_load_lds.
__device__ __forceinline__ long tiled_off(int row, int k) {
  return ((((long)(row >> 7) * 128 + (k >> 3)) * 128 + (row & 127)) * 8 + (k & 7));
}

// =====================================================================
// Fused 3-weight transpose+split for Wq/Wk/Wv -> [3072][1024] tiled.
// =====================================================================
__global__ __launch_bounds__(256) void wsplit3(
    const float* __restrict__ W0, const float* __restrict__ W1,
    const float* __restrict__ W2, short* __restrict__ Thi,
    short* __restrict__ Tlo)
{
  __shared__ float tile[64][65];
  const int z = blockIdx.z;
  const float* W = (z == 0) ? W0 : (z == 1) ? W1 : W2;
  const int t  = threadIdx.x;
  const int kb = blockIdx.y * 64;
  const int cb = blockIdx.x * 64;
  const int r0 = t >> 4;
  const int c4 = t & 15;
  #pragma unroll
  for (int i = 0; i < 4; i++) {
    const int r = r0 + i * 16;
    *(float4*)&tile[r][c4 * 4] = *(const float4*)&W[(long)(kb + r) * D_ + cb + c4 * 4];
  }
  __syncthreads();
  #pragma unroll
  for (int i = 0; i < 4; i++) {
    const int c = r0 + i * 16;
    short hi[4], lo[4];
    #pragma unroll
    for (int e = 0; e < 4; e++)
      split2(tile[c4 * 4 + e][c], hi[e], lo[e]);
    const long o = tiled_off(z * D_ + cb + c, kb + c4 * 4);
    *(s16x4*)&Thi[o] = *(s16x4*)hi;
    *(s16x4*)&Tlo[o] = *(s16x4*)lo;
  }
}

// =====================================================================
// Gate/final weight prep in ONE dispatch: z=0 Wiq->hi, z=1 Wik->hi,
// z=2 Wo->hi+lo. (Runs after the QKV GEMM frees the Wbig slots.)
// =====================================================================
__global__ __launch_bounds__(256) void wsplitG(
    const float* __restrict__ Wiq, const float* __restrict__ Wik,
    const float* __restrict__ Wo, short* __restrict__ WiqH,
    short* __restrict__ WikH, short* __restrict__ WoH,
    short* __restrict__ WoL)
{
  __shared__ float tile[64][65];
  const int z = blockIdx.z;
  const float* W = (z == 0) ? Wiq : (z == 1) ? Wik : Wo;
  const int t  = threadIdx.x;
  const int kb = blockIdx.y * 64;
  const int cb = blockIdx.x * 64;
  const int r0 = t >> 4;
  const int c4 = t & 15;
  #pragma unroll
  for (int i = 0; i < 4; i++) {
    const int r = r0 + i * 16;
    *(float4*)&tile[r][c4 * 4] = *(const float4*)&W[(long)(kb + r) * D_ + cb + c4 * 4];
  }
  __syncthreads();
  #pragma unroll
  for (int i = 0; i < 4; i++) {
    const int c = r0 + i * 16;
    short hi[4], lo[4];
    #pragma unroll
    for (int e = 0; e < 4; e++)
      split2(tile[c4 * 4 + e][c], hi[e], lo[e]);
    const long o = tiled_off(cb + c, kb + c4 * 4);
    if (z == 0) {
      *(s16x4*)&WiqH[o] = *(s16x4*)hi;
    } else if (z == 1) {
      *(s16x4*)&WikH[o] = *(s16x4*)hi;
    } else {
      *(s16x4*)&WoH[o] = *(s16x4*)hi;
      *(s16x4*)&WoL[o] = *(s16x4*)lo;
    }
  }
}

// =====================================================================
// Elementwise fp32 -> tiled-split hi/lo bf16 (for x).
// =====================================================================
__global__ __launch_bounds__(256) void asplit(const float* __restrict__ in,
                                              short* __restrict__ hi,
                                              short* __restrict__ lo)
{
  const long i4 = ((long)blockIdx.x * 256 + threadIdx.x) * 4;
  const int row = (int)(i4 >> 10);
  const int kk  = (int)(i4 & 1023);
  float4 v = *(const float4*)&in[i4];
  short h[4], l[4];
  split2(v.x, h[0], l[0]);
  split2(v.y, h[1], l[1]);
  split2(v.z, h[2], l[2]);
  split2(v.w, h[3], l[3]);
  const long o = tiled_off(row, kk);
  *(s16x4*)&hi[o] = *(s16x4*)h;
  *(s16x4*)&lo[o] = *(s16x4*)l;
}

// =====================================================================
// MFMA GEMM v3. Tiled bf16 operands, linear global_load_lds staging,
// double-buffered LDS, counted vmcnt.
// SPLIT=1: hi/lo split inputs (3 MFMAs/pair); wave w stages operand w
//          (Ahi,Alo,Bhi,Blo), vmcnt(8).
// SPLIT=0: plain bf16 (1 MFMA/pair); waves 0,1 stage A halves,
//          waves 2,3 stage B halves, vmcnt(4). (gate path only: errors
//          attenuated by sigmoid'/4 and the /512 mean -> <1e-6 in gate.)
// MODE 0: C[bz*sC + row*D + col] = A@B + bias(bz)     (QKV fused)
// MODE 2: C = gate(row)*(A@B) + bias, gate = 1 + sum8(part_in[row])/512
// MODE 3: part_out[(bz*N+row)*8 + bx*2 + wc] = per-wave 64-col partial
//         row sum of sigmoid(acc*SCALE/H).  FULL K per block — sigmoid
//         sits between the K-reduction and the m-sum, K-split is
//         algebraically invalid (round-8 lesson).
// MODE 4: DUAL plain GEMM -> bf16 tiled out: bz=0: Chi=Ahi@Bhi+b0;
//         bz=1: Clo=Alo@Blo+b1   (iq & ik in one dispatch, 2 blocks/CU)
// =====================================================================
template<int MODE, int SPLIT>
__global__ __launch_bounds__(256) void mfgemm2(
    const short* __restrict__ Ahi, const short* __restrict__ Alo,
    const short* __restrict__ Bhi, const short* __restrict__ Blo,
    const float* __restrict__ b0, const float* __restrict__ b1,
    const float* __restrict__ b2,
    float* __restrict__ C, short* __restrict__ Chi, short* __restrict__ Clo,
    int aBlk, int bBlk, long sC,
    const float* __restrict__ part_in, float* __restrict__ part_out)
{
  constexpr int NOPS = SPLIT ? 4 : 2;
  __shared__ short lds[2][NOPS][4096];
  const int t = threadIdx.x, w = t >> 6, lane = t & 63;
  const int bx = blockIdx.x, by = blockIdx.y, bz = blockIdx.z;
  const int rowBase = by * 128;
  const int colBase = bx * 128;
  const long aoff = (long)(bz * aBlk + by) * 131072;   // 128 oct * 128 rows * 8
  const long boff = (long)(bz * bBlk + bx) * 131072;

  const short* Abase = (MODE == 4 && bz) ? Alo : Ahi;
  const short* Bbase = (MODE == 4 && bz) ? Blo : Bhi;

  const short* mySrc;
  int op, half;
  if (SPLIT) {
    op = w; half = 0;
    mySrc = (w == 0) ? Ahi + aoff : (w == 1) ? Alo + aoff
          : (w == 2) ? Bhi + boff : Blo + boff;
  } else {
    op = w >> 1; half = w & 1;
    mySrc = op ? Bbase + boff : Abase + aoff;
  }

  auto stage = [&](int buf, int tt) {
    if (SPLIT) {
      const short* g = mySrc + ((long)tt * 512 + lane) * 8;
      #pragma unroll
      for (int i = 0; i < 8; i++)
        GLOAD16(g + i * 512, &lds[buf][op][i * 512]);
    } else {
      const short* g = mySrc + ((long)tt * 512 + half * 256 + lane) * 8;
      #pragma unroll
      for (int i = 0; i < 4; i++)
        GLOAD16(g + i * 512, &lds[buf][op][(half * 256 + i * 64) * 8]);
    }
  };

  const int wr = w >> 1, wc = w & 1;
  const int lrow = lane & 31, lk = lane >> 5;

  f32x16 acc[2][2] = {};

  auto compute = [&](int buf) {
    #pragma unroll
    for (int kh = 0; kh < 2; kh++) {
      const int kq = 2 * kh + lk;
      bf16x8 ah[2], bh[2];
      #pragma unroll
      for (int m = 0; m < 2; m++)
        ah[m] = *(const bf16x8*)&lds[buf][0][(kq * 128 + wr * 64 + m * 32 + lrow) * 8];
      #pragma unroll
      for (int n = 0; n < 2; n++)
        bh[n] = *(const bf16x8*)&lds[buf][SPLIT ? 2 : 1][(kq * 128 + wc * 64 + n * 32 + lrow) * 8];
      if (SPLIT) {
        bf16x8 al[2], bl[2];
        #pragma unroll
        for (int m = 0; m < 2; m++)
          al[m] = *(const bf16x8*)&lds[buf][1][(kq * 128 + wr * 64 + m * 32 + lrow) * 8];
        #pragma unroll
        for (int n = 0; n < 2; n++)
          bl[n] = *(const bf16x8*)&lds[buf][3][(kq * 128 + wc * 64 + n * 32 + lrow) * 8];
        #pragma unroll
        for (int m = 0; m < 2; m++)
          #pragma unroll
          for (int n = 0; n < 2; n++) {
            acc[m][n] = mfma_bf16(al[m], bh[n], acc[m][n]);
            acc[m][n] = mfma_bf16(ah[m], bl[n], acc[m][n]);
            acc[m][n] = mfma_bf16(ah[m], bh[n], acc[m][n]);
          }
      } else {
        #pragma unroll
        for (int m = 0; m < 2; m++)
          #pragma unroll
          for (int n = 0; n < 2; n++)
            acc[m][n] = mfma_bf16(ah[m], bh[n], acc[m][n]);
      }
    }
  };

  const int NT = 32;   // K=1024 / BK=32 (always full K — see MODE 3 note)
  stage(0, 0);
  for (int tt = 0; tt < NT - 1; ++tt) {
    stage((tt + 1) & 1, tt + 1);
    if (SPLIT) asm volatile("s_waitcnt vmcnt(8)" ::: "memory");
    else       asm volatile("s_waitcnt vmcnt(4)" ::: "memory");
    __builtin_amdgcn_s_barrier();
    __builtin_amdgcn_sched_barrier(0);
    compute(tt & 1);
    __builtin_amdgcn_s_barrier();
  }
  asm volatile("s_waitcnt vmcnt(0)" ::: "memory");
  __builtin_amdgcn_s_barrier();
  __builtin_amdgcn_sched_barrier(0);
  compute((NT - 1) & 1);

  // ---------------- epilogue ----------------
  if (MODE == 3) {
    const float sc = 0.125f / 16.f;   // SCALE/H
    #pragma unroll
    for (int m = 0; m < 2; m++)
      #pragma unroll
      for (int r = 0; r < 16; r++) {
        const int row = rowBase + wr * 64 + m * 32 + (r & 3) + 8 * (r >> 2) + 4 * lk;
        float v = 1.f / (1.f + __expf(-acc[m][0][r] * sc))
                + 1.f / (1.f + __expf(-acc[m][1][r] * sc));
        v += __shfl_xor(v, 1);  v += __shfl_xor(v, 2);  v += __shfl_xor(v, 4);
        v += __shfl_xor(v, 8);  v += __shfl_xor(v, 16);
        if (lrow == 0)
          part_out[(long)(bz * N_ + row) * 8 + bx * 2 + wc] = v;
      }
    return;
  }

  const float* bias = (bz == 1) ? b1 : (bz == 2) ? b2 : b0;
  float bcol[2];
  #pragma unroll
  for (int n = 0; n < 2; n++)
    bcol[n] = bias[colBase + wc * 64 + n * 32 + lrow];

  float* Cb = C + (long)bz * sC;
  short* Cdst = (MODE == 4 && bz) ? Clo : Chi;

  #pragma unroll
  for (int m = 0; m < 2; m++) {
    #pragma unroll
    for (int r = 0; r < 16; r++) {
      const int row = rowBase + wr * 64 + m * 32 + (r & 3) + 8 * (r >> 2) + 4 * lk;
      float g = 1.f;
      if (MODE == 2) {
        const float4 p0 = *(const float4*)&part_in[(long)row * 8];
        const float4 p1 = *(const float4*)&part_in[(long)row * 8 + 4];
        g = 1.f + (p0.x + p0.y + p0.z + p0.w + p1.x + p1.y + p1.z + p1.w)
                  * (1.f / 512.f);
      }
      #pragma unroll
      for (int n = 0; n < 2; n++) {
        const int col = colBase + wc * 64 + n * 32 + lrow;
        const float val = acc[m][n][r] * g + bcol[n];
        if (MODE == 4) {
          Cdst[tiled_off(row, col)] = bf16_rn(val);
        } else {
          Cb[(long)row * D_ + col] = val;
        }
      }
    }
  }
}

// =====================================================================
// KV prep: K RMSNorm->bf16 swizzled [g][h][m][64]; V transposed bf16
// tiles [g][h][tile][d][32kv], chunk-swizzled. Both linear per 4KB tile
// for coalesced global_load_lds in attention.
// =====================================================================
__global__ __launch_bounds__(256) void kvprep(
    const float* __restrict__ kf, const float* __restrict__ vf,
    const float* __restrict__ knw, short* __restrict__ Knb,
    short* __restrict__ Vtb)
{
  const int tile = blockIdx.x, h = blockIdx.y, g = blockIdx.z;
  const int t = threadIdx.x;
  // ---- K ----
  const int skv = t >> 3, sg = t & 7;
  const int m  = tile * 32 + skv;
  const int bb = g * NI_ + (m >> 9), nn = m & (N_ - 1);
  const float* kp = kf + ((long)(bb * N_ + nn)) * D_ + h * HD_ + sg * 8;
  float k8[8];
  *(float4*)&k8[0] = *(const float4*)&kp[0];
  *(float4*)&k8[4] = *(const float4*)&kp[4];
  float ks2 = 0.f;
  #pragma unroll
  for (int j = 0; j < 8; j++) ks2 += k8[j] * k8[j];
  ks2 += __shfl_xor(ks2, 1);
  ks2 += __shfl_xor(ks2, 2);
  ks2 += __shfl_xor(ks2, 4);
  const float kr = rsqrtf(ks2 * (1.f / 64.f) + 1e-6f);
  bf16x8 kb;
  #pragma unroll
  for (int j = 0; j < 8; j++) kb[j] = bf16_rn(k8[j] * kr * knw[sg * 8 + j]);
  *(bf16x8*)&Knb[((long)(g * H_ + h) * KVLEN + m) * 64 + ((sg ^ (m & 7)) * 8)] = kb;
  // ---- V ----
  const int vkv = t & 31, vg = t >> 5;
  const int m2  = tile * 32 + vkv;
  const int bb2 = g * NI_ + (m2 >> 9), nn2 = m2 & (N_ - 1);
  const float* vp = vf + ((long)(bb2 * N_ + nn2)) * D_ + h * HD_ + vg * 8;
  float v8[8];
  *(float4*)&v8[0] = *(const float4*)&vp[0];
  *(float4*)&v8[4] = *(const float4*)&vp[4];
  const long vbase = ((long)(g * H_ + h) * 64 + tile) * 2048;
  #pragma unroll
  for (int e = 0; e < 8; e++) {
    const int d = vg * 8 + e;
    Vtb[vbase + d * 32 + (((vkv >> 3) ^ ((d >> 1) & 3)) * 8) + (vkv & 7)] = bf16_rn(v8[e]);
  }
}

// =====================================================================
// MFMA grouped flash attention v3 — KV-SPLIT x2 (flash-decoding).
// grid (N/128, H, B*2); bz = b*2 + s; half s covers kv [s*1024,(s+1)*1024).
// The STATIC softmax max (-8) makes partials combine exactly:
// o = o0+o1, l = l0+l1 (no max reconciliation). Partial o (fp32) and l
// go to workspace; attn_reduce divides and emits tiled split bf16.
// 1024 blocks -> 4 waves/SIMD (vs 2): hides the softmax VALU chain.
// =====================================================================
__global__ __launch_bounds__(256) void attn3(
    const float* __restrict__ q, const short* __restrict__ Knb,
    const short* __restrict__ Vtb, const float* __restrict__ qnw,
    float* __restrict__ opart, float* __restrict__ lpart)
{
  const int bz = blockIdx.z, h = blockIdx.y, qb = blockIdx.x;
  const int b  = bz >> 1, s = bz & 1;
  const int g  = b >> 2;
  const int t  = threadIdx.x;
  const int w  = t >> 6;
  const int lane = t & 63;
  const int l31 = lane & 31, hi = lane >> 5;

  __shared__ short Kt[2][2048];
  __shared__ short Vt[2][2048];

  // ---- Q: load + RMSNorm + B-operand frags ----
  const int qrow = qb * 128 + w * 32 + l31;
  const float* qp = q + ((long)b * N_ + qrow) * D_ + h * HD_ + hi * 8;
  float qv[4][8];
  float ss = 0.f;
  #pragma unroll
  for (int c = 0; c < 4; c++) {
    *(float4*)&qv[c][0] = *(const float4*)&qp[c * 16];
    *(float4*)&qv[c][4] = *(const float4*)&qp[c * 16 + 4];
    #pragma unroll
    for (int j = 0; j < 8; j++) ss += qv[c][j] * qv[c][j];
  }
  ss += __shfl_xor(ss, 32);
  const float qr = rsqrtf(ss * (1.f / 64.f) + 1e-6f);
  bf16x8 qf[4];
  #pragma unroll
  for (int c = 0; c < 4; c++)
    #pragma unroll
    for (int j = 0; j < 8; j++)
      qf[c][j] = bf16_rn(qv[c][j] * qr * qnw[c * 16 + hi * 8 + j]);

  const short* Kg = Knb + (long)(g * H_ + h) * KVLEN * 64 + (long)s * 32 * 2048;
  const short* Vg = Vtb + (long)(g * H_ + h) * 64 * 2048 + (long)s * 32 * 2048;

  auto stage = [&](int buf, int i) {
    GLOAD16(Kg + (long)i * 2048 + t * 8, &Kt[buf][w * 512]);
    GLOAD16(Vg + (long)i * 2048 + t * 8, &Vt[buf][w * 512]);
  };

  f32x16 oacc[2] = {};
  float l = 0.f;

  stage(0, 0);
  for (int i = 0; i < 32; ++i) {
    const int buf = i & 1;
    if (i + 1 < 32) {
      stage(buf ^ 1, i + 1);
      asm volatile("s_waitcnt vmcnt(2)" ::: "memory");
    } else {
      asm volatile("s_waitcnt vmcnt(0)" ::: "memory");
    }
    __builtin_amdgcn_s_barrier();
    __builtin_amdgcn_sched_barrier(0);

    // ---- QK^T: scores[kv][q] ----
    f32x16 sc = {};
    #pragma unroll
    for (int c = 0; c < 4; c++) {
      bf16x8 kfr = *(const bf16x8*)&Kt[buf][l31 * 64 + (((2 * c + hi) * 8) ^ ((l31 & 7) << 3))];
      sc = mfma_bf16(kfr, qf[c], sc);
    }
    // ---- softmax, static max: p = exp2(s*0.125*log2e - 8*log2e) ----
    float p[16];
    #pragma unroll
    for (int r = 0; r < 16; r++) {
      p[r] = exp2f(fmaf(sc[r], 0.1803368801111244f, -11.541560327111961f));
      l += p[r];
    }
    // ---- pack P pairs to bf16 (cvt_pk), swap kv halves across lanes ----
    unsigned wd[8], sw[8];
    #pragma unroll
    for (int i2 = 0; i2 < 8; i2++)
      asm("v_cvt_pk_bf16_f32 %0, %1, %2" : "=v"(wd[i2]) : "v"(p[2 * i2]), "v"(p[2 * i2 + 1]));
    #pragma unroll
    for (int i2 = 0; i2 < 8; i2++) sw[i2] = __shfl_xor(wd[i2], 32);
    int4 f0 = { (int)(hi ? sw[2] : wd[0]), (int)(hi ? sw[3] : wd[1]),
                (int)(hi ? wd[2] : sw[0]), (int)(hi ? wd[3] : sw[1]) };
    int4 f1 = { (int)(hi ? sw[6] : wd[4]), (int)(hi ? sw[7] : wd[5]),
                (int)(hi ? wd[6] : sw[4]), (int)(hi ? wd[7] : sw[5]) };
    // ---- PV ----
    #pragma unroll
    for (int n = 0; n < 2; n++) {
      const int d = n * 32 + l31;
      const int fd = (d >> 1) & 3;
      bf16x8 v0 = *(const bf16x8*)&Vt[buf][d * 32 + ((hi ^ fd) * 8)];
      bf16x8 v1 = *(const bf16x8*)&Vt[buf][d * 32 + (((2 | hi) ^ fd) * 8)];
      oacc[n] = mfma_bf16(__builtin_bit_cast(bf16x8, f0), v0, oacc[n]);
      oacc[n] = mfma_bf16(__builtin_bit_cast(bf16x8, f1), v1, oacc[n]);
    }
    __builtin_amdgcn_s_barrier();
  }

  // ---- epilogue: write PARTIAL o (no divide) + l ----
  l += __shfl_xor(l, 32);
  #pragma unroll
  for (int r = 0; r < 16; r++) {
    const int qg = qb * 128 + w * 32 + (r & 3) + 8 * (r >> 2) + 4 * hi;
    float* op = opart + ((long)s * BN_ + b * N_ + qg) * D_ + h * HD_ + l31;
    op[0]  = oacc[0][r];
    op[32] = oacc[1][r];
  }
  if (hi == 0)
    lpart[((long)s * BN_ + b * N_ + qb * 128 + w * 32 + l31) * H_ + h] = l;
}

// =====================================================================
// attn_reduce: o = (o0+o1)/(l0+l1), split2 -> tiled bf16 hi/lo.
// One block per row (256 thr x 4 floats = 1024 cols).
// =====================================================================
__global__ __launch_bounds__(256) void attn_reduce(
    const float* __restrict__ opart, const float* __restrict__ lpart,
    short* __restrict__ ohi, short* __restrict__ olo)
{
  const int row = blockIdx.x;
  const int col = threadIdx.x * 4;
  const int h   = col >> 6;
  const float l = lpart[(long)row * H_ + h] + lpart[((long)BN_ + row) * H_ + h];
  const float inv = 1.f / l;
  float4 a = *(const float4*)&opart[(long)row * D_ + col];
  float4 b = *(const float4*)&opart[((long)BN_ + row) * D_ + col];
  short hh[4], ll[4];
  split2((a.x + b.x) * inv, hh[0], ll[0]);
  split2((a.y + b.y) * inv, hh[1], ll[1]);
  split2((a.z + b.z) * inv, hh[2], ll[2]);
  split2((a.w + b.w) * inv, hh[3], ll[3]);
  const long o = tiled_off(row, col);
  *(s16x4*)&ohi[o] = *(s16x4*)hh;
  *(s16x4*)&olo[o] = *(s16x4*)ll;
}

// =====================================================================
// inst_feat: mask @ embed -> tiled bf16 (hi only; feeds plain-bf16 ik)
// =====================================================================
__global__ __launch_bounds__(256) void instfeat_split(
    const float* __restrict__ mask, const float* __restrict__ emb,
    short* __restrict__ ofh)
{
  const long idx = (long)blockIdx.x * 256 + threadIdx.x;
  const int  d4  = (int)(idx & (D_ / 4 - 1));
  const long bn  = idx >> 8;
  const float* mk = mask + bn * NI_;
  float4 acc = {0.f, 0.f, 0.f, 0.f};
  #pragma unroll
  for (int i = 0; i < NI_; i++) {
    const float mm = mk[i];
    const float4 e = *(const float4*)&emb[(long)i * D_ + d4 * 4];
    acc.x = fmaf(mm, e.x, acc.x);
    acc.y = fmaf(mm, e.y, acc.y);
    acc.z = fmaf(mm, e.z, acc.z);
    acc.w = fmaf(mm, e.w, acc.w);
  }
  short h[4];
  h[0] = bf16_rn(acc.x);  h[1] = bf16_rn(acc.y);
  h[2] = bf16_rn(acc.z);  h[3] = bf16_rn(acc.w);
  *(s16x4*)&ofh[tiled_off((int)bn, d4 * 4)] = *(s16x4*)h;
}

// =====================================================================
extern "C" void kernel_launch(void* const* d_in, const int* in_sizes, int n_in,
                              void* d_out, int out_size, void* d_ws, size_t ws_size,
                              hipStream_t stream)
{
  const float* x    = (const float*)d_in[0];
  const float* mask = (const float*)d_in[1];
  const float* Wq   = (const float*)d_in[2];
  const float* bq   = (const float*)d_in[3];
  const float* Wk   = (const float*)d_in[4];
  const float* bk   = (const float*)d_in[5];
  const float* Wv   = (const float*)d_in[6];
  const float* bv   = (const float*)d_in[7];
  const float* Wo   = (const float*)d_in[8];
  const float* bo   = (const float*)d_in[9];
  const float* Wiq  = (const float*)d_in[10];
  const float* biq  = (const float*)d_in[11];
  const float* Wik  = (const float*)d_in[12];
  const float* bik  = (const float*)d_in[13];
  const float* emb  = (const float*)d_in[14];
  const float* qnw  = (const float*)d_in[15];
  const float* knw  = (const float*)d_in[16];
  float* out = (float*)d_out;

  // Workspace layout — ROUND-10 LESSON: appending part/lpart at the END
  // of ws grew the footprint past the (round-9-proven) safe size; the
  // lpart tail landed out-of-bounds and clobbered adjacent allocations
  // (inputs) AFTER they were consumed -> first call validated clean,
  // every replay read corrupted inputs. Fix: part/lpart now live INSIDE
  // the dead interior of Wbig_lo (Wk/Wv lo-planes, dead after the QKV
  // GEMM; wsplitG only writes WoL = Wbig_lo[0:D*D]). Total footprint is
  // now strictly below the round-9-proven bound.
  float* ws = (float*)d_ws;
  const size_t SZ = (size_t)BN_ * D_;
  float* qbuf = ws;                     // fp32 q (attn reads)
  float* kbuf = qbuf + SZ;              // fp32 k -> opart[0] after kvprep
  float* vbuf = kbuf + SZ;              // fp32 v -> opart[1] after kvprep
  float* opart = kbuf;                  // [2][BN][D] fp32 attn partials
  short* ohi  = (short*)(vbuf + SZ);    // attn output (tiled split bf16)
  short* olo  = ohi + SZ;
  short* xhi  = (short*)(ws + 4 * SZ);  // x split; dead after QKV ->
  short* xlo  = xhi + SZ;               //   reused as Knb / Vtb
  short* Knb  = xhi;                    // [2][16][2048][64] bf16
  short* Vtb  = xlo;                    // [2][16][64][64][32] bf16
  short* Wbig_hi = (short*)(ws + 5 * SZ);
  short* Wbig_lo = Wbig_hi + (size_t)3 * D_ * D_;
  // part/lpart inside Wbig_lo[D*D : 3*D*D] (dead after QKV GEMM):
  float* part  = (float*)(Wbig_lo + (size_t)D_ * D_);      // [BN][8]
  float* lpart = part + (size_t)BN_ * 8;                   // [2][BN][16]
  short* iqh = (short*)qbuf;            // aliases (post-attention)
  short* ifh = (short*)kbuf;            //   (post-reduce)
  short* ikh = (short*)vbuf;
  short* WiqH = Wbig_hi;                // after QKV GEMM frees Wbig
  short* WikH = Wbig_hi + (size_t)D_ * D_;
  short* WoH  = Wbig_hi + (size_t)2 * D_ * D_;
  short* WoL  = Wbig_lo;                // Wbig_lo[0:D*D] only

  const dim3 blk(256);

  // 1) QKV weight prep + x split
  wsplit3<<<dim3(16, 16, 3), blk, 0, stream>>>(Wq, Wk, Wv, Wbig_hi, Wbig_lo);
  asplit<<<(BN_ * D_ / 4) / 256, blk, 0, stream>>>(x, xhi, xlo);

  // 2) fused QKV projection (split, 3-MFMA)
  mfgemm2<0, 1><<<dim3(8, 32, 3), blk, 0, stream>>>(
      xhi, xlo, Wbig_hi, Wbig_lo, bq, bk, bv,
      qbuf, nullptr, nullptr, 0, 8, (long)SZ, nullptr, nullptr);

  // 3) KV prep (norm K, transpose V, bf16, swizzled; group-indexed)
  kvprep<<<dim3(KVLEN / 32, H_, 2), blk, 0, stream>>>(kbuf, vbuf, knw, Knb, Vtb);

  // 4) attention, KV-split x2 -> fp32 partials (over dead kbuf/vbuf);
  //    lpart goes into the dead Wbig_lo interior (in-bounds).
  attn3<<<dim3(N_ / 128, H_, B_ * 2), blk, 0, stream>>>(
      qbuf, Knb, Vtb, qnw, opart, lpart);

  // 5) gate/final weight prep (Wbig_hi + Wbig_lo[0:D*D] now free)
  wsplitG<<<dim3(16, 16, 3), blk, 0, stream>>>(Wiq, Wik, Wo, WiqH, WikH, WoH, WoL);

  // 6) combine partials -> tiled split bf16 o
  attn_reduce<<<BN_, blk, 0, stream>>>(opart, lpart, ohi, olo);

  // 7) inst_feat (over kbuf, free after reduce)
  instfeat_split<<<(BN_ * D_ / 4) / 256, blk, 0, stream>>>(mask, emb, ifh);

  // 8) DUAL iq & ik GEMM (plain bf16), one dispatch, 2 blocks/CU
  mfgemm2<4, 0><<<dim3(8, 32, 2), blk, 0, stream>>>(
      ohi, ifh, WiqH, WikH, biq, bik, nullptr,
      nullptr, iqh, ikh, 0, 0, 0, nullptr, nullptr);

  // 9) gate partials: plain bf16, FULL K per block
  mfgemm2<3, 0><<<dim3(4, 4, 8), blk, 0, stream>>>(
      iqh, nullptr, ikh, nullptr, nullptr, nullptr, nullptr,
      nullptr, nullptr, nullptr, 4, 4, 0, nullptr, part);

  // 10) final: gate(row)*(o@Wo) + bo -> d_out (split, 3-MFMA)
  mfgemm2<2, 1><<<dim3(8, 32, 1), blk, 0, stream>>>(
      ohi, olo, WoH, WoL, bo, nullptr, nullptr,
      out, nullptr, nullptr, 0, 0, 0, part, nullptr);
}

// Round 12
// 263.175 us; speedup vs baseline: 2.2693x; 1.1033x over previous
//
#include <hip/hip_runtime.h>
#include <cmath>

// Problem constants (fixed by the reference file)
#define B_   8
#define N_   512
#define D_   1024
#define H_   16
#define HD_  64
#define NI_  4
#define BN_  (B_*N_)      // 4096 rows when [B,N,*] is flattened
#define KVLEN (NI_*N_)    // 2048 keys per attention group

typedef __attribute__((ext_vector_type(8)))  short  bf16x8;   // 8 bf16 bit patterns
typedef __attribute__((ext_vector_type(8)))  __bf16 bf16x8_t; // builtin operand type
typedef __attribute__((ext_vector_type(16))) float  f32x16;
typedef __attribute__((ext_vector_type(4)))  short  s16x4;

// round-to-nearest-even bf16 conversion (bit trick)
__device__ __forceinline__ short bf16_rn(float x) {
  unsigned u = __float_as_uint(x);
  unsigned r = (u + 0x7FFFu + ((u >> 16) & 1u)) >> 16;
  return (short)r;
}

// RN hi/lo split: x = hi + lo + eps, |eps| <~ 2^-18 |x|.
__device__ __forceinline__ void split2(float x, short& hi, short& lo) {
  hi = bf16_rn(x);
  float h = __uint_as_float(((unsigned)(unsigned short)hi) << 16);
  float r = x - h;              // exact (Dekker-style split)
  lo = bf16_rn(r);
}

__device__ __forceinline__ f32x16 mfma_bf16(bf16x8 a, bf16x8 b, f32x16 c) {
  return __builtin_amdgcn_mfma_f32_32x32x16_bf16(
      __builtin_bit_cast(bf16x8_t, a), __builtin_bit_cast(bf16x8_t, b), c, 0, 0, 0);
}

#define GLOAD16(gp, lp) __builtin_amdgcn_global_load_lds( \
  (const __attribute__((address_space(1))) unsigned*)(gp), \
  (__attribute__((address_space(3))) unsigned*)(lp), 16, 0, 0)

// TILED-SPLIT layout for all bf16 GEMM operands (K = 1024):
// addr(row,k) = (((row>>7)*128 + (k>>3))*128 + (row&127))*8 + (k&7).
// GEMM staging is then a LINEAR copy -> fully coalesced global_load_lds.
__device__ __forceinline__ long tiled_off(int row, int k) {
  return ((((long)(row >> 7) * 128 + (k >> 3)) * 128 + (row & 127)) * 8 + (k & 7));
}

// T1 XCD-aware block swizzle (MI355X: 8 XCDs, private L2s). Default
// dispatch round-robins consecutive blockIdx across XCDs, so the 8
// blocks sharing an A-panel land on 8 different L2s (round-11: 183MB
// FETCH vs 29MB unique). Remap so each XCD gets a CONTIGUOUS tile
// range. REQUIRES nwg % 8 == 0 (all grids here are).
__device__ __forceinline__ void xcd_swizzle(int& bx, int& by, int& bz) {
  const int gx = gridDim.x, gy = gridDim.y;
  const int nwg = gx * gy * gridDim.z;
  const int lin = blockIdx.x + gx * (blockIdx.y + gy * blockIdx.z);
  const int swz = (lin & 7) * (nwg >> 3) + (lin >> 3);
  bx = swz % gx;
  const int rest = swz / gx;
  by = rest % gy;
  bz = rest / gy;
}

// =====================================================================
// Fused 3-weight transpose+split for Wq/Wk/Wv -> [3072][1024] tiled.
// WLO=0: hi plane only (QKV GEMM is 2-MFMA now; W-lo unused).
// =====================================================================
template<int WLO>
__global__ __launch_bounds__(256) void wsplit3(
    const float* __restrict__ W0, const float* __restrict__ W1,
    const float* __restrict__ W2, short* __restrict__ Thi,
    short* __restrict__ Tlo)
{
  __shared__ float tile[64][65];
  const int z = blockIdx.z;
  const float* W = (z == 0) ? W0 : (z == 1) ? W1 : W2;
  const int t  = threadIdx.x;
  const int kb = blockIdx.y * 64;
  const int cb = blockIdx.x * 64;
  const int r0 = t >> 4;
  const int c4 = t & 15;
  #pragma unroll
  for (int i = 0; i < 4; i++) {
    const int r = r0 + i * 16;
    *(float4*)&tile[r][c4 * 4] = *(const float4*)&W[(long)(kb + r) * D_ + cb + c4 * 4];
  }
  __syncthreads();
  #pragma unroll
  for (int i = 0; i < 4; i++) {
    const int c = r0 + i * 16;
    short hi[4], lo[4];
    #pragma unroll
    for (int e = 0; e < 4; e++)
      split2(tile[c4 * 4 + e][c], hi[e], lo[e]);
    const long o = tiled_off(z * D_ + cb + c, kb + c4 * 4);
    *(s16x4*)&Thi[o] = *(s16x4*)hi;
    if (WLO) *(s16x4*)&Tlo[o] = *(s16x4*)lo;
  }
}

// =====================================================================
// Gate/final weight prep in ONE dispatch: z=0 Wiq->hi, z=1 Wik->hi,
// z=2 Wo->hi+lo. (Runs after the QKV GEMM frees the Wbig slots.)
// =====================================================================
__global__ __launch_bounds__(256) void wsplitG(
    const float* __restrict__ Wiq, const float* __restrict__ Wik,
    const float* __restrict__ Wo, short* __restrict__ WiqH,
    short* __restrict__ WikH, short* __restrict__ WoH,
    short* __restrict__ WoL)
{
  __shared__ float tile[64][65];
  const int z = blockIdx.z;
  const float* W = (z == 0) ? Wiq : (z == 1) ? Wik : Wo;
  const int t  = threadIdx.x;
  const int kb = blockIdx.y * 64;
  const int cb = blockIdx.x * 64;
  const int r0 = t >> 4;
  const int c4 = t & 15;
  #pragma unroll
  for (int i = 0; i < 4; i++) {
    const int r = r0 + i * 16;
    *(float4*)&tile[r][c4 * 4] = *(const float4*)&W[(long)(kb + r) * D_ + cb + c4 * 4];
  }
  __syncthreads();
  #pragma unroll
  for (int i = 0; i < 4; i++) {
    const int c = r0 + i * 16;
    short hi[4], lo[4];
    #pragma unroll
    for (int e = 0; e < 4; e++)
      split2(tile[c4 * 4 + e][c], hi[e], lo[e]);
    const long o = tiled_off(cb + c, kb + c4 * 4);
    if (z == 0) {
      *(s16x4*)&WiqH[o] = *(s16x4*)hi;
    } else if (z == 1) {
      *(s16x4*)&WikH[o] = *(s16x4*)hi;
    } else {
      *(s16x4*)&WoH[o] = *(s16x4*)hi;
      *(s16x4*)&WoL[o] = *(s16x4*)lo;
    }
  }
}

// =====================================================================
// Elementwise fp32 -> tiled-split hi/lo bf16 (for x).
// =====================================================================
__global__ __launch_bounds__(256) void asplit(const float* __restrict__ in,
                                              short* __restrict__ hi,
                                              short* __restrict__ lo)
{
  const long i4 = ((long)blockIdx.x * 256 + threadIdx.x) * 4;
  const int row = (int)(i4 >> 10);
  const int kk  = (int)(i4 & 1023);
  float4 v = *(const float4*)&in[i4];
  short h[4], l[4];
  split2(v.x, h[0], l[0]);
  split2(v.y, h[1], l[1]);
  split2(v.z, h[2], l[2]);
  split2(v.w, h[3], l[3]);
  const long o = tiled_off(row, kk);
  *(s16x4*)&hi[o] = *(s16x4*)h;
  *(s16x4*)&lo[o] = *(s16x4*)l;
}

// =====================================================================
// MFMA GEMM v4. Tiled bf16 operands, linear global_load_lds staging,
// double-buffered LDS, counted vmcnt, XCD-swizzled block mapping.
// SPLIT=1: A,B both hi/lo (3 MFMAs/pair); wave w stages operand w,
//          vmcnt(8). 64 KB LDS.
// SPLIT=2: A hi/lo, B hi-only (2 MFMAs/pair: Al*Bh + Ah*Bh — W-lo
//          rounding error ~= the bf16 rounding q/k/v get later anyway);
//          waves 0-2 stage {Ahi,Alo,Bhi}, wave 3 idle, vmcnt(8).
//          48 KB LDS -> 3 blocks/CU.
// SPLIT=0: plain bf16 (1 MFMA/pair); waves 0,1 stage A halves, waves
//          2,3 stage B halves, vmcnt(4). (gate path: errors attenuated
//          by sigmoid'/4 and the /512 mean -> <1e-6 in gate.)
// MODE 0: C[bz*sC + row*D + col] = A@B + bias(bz)     (QKV fused)
// MODE 2: C = gate(row)*(A@B) + bias, gate = 1 + sum8(part_in[row])/512
// MODE 3: part_out[(bz*N+row)*8 + bx*2 + wc] = per-wave 64-col partial
//         row sum of sigmoid(acc*SCALE/H).  FULL K per block — sigmoid
//         sits between the K-reduction and the m-sum, K-split is
//         algebraically invalid (round-8 lesson).
// MODE 4: DUAL plain GEMM -> bf16 tiled out: bz=0: Chi=Ahi@Bhi+b0;
//         bz=1: Clo=Alo@Blo+b1   (iq & ik in one dispatch)
// =====================================================================
template<int MODE, int SPLIT>
__global__ __launch_bounds__(256) void mfgemm2(
    const short* __restrict__ Ahi, const short* __restrict__ Alo,
    const short* __restrict__ Bhi, const short* __restrict__ Blo,
    const float* __restrict__ b0, const float* __restrict__ b1,
    const float* __restrict__ b2,
    float* __restrict__ C, short* __restrict__ Chi, short* __restrict__ Clo,
    int aBlk, int bBlk, long sC,
    const float* __restrict__ part_in, float* __restrict__ part_out)
{
  constexpr int NOPS = (SPLIT == 1) ? 4 : (SPLIT == 2) ? 3 : 2;
  __shared__ short lds[2][NOPS][4096];
  const int t = threadIdx.x, w = t >> 6, lane = t & 63;
  int bx, by, bz;
  xcd_swizzle(bx, by, bz);
  const int rowBase = by * 128;
  const int colBase = bx * 128;
  const long aoff = (long)(bz * aBlk + by) * 131072;   // 128 oct * 128 rows * 8
  const long boff = (long)(bz * bBlk + bx) * 131072;

  const short* Abase = (MODE == 4 && bz) ? Alo : Ahi;
  const short* Bbase = (MODE == 4 && bz) ? Blo : Bhi;

  const short* mySrc;
  int op, half;
  if (SPLIT == 1) {
    op = w; half = 0;
    mySrc = (w == 0) ? Ahi + aoff : (w == 1) ? Alo + aoff
          : (w == 2) ? Bhi + boff : Blo + boff;
  } else if (SPLIT == 2) {
    op = (w < 3) ? w : 0; half = 0;
    mySrc = (w == 0) ? Ahi + aoff : (w == 1) ? Alo + aoff : Bhi + boff;
  } else {
    op = w >> 1; half = w & 1;
    mySrc = op ? Bbase + boff : Abase + aoff;
  }

  auto stage = [&](int buf, int tt) {
    if (SPLIT) {
      if (SPLIT == 2 && w == 3) return;   // 3 operands, wave 3 idle
      const short* g = mySrc + ((long)tt * 512 + lane) * 8;
      #pragma unroll
      for (int i = 0; i < 8; i++)
        GLOAD16(g + i * 512, &lds[buf][op][i * 512]);
    } else {
      const short* g = mySrc + ((long)tt * 512 + half * 256 + lane) * 8;
      #pragma unroll
      for (int i = 0; i < 4; i++)
        GLOAD16(g + i * 512, &lds[buf][op][(half * 256 + i * 64) * 8]);
    }
  };

  const int wr = w >> 1, wc = w & 1;
  const int lrow = lane & 31, lk = lane >> 5;

  f32x16 acc[2][2] = {};

  auto compute = [&](int buf) {
    #pragma unroll
    for (int kh = 0; kh < 2; kh++) {
      const int kq = 2 * kh + lk;
      bf16x8 ah[2], bh[2];
      #pragma unroll
      for (int m = 0; m < 2; m++)
        ah[m] = *(const bf16x8*)&lds[buf][0][(kq * 128 + wr * 64 + m * 32 + lrow) * 8];
      #pragma unroll
      for (int n = 0; n < 2; n++)
        bh[n] = *(const bf16x8*)&lds[buf][SPLIT ? 2 : 1][(kq * 128 + wc * 64 + n * 32 + lrow) * 8];
      if (SPLIT == 1) {
        bf16x8 al[2], bl[2];
        #pragma unroll
        for (int m = 0; m < 2; m++)
          al[m] = *(const bf16x8*)&lds[buf][1][(kq * 128 + wr * 64 + m * 32 + lrow) * 8];
        #pragma unroll
        for (int n = 0; n < 2; n++)
          bl[n] = *(const bf16x8*)&lds[buf][3][(kq * 128 + wc * 64 + n * 32 + lrow) * 8];
        #pragma unroll
        for (int m = 0; m < 2; m++)
          #pragma unroll
          for (int n = 0; n < 2; n++) {
            acc[m][n] = mfma_bf16(al[m], bh[n], acc[m][n]);
            acc[m][n] = mfma_bf16(ah[m], bl[n], acc[m][n]);
            acc[m][n] = mfma_bf16(ah[m], bh[n], acc[m][n]);
          }
      } else if (SPLIT == 2) {
        bf16x8 al[2];
        #pragma unroll
        for (int m = 0; m < 2; m++)
          al[m] = *(const bf16x8*)&lds[buf][1][(kq * 128 + wr * 64 + m * 32 + lrow) * 8];
        #pragma unroll
        for (int m = 0; m < 2; m++)
          #pragma unroll
          for (int n = 0; n < 2; n++) {
            acc[m][n] = mfma_bf16(al[m], bh[n], acc[m][n]);
            acc[m][n] = mfma_bf16(ah[m], bh[n], acc[m][n]);
          }
      } else {
        #pragma unroll
        for (int m = 0; m < 2; m++)
          #pragma unroll
          for (int n = 0; n < 2; n++)
            acc[m][n] = mfma_bf16(ah[m], bh[n], acc[m][n]);
      }
    }
  };

  const int NT = 32;   // K=1024 / BK=32 (always full K — see MODE 3 note)
  stage(0, 0);
  for (int tt = 0; tt < NT - 1; ++tt) {
    stage((tt + 1) & 1, tt + 1);
    if (SPLIT) asm volatile("s_waitcnt vmcnt(8)" ::: "memory");
    else       asm volatile("s_waitcnt vmcnt(4)" ::: "memory");
    __builtin_amdgcn_s_barrier();
    __builtin_amdgcn_sched_barrier(0);
    compute(tt & 1);
    __builtin_amdgcn_s_barrier();
  }
  asm volatile("s_waitcnt vmcnt(0)" ::: "memory");
  __builtin_amdgcn_s_barrier();
  __builtin_amdgcn_sched_barrier(0);
  compute((NT - 1) & 1);

  // ---------------- epilogue ----------------
  if (MODE == 3) {
    const float sc = 0.125f / 16.f;   // SCALE/H
    #pragma unroll
    for (int m = 0; m < 2; m++)
      #pragma unroll
      for (int r = 0; r < 16; r++) {
        const int row = rowBase + wr * 64 + m * 32 + (r & 3) + 8 * (r >> 2) + 4 * lk;
        float v = 1.f / (1.f + __expf(-acc[m][0][r] * sc))
                + 1.f / (1.f + __expf(-acc[m][1][r] * sc));
        v += __shfl_xor(v, 1);  v += __shfl_xor(v, 2);  v += __shfl_xor(v, 4);
        v += __shfl_xor(v, 8);  v += __shfl_xor(v, 16);
        if (lrow == 0)
          part_out[(long)(bz * N_ + row) * 8 + bx * 2 + wc] = v;
      }
    return;
  }

  const float* bias = (bz == 1) ? b1 : (bz == 2) ? b2 : b0;
  float bcol[2];
  #pragma unroll
  for (int n = 0; n < 2; n++)
    bcol[n] = bias[colBase + wc * 64 + n * 32 + lrow];

  float* Cb = C + (long)bz * sC;
  short* Cdst = (MODE == 4 && bz) ? Clo : Chi;

  #pragma unroll
  for (int m = 0; m < 2; m++) {
    #pragma unroll
    for (int r = 0; r < 16; r++) {
      const int row = rowBase + wr * 64 + m * 32 + (r & 3) + 8 * (r >> 2) + 4 * lk;
      float g = 1.f;
      if (MODE == 2) {
        const float4 p0 = *(const float4*)&part_in[(long)row * 8];
        const float4 p1 = *(const float4*)&part_in[(long)row * 8 + 4];
        g = 1.f + (p0.x + p0.y + p0.z + p0.w + p1.x + p1.y + p1.z + p1.w)
                  * (1.f / 512.f);
      }
      #pragma unroll
      for (int n = 0; n < 2; n++) {
        const int col = colBase + wc * 64 + n * 32 + lrow;
        const float val = acc[m][n][r] * g + bcol[n];
        if (MODE == 4) {
          Cdst[tiled_off(row, col)] = bf16_rn(val);
        } else {
          Cb[(long)row * D_ + col] = val;
        }
      }
    }
  }
}

// =====================================================================
// KV prep: K RMSNorm->bf16 swizzled [g][h][m][64]; V transposed bf16
// tiles [g][h][tile][d][32kv], chunk-swizzled. Both linear per 4KB tile
// for coalesced global_load_lds in attention.
// =====================================================================
__global__ __launch_bounds__(256) void kvprep(
    const float* __restrict__ kf, const float* __restrict__ vf,
    const float* __restrict__ knw, short* __restrict__ Knb,
    short* __restrict__ Vtb)
{
  const int tile = blockIdx.x, h = blockIdx.y, g = blockIdx.z;
  const int t = threadIdx.x;
  // ---- K ----
  const int skv = t >> 3, sg = t & 7;
  const int m  = tile * 32 + skv;
  const int bb = g * NI_ + (m >> 9), nn = m & (N_ - 1);
  const float* kp = kf + ((long)(bb * N_ + nn)) * D_ + h * HD_ + sg * 8;
  float k8[8];
  *(float4*)&k8[0] = *(const float4*)&kp[0];
  *(float4*)&k8[4] = *(const float4*)&kp[4];
  float ks2 = 0.f;
  #pragma unroll
  for (int j = 0; j < 8; j++) ks2 += k8[j] * k8[j];
  ks2 += __shfl_xor(ks2, 1);
  ks2 += __shfl_xor(ks2, 2);
  ks2 += __shfl_xor(ks2, 4);
  const float kr = rsqrtf(ks2 * (1.f / 64.f) + 1e-6f);
  bf16x8 kb;
  #pragma unroll
  for (int j = 0; j < 8; j++) kb[j] = bf16_rn(k8[j] * kr * knw[sg * 8 + j]);
  *(bf16x8*)&Knb[((long)(g * H_ + h) * KVLEN + m) * 64 + ((sg ^ (m & 7)) * 8)] = kb;
  // ---- V ----
  const int vkv = t & 31, vg = t >> 5;
  const int m2  = tile * 32 + vkv;
  const int bb2 = g * NI_ + (m2 >> 9), nn2 = m2 & (N_ - 1);
  const float* vp = vf + ((long)(bb2 * N_ + nn2)) * D_ + h * HD_ + vg * 8;
  float v8[8];
  *(float4*)&v8[0] = *(const float4*)&vp[0];
  *(float4*)&v8[4] = *(const float4*)&vp[4];
  const long vbase = ((long)(g * H_ + h) * 64 + tile) * 2048;
  #pragma unroll
  for (int e = 0; e < 8; e++) {
    const int d = vg * 8 + e;
    Vtb[vbase + d * 32 + (((vkv >> 3) ^ ((d >> 1) & 3)) * 8) + (vkv & 7)] = bf16_rn(v8[e]);
  }
}

// =====================================================================
// MFMA grouped flash attention v3 — KV-SPLIT x2 (flash-decoding),
// XCD-swizzled block mapping (same-XCD blocks share K/V L2 lines).
// grid (N/128, H, B*2); bz = b*2 + s; half s covers kv [s*1024,(s+1)*1024).
// The STATIC softmax max (-8) makes partials combine exactly:
// o = o0+o1, l = l0+l1. Partials to workspace; attn_reduce finishes.
// =====================================================================
__global__ __launch_bounds__(256) void attn3(
    const float* __restrict__ q, const short* __restrict__ Knb,
    const short* __restrict__ Vtb, const float* __restrict__ qnw,
    float* __restrict__ opart, float* __restrict__ lpart)
{
  int qb, h, bz;
  xcd_swizzle(qb, h, bz);
  const int b  = bz >> 1, s = bz & 1;
  const int g  = b >> 2;
  const int t  = threadIdx.x;
  const int w  = t >> 6;
  const int lane = t & 63;
  const int l31 = lane & 31, hi = lane >> 5;

  __shared__ short Kt[2][2048];
  __shared__ short Vt[2][2048];

  // ---- Q: load + RMSNorm + B-operand frags ----
  const int qrow = qb * 128 + w * 32 + l31;
  const float* qp = q + ((long)b * N_ + qrow) * D_ + h * HD_ + hi * 8;
  float qv[4][8];
  float ss = 0.f;
  #pragma unroll
  for (int c = 0; c < 4; c++) {
    *(float4*)&qv[c][0] = *(const float4*)&qp[c * 16];
    *(float4*)&qv[c][4] = *(const float4*)&qp[c * 16 + 4];
    #pragma unroll
    for (int j = 0; j < 8; j++) ss += qv[c][j] * qv[c][j];
  }
  ss += __shfl_xor(ss, 32);
  const float qr = rsqrtf(ss * (1.f / 64.f) + 1e-6f);
  bf16x8 qf[4];
  #pragma unroll
  for (int c = 0; c < 4; c++)
    #pragma unroll
    for (int j = 0; j < 8; j++)
      qf[c][j] = bf16_rn(qv[c][j] * qr * qnw[c * 16 + hi * 8 + j]);

  const short* Kg = Knb + (long)(g * H_ + h) * KVLEN * 64 + (long)s * 32 * 2048;
  const short* Vg = Vtb + (long)(g * H_ + h) * 64 * 2048 + (long)s * 32 * 2048;

  auto stage = [&](int buf, int i) {
    GLOAD16(Kg + (long)i * 2048 + t * 8, &Kt[buf][w * 512]);
    GLOAD16(Vg + (long)i * 2048 + t * 8, &Vt[buf][w * 512]);
  };

  f32x16 oacc[2] = {};
  float l = 0.f;

  stage(0, 0);
  for (int i = 0; i < 32; ++i) {
    const int buf = i & 1;
    if (i + 1 < 32) {
      stage(buf ^ 1, i + 1);
      asm volatile("s_waitcnt vmcnt(2)" ::: "memory");
    } else {
      asm volatile("s_waitcnt vmcnt(0)" ::: "memory");
    }
    __builtin_amdgcn_s_barrier();
    __builtin_amdgcn_sched_barrier(0);

    // ---- QK^T: scores[kv][q] ----
    f32x16 sc = {};
    #pragma unroll
    for (int c = 0; c < 4; c++) {
      bf16x8 kfr = *(const bf16x8*)&Kt[buf][l31 * 64 + (((2 * c + hi) * 8) ^ ((l31 & 7) << 3))];
      sc = mfma_bf16(kfr, qf[c], sc);
    }
    // ---- softmax, static max: p = exp2(s*0.125*log2e - 8*log2e) ----
    float p[16];
    #pragma unroll
    for (int r = 0; r < 16; r++) {
      p[r] = exp2f(fmaf(sc[r], 0.1803368801111244f, -11.541560327111961f));
      l += p[r];
    }
    // ---- pack P pairs to bf16 (cvt_pk), swap kv halves across lanes ----
    unsigned wd[8], sw[8];
    #pragma unroll
    for (int i2 = 0; i2 < 8; i2++)
      asm("v_cvt_pk_bf16_f32 %0, %1, %2" : "=v"(wd[i2]) : "v"(p[2 * i2]), "v"(p[2 * i2 + 1]));
    #pragma unroll
    for (int i2 = 0; i2 < 8; i2++) sw[i2] = __shfl_xor(wd[i2], 32);
    int4 f0 = { (int)(hi ? sw[2] : wd[0]), (int)(hi ? sw[3] : wd[1]),
                (int)(hi ? wd[2] : sw[0]), (int)(hi ? wd[3] : sw[1]) };
    int4 f1 = { (int)(hi ? sw[6] : wd[4]), (int)(hi ? sw[7] : wd[5]),
                (int)(hi ? wd[6] : sw[4]), (int)(hi ? wd[7] : sw[5]) };
    // ---- PV ----
    #pragma unroll
    for (int n = 0; n < 2; n++) {
      const int d = n * 32 + l31;
      const int fd = (d >> 1) & 3;
      bf16x8 v0 = *(const bf16x8*)&Vt[buf][d * 32 + ((hi ^ fd) * 8)];
      bf16x8 v1 = *(const bf16x8*)&Vt[buf][d * 32 + (((2 | hi) ^ fd) * 8)];
      oacc[n] = mfma_bf16(__builtin_bit_cast(bf16x8, f0), v0, oacc[n]);
      oacc[n] = mfma_bf16(__builtin_bit_cast(bf16x8, f1), v1, oacc[n]);
    }
    __builtin_amdgcn_s_barrier();
  }

  // ---- epilogue: write PARTIAL o (no divide) + l ----
  l += __shfl_xor(l, 32);
  #pragma unroll
  for (int r = 0; r < 16; r++) {
    const int qg = qb * 128 + w * 32 + (r & 3) + 8 * (r >> 2) + 4 * hi;
    float* op = opart + ((long)s * BN_ + b * N_ + qg) * D_ + h * HD_ + l31;
    op[0]  = oacc[0][r];
    op[32] = oacc[1][r];
  }
  if (hi == 0)
    lpart[((long)s * BN_ + b * N_ + qb * 128 + w * 32 + l31) * H_ + h] = l;
}

// =====================================================================
// attn_reduce: o = (o0+o1)/(l0+l1), split2 -> tiled bf16 hi/lo.
// One block per row (256 thr x 4 floats = 1024 cols).
// =====================================================================
__global__ __launch_bounds__(256) void attn_reduce(
    const float* __restrict__ opart, const float* __restrict__ lpart,
    short* __restrict__ ohi, short* __restrict__ olo)
{
  const int row = blockIdx.x;
  const int col = threadIdx.x * 4;
  const int h   = col >> 6;
  const float l = lpart[(long)row * H_ + h] + lpart[((long)BN_ + row) * H_ + h];
  const float inv = 1.f / l;
  float4 a = *(const float4*)&opart[(long)row * D_ + col];
  float4 b = *(const float4*)&opart[((long)BN_ + row) * D_ + col];
  short hh[4], ll[4];
  split2((a.x + b.x) * inv, hh[0], ll[0]);
  split2((a.y + b.y) * inv, hh[1], ll[1]);
  split2((a.z + b.z) * inv, hh[2], ll[2]);
  split2((a.w + b.w) * inv, hh[3], ll[3]);
  const long o = tiled_off(row, col);
  *(s16x4*)&ohi[o] = *(s16x4*)hh;
  *(s16x4*)&olo[o] = *(s16x4*)ll;
}

// =====================================================================
// inst_feat: mask @ embed -> tiled bf16 (hi only; feeds plain-bf16 ik)
// =====================================================================
__global__ __launch_bounds__(256) void instfeat_split(
    const float* __restrict__ mask, const float* __restrict__ emb,
    short* __restrict__ ofh)
{
  const long idx = (long)blockIdx.x * 256 + threadIdx.x;
  const int  d4  = (int)(idx & (D_ / 4 - 1));
  const long bn  = idx >> 8;
  const float* mk = mask + bn * NI_;
  float4 acc = {0.f, 0.f, 0.f, 0.f};
  #pragma unroll
  for (int i = 0; i < NI_; i++) {
    const float mm = mk[i];
    const float4 e = *(const float4*)&emb[(long)i * D_ + d4 * 4];
    acc.x = fmaf(mm, e.x, acc.x);
    acc.y = fmaf(mm, e.y, acc.y);
    acc.z = fmaf(mm, e.z, acc.z);
    acc.w = fmaf(mm, e.w, acc.w);
  }
  short h[4];
  h[0] = bf16_rn(acc.x);  h[1] = bf16_rn(acc.y);
  h[2] = bf16_rn(acc.z);  h[3] = bf16_rn(acc.w);
  *(s16x4*)&ofh[tiled_off((int)bn, d4 * 4)] = *(s16x4*)h;
}

// =====================================================================
extern "C" void kernel_launch(void* const* d_in, const int* in_sizes, int n_in,
                              void* d_out, int out_size, void* d_ws, size_t ws_size,
                              hipStream_t stream)
{
  const float* x    = (const float*)d_in[0];
  const float* mask = (const float*)d_in[1];
  const float* Wq   = (const float*)d_in[2];
  const float* bq   = (const float*)d_in[3];
  const float* Wk   = (const float*)d_in[4];
  const float* bk   = (const float*)d_in[5];
  const float* Wv   = (const float*)d_in[6];
  const float* bv   = (const float*)d_in[7];
  const float* Wo   = (const float*)d_in[8];
  const float* bo   = (const float*)d_in[9];
  const float* Wiq  = (const float*)d_in[10];
  const float* biq  = (const float*)d_in[11];
  const float* Wik  = (const float*)d_in[12];
  const float* bik  = (const float*)d_in[13];
  const float* emb  = (const float*)d_in[14];
  const float* qnw  = (const float*)d_in[15];
  const float* knw  = (const float*)d_in[16];
  float* out = (float*)d_out;

  // Workspace layout (round-10 lesson: stay within the proven footprint;
  // part/lpart live in the dead interior of Wbig_lo — now entirely dead
  // since wsplit3 emits hi-only).
  float* ws = (float*)d_ws;
  const size_t SZ = (size_t)BN_ * D_;
  float* qbuf = ws;                     // fp32 q (attn reads)
  float* kbuf = qbuf + SZ;              // fp32 k -> opart[0] after kvprep
  float* vbuf = kbuf + SZ;              // fp32 v -> opart[1] after kvprep
  float* opart = kbuf;                  // [2][BN][D] fp32 attn partials
  short* ohi  = (short*)(vbuf + SZ);    // attn output (tiled split bf16)
  short* olo  = ohi + SZ;
  short* xhi  = (short*)(ws + 4 * SZ);  // x split; dead after QKV ->
  short* xlo  = xhi + SZ;               //   reused as Knb / Vtb
  short* Knb  = xhi;                    // [2][16][2048][64] bf16
  short* Vtb  = xlo;                    // [2][16][64][64][32] bf16
  short* Wbig_hi = (short*)(ws + 5 * SZ);
  short* Wbig_lo = Wbig_hi + (size_t)3 * D_ * D_;
  float* part  = (float*)(Wbig_lo + (size_t)D_ * D_);      // [BN][8]
  float* lpart = part + (size_t)BN_ * 8;                   // [2][BN][16]
  short* iqh = (short*)qbuf;            // aliases (post-attention)
  short* ifh = (short*)kbuf;            //   (post-reduce)
  short* ikh = (short*)vbuf;
  short* WiqH = Wbig_hi;                // after QKV GEMM frees Wbig
  short* WikH = Wbig_hi + (size_t)D_ * D_;
  short* WoH  = Wbig_hi + (size_t)2 * D_ * D_;
  short* WoL  = Wbig_lo;                // Wbig_lo[0:D*D] only

  const dim3 blk(256);

  // 1) QKV weight prep (hi only — 2-MFMA scheme) + x split
  wsplit3<0><<<dim3(16, 16, 3), blk, 0, stream>>>(Wq, Wk, Wv, Wbig_hi, nullptr);
  asplit<<<(BN_ * D_ / 4) / 256, blk, 0, stream>>>(x, xhi, xlo);

  // 2) fused QKV projection (SPLIT=2: x split, W hi-only, 2 MFMAs)
  mfgemm2<0, 2><<<dim3(8, 32, 3), blk, 0, stream>>>(
      xhi, xlo, Wbig_hi, nullptr, bq, bk, bv,
      qbuf, nullptr, nullptr, 0, 8, (long)SZ, nullptr, nullptr);

  // 3) KV prep (norm K, transpose V, bf16, swizzled; group-indexed)
  kvprep<<<dim3(KVLEN / 32, H_, 2), blk, 0, stream>>>(kbuf, vbuf, knw, Knb, Vtb);

  // 4) attention, KV-split x2 -> fp32 partials (over dead kbuf/vbuf)
  attn3<<<dim3(N_ / 128, H_, B_ * 2), blk, 0, stream>>>(
      qbuf, Knb, Vtb, qnw, opart, lpart);

  // 5) gate/final weight prep (Wbig now free)
  wsplitG<<<dim3(16, 16, 3), blk, 0, stream>>>(Wiq, Wik, Wo, WiqH, WikH, WoH, WoL);

  // 6) combine partials -> tiled split bf16 o
  attn_reduce<<<BN_, blk, 0, stream>>>(opart, lpart, ohi, olo);

  // 7) inst_feat (over kbuf, free after reduce)
  instfeat_split<<<(BN_ * D_ / 4) / 256, blk, 0, stream>>>(mask, emb, ifh);

  // 8) DUAL iq & ik GEMM (plain bf16), one dispatch
  mfgemm2<4, 0><<<dim3(8, 32, 2), blk, 0, stream>>>(
      ohi, ifh, WiqH, WikH, biq, bik, nullptr,
      nullptr, iqh, ikh, 0, 0, 0, nullptr, nullptr);

  // 9) gate partials: plain bf16, FULL K per block
  mfgemm2<3, 0><<<dim3(4, 4, 8), blk, 0, stream>>>(
      iqh, nullptr, ikh, nullptr, nullptr, nullptr, nullptr,
      nullptr, nullptr, nullptr, 4, 4, 0, nullptr, part);

  // 10) final: gate(row)*(o@Wo) + bo -> d_out (split, 3-MFMA)
  mfgemm2<2, 1><<<dim3(8, 32, 1), blk, 0, stream>>>(
      ohi, olo, WoH, WoL, bo, nullptr, nullptr,
      out, nullptr, nullptr, 0, 0, 0, part, nullptr);
}

// Round 13
// 243.622 us; speedup vs baseline: 2.4514x; 1.0803x over previous
//
#include <hip/hip_runtime.h>
#include <cmath>

// Problem constants (fixed by the reference file)
#define B_   8
#define N_   512
#define D_   1024
#define H_   16
#define HD_  64
#define NI_  4
#define BN_  (B_*N_)      // 4096 rows when [B,N,*] is flattened
#define KVLEN (NI_*N_)    // 2048 keys per attention group

typedef __attribute__((ext_vector_type(8)))  short  bf16x8;   // 8 bf16 bit patterns
typedef __attribute__((ext_vector_type(8)))  __bf16 bf16x8_t; // builtin operand type
typedef __attribute__((ext_vector_type(16))) float  f32x16;
typedef __attribute__((ext_vector_type(4)))  short  s16x4;
typedef __attribute__((ext_vector_type(2)))  unsigned u32x2;

// round-to-nearest-even bf16 conversion (bit trick)
__device__ __forceinline__ short bf16_rn(float x) {
  unsigned u = __float_as_uint(x);
  unsigned r = (u + 0x7FFFu + ((u >> 16) & 1u)) >> 16;
  return (short)r;
}

// RN hi/lo split: x = hi + lo + eps, |eps| <~ 2^-18 |x|.
__device__ __forceinline__ void split2(float x, short& hi, short& lo) {
  hi = bf16_rn(x);
  float h = __uint_as_float(((unsigned)(unsigned short)hi) << 16);
  float r = x - h;              // exact (Dekker-style split)
  lo = bf16_rn(r);
}

__device__ __forceinline__ f32x16 mfma_bf16(bf16x8 a, bf16x8 b, f32x16 c) {
  return __builtin_amdgcn_mfma_f32_32x32x16_bf16(
      __builtin_bit_cast(bf16x8_t, a), __builtin_bit_cast(bf16x8_t, b), c, 0, 0, 0);
}

#define GLOAD16(gp, lp) __builtin_amdgcn_global_load_lds( \
  (const __attribute__((address_space(1))) unsigned*)(gp), \
  (__attribute__((address_space(3))) unsigned*)(lp), 16, 0, 0)

// TILED-SPLIT layout for all bf16 GEMM operands (K = 1024):
// addr(row,k) = (((row>>7)*128 + (k>>3))*128 + (row&127))*8 + (k&7).
// GEMM staging is then a LINEAR copy -> fully coalesced global_load_lds.
__device__ __forceinline__ long tiled_off(int row, int k) {
  return ((((long)(row >> 7) * 128 + (k >> 3)) * 128 + (row & 127)) * 8 + (k & 7));
}

// T1 XCD-aware block swizzle (MI355X: 8 XCDs, private L2s). Default
// dispatch round-robins consecutive blockIdx across XCDs; remap so each
// XCD gets a CONTIGUOUS tile range. REQUIRES nwg % 8 == 0 (all grids are).
__device__ __forceinline__ void xcd_swizzle(int& bx, int& by, int& bz) {
  const int gx = gridDim.x, gy = gridDim.y;
  const int nwg = gx * gy * gridDim.z;
  const int lin = blockIdx.x + gx * (blockIdx.y + gy * blockIdx.z);
  const int swz = (lin & 7) * (nwg >> 3) + (lin >> 3);
  bx = swz % gx;
  const int rest = swz / gx;
  by = rest % gy;
  bz = rest / gy;
}

// =====================================================================
// Fused 3-weight transpose+split for Wq/Wk/Wv -> [3072][1024] tiled.
// Hi plane only (QKV GEMM is plain-bf16 now).
// =====================================================================
__global__ __launch_bounds__(256) void wsplit3(
    const float* __restrict__ W0, const float* __restrict__ W1,
    const float* __restrict__ W2, short* __restrict__ Thi)
{
  __shared__ float tile[64][65];
  const int z = blockIdx.z;
  const float* W = (z == 0) ? W0 : (z == 1) ? W1 : W2;
  const int t  = threadIdx.x;
  const int kb = blockIdx.y * 64;
  const int cb = blockIdx.x * 64;
  const int r0 = t >> 4;
  const int c4 = t & 15;
  #pragma unroll
  for (int i = 0; i < 4; i++) {
    const int r = r0 + i * 16;
    *(float4*)&tile[r][c4 * 4] = *(const float4*)&W[(long)(kb + r) * D_ + cb + c4 * 4];
  }
  __syncthreads();
  #pragma unroll
  for (int i = 0; i < 4; i++) {
    const int c = r0 + i * 16;
    short hi[4];
    #pragma unroll
    for (int e = 0; e < 4; e++)
      hi[e] = bf16_rn(tile[c4 * 4 + e][c]);
    *(s16x4*)&Thi[tiled_off(z * D_ + cb + c, kb + c4 * 4)] = *(s16x4*)hi;
  }
}

// =====================================================================
// Gate/final weight prep in ONE dispatch: z=0 Wiq->hi, z=1 Wik->hi,
// z=2 Wo->hi+lo. (Runs after the QKV GEMM frees the Wbig slots.)
// =====================================================================
__global__ __launch_bounds__(256) void wsplitG(
    const float* __restrict__ Wiq, const float* __restrict__ Wik,
    const float* __restrict__ Wo, short* __restrict__ WiqH,
    short* __restrict__ WikH, short* __restrict__ WoH,
    short* __restrict__ WoL)
{
  __shared__ float tile[64][65];
  const int z = blockIdx.z;
  const float* W = (z == 0) ? Wiq : (z == 1) ? Wik : Wo;
  const int t  = threadIdx.x;
  const int kb = blockIdx.y * 64;
  const int cb = blockIdx.x * 64;
  const int r0 = t >> 4;
  const int c4 = t & 15;
  #pragma unroll
  for (int i = 0; i < 4; i++) {
    const int r = r0 + i * 16;
    *(float4*)&tile[r][c4 * 4] = *(const float4*)&W[(long)(kb + r) * D_ + cb + c4 * 4];
  }
  __syncthreads();
  #pragma unroll
  for (int i = 0; i < 4; i++) {
    const int c = r0 + i * 16;
    short hi[4], lo[4];
    #pragma unroll
    for (int e = 0; e < 4; e++)
      split2(tile[c4 * 4 + e][c], hi[e], lo[e]);
    const long o = tiled_off(cb + c, kb + c4 * 4);
    if (z == 0) {
      *(s16x4*)&WiqH[o] = *(s16x4*)hi;
    } else if (z == 1) {
      *(s16x4*)&WikH[o] = *(s16x4*)hi;
    } else {
      *(s16x4*)&WoH[o] = *(s16x4*)hi;
      *(s16x4*)&WoL[o] = *(s16x4*)lo;
    }
  }
}

// =====================================================================
// Elementwise fp32 -> tiled bf16 (hi only — QKV is plain-bf16 now).
// =====================================================================
__global__ __launch_bounds__(256) void asplit(const float* __restrict__ in,
                                              short* __restrict__ hi)
{
  const long i4 = ((long)blockIdx.x * 256 + threadIdx.x) * 4;
  const int row = (int)(i4 >> 10);
  const int kk  = (int)(i4 & 1023);
  float4 v = *(const float4*)&in[i4];
  short h[4];
  h[0] = bf16_rn(v.x);
  h[1] = bf16_rn(v.y);
  h[2] = bf16_rn(v.z);
  h[3] = bf16_rn(v.w);
  *(s16x4*)&hi[tiled_off(row, kk)] = *(s16x4*)h;
}

// =====================================================================
// MFMA GEMM v4. Tiled bf16 operands, linear global_load_lds staging,
// double-buffered LDS, counted vmcnt, XCD-swizzled block mapping.
// SPLIT=1: A,B both hi/lo (3 MFMAs/pair); wave w stages operand w,
//          vmcnt(8). 64 KB LDS.
// SPLIT=0: plain bf16 (1 MFMA/pair); waves 0,1 stage A halves, waves
//          2,3 stage B halves, vmcnt(4). 32 KB LDS. (QKV: q/k/v get
//          bf16-rounded downstream anyway; gate path: errors attenuated
//          by sigmoid'/4 and the /512 mean.)
// MODE 0: C[bz*sC + row*D + col] = A@B + bias(bz)     (QKV fused)
// MODE 2: C = gate(row)*(A@B) + bias, gate = 1 + sum8(part_in[row])/512
// MODE 3: part_out[(bz*N+row)*8 + bx*2 + wc] = per-wave 64-col partial
//         row sum of sigmoid(acc*SCALE/H).  FULL K per block — sigmoid
//         sits between the K-reduction and the m-sum, K-split is
//         algebraically invalid (round-8 lesson).
// MODE 4: DUAL plain GEMM -> bf16 tiled out: bz=0: Chi=Ahi@Bhi+b0;
//         bz=1: Clo=Alo@Blo+b1   (iq & ik in one dispatch)
// =====================================================================
template<int MODE, int SPLIT>
__global__ __launch_bounds__(256) void mfgemm2(
    const short* __restrict__ Ahi, const short* __restrict__ Alo,
    const short* __restrict__ Bhi, const short* __restrict__ Blo,
    const float* __restrict__ b0, const float* __restrict__ b1,
    const float* __restrict__ b2,
    float* __restrict__ C, short* __restrict__ Chi, short* __restrict__ Clo,
    int aBlk, int bBlk, long sC,
    const float* __restrict__ part_in, float* __restrict__ part_out)
{
  constexpr int NOPS = (SPLIT == 1) ? 4 : 2;
  __shared__ short lds[2][NOPS][4096];
  const int t = threadIdx.x, w = t >> 6, lane = t & 63;
  int bx, by, bz;
  xcd_swizzle(bx, by, bz);
  const int rowBase = by * 128;
  const int colBase = bx * 128;
  const long aoff = (long)(bz * aBlk + by) * 131072;   // 128 oct * 128 rows * 8
  const long boff = (long)(bz * bBlk + bx) * 131072;

  const short* Abase = (MODE == 4 && bz) ? Alo : Ahi;
  const short* Bbase = (MODE == 4 && bz) ? Blo : Bhi;

  const short* mySrc;
  int op, half;
  if (SPLIT == 1) {
    op = w; half = 0;
    mySrc = (w == 0) ? Ahi + aoff : (w == 1) ? Alo + aoff
          : (w == 2) ? Bhi + boff : Blo + boff;
  } else {
    op = w >> 1; half = w & 1;
    mySrc = op ? Bbase + boff : Abase + aoff;
  }

  auto stage = [&](int buf, int tt) {
    if (SPLIT == 1) {
      const short* g = mySrc + ((long)tt * 512 + lane) * 8;
      #pragma unroll
      for (int i = 0; i < 8; i++)
        GLOAD16(g + i * 512, &lds[buf][op][i * 512]);
    } else {
      const short* g = mySrc + ((long)tt * 512 + half * 256 + lane) * 8;
      #pragma unroll
      for (int i = 0; i < 4; i++)
        GLOAD16(g + i * 512, &lds[buf][op][(half * 256 + i * 64) * 8]);
    }
  };

  const int wr = w >> 1, wc = w & 1;
  const int lrow = lane & 31, lk = lane >> 5;

  f32x16 acc[2][2] = {};

  auto compute = [&](int buf) {
    #pragma unroll
    for (int kh = 0; kh < 2; kh++) {
      const int kq = 2 * kh + lk;
      bf16x8 ah[2], bh[2];
      #pragma unroll
      for (int m = 0; m < 2; m++)
        ah[m] = *(const bf16x8*)&lds[buf][0][(kq * 128 + wr * 64 + m * 32 + lrow) * 8];
      #pragma unroll
      for (int n = 0; n < 2; n++)
        bh[n] = *(const bf16x8*)&lds[buf][(SPLIT == 1) ? 2 : 1][(kq * 128 + wc * 64 + n * 32 + lrow) * 8];
      if (SPLIT == 1) {
        bf16x8 al[2], bl[2];
        #pragma unroll
        for (int m = 0; m < 2; m++)
          al[m] = *(const bf16x8*)&lds[buf][1][(kq * 128 + wr * 64 + m * 32 + lrow) * 8];
        #pragma unroll
        for (int n = 0; n < 2; n++)
          bl[n] = *(const bf16x8*)&lds[buf][3][(kq * 128 + wc * 64 + n * 32 + lrow) * 8];
        #pragma unroll
        for (int m = 0; m < 2; m++)
          #pragma unroll
          for (int n = 0; n < 2; n++) {
            acc[m][n] = mfma_bf16(al[m], bh[n], acc[m][n]);
            acc[m][n] = mfma_bf16(ah[m], bl[n], acc[m][n]);
            acc[m][n] = mfma_bf16(ah[m], bh[n], acc[m][n]);
          }
      } else {
        #pragma unroll
        for (int m = 0; m < 2; m++)
          #pragma unroll
          for (int n = 0; n < 2; n++)
            acc[m][n] = mfma_bf16(ah[m], bh[n], acc[m][n]);
      }
    }
  };

  const int NT = 32;   // K=1024 / BK=32 (always full K — see MODE 3 note)
  stage(0, 0);
  for (int tt = 0; tt < NT - 1; ++tt) {
    stage((tt + 1) & 1, tt + 1);
    if (SPLIT == 1) asm volatile("s_waitcnt vmcnt(8)" ::: "memory");
    else            asm volatile("s_waitcnt vmcnt(4)" ::: "memory");
    __builtin_amdgcn_s_barrier();
    __builtin_amdgcn_sched_barrier(0);
    compute(tt & 1);
    __builtin_amdgcn_s_barrier();
  }
  asm volatile("s_waitcnt vmcnt(0)" ::: "memory");
  __builtin_amdgcn_s_barrier();
  __builtin_amdgcn_sched_barrier(0);
  compute((NT - 1) & 1);

  // ---------------- epilogue ----------------
  if (MODE == 3) {
    const float sc = 0.125f / 16.f;   // SCALE/H
    #pragma unroll
    for (int m = 0; m < 2; m++)
      #pragma unroll
      for (int r = 0; r < 16; r++) {
        const int row = rowBase + wr * 64 + m * 32 + (r & 3) + 8 * (r >> 2) + 4 * lk;
        float v = 1.f / (1.f + __expf(-acc[m][0][r] * sc))
                + 1.f / (1.f + __expf(-acc[m][1][r] * sc));
        v += __shfl_xor(v, 1);  v += __shfl_xor(v, 2);  v += __shfl_xor(v, 4);
        v += __shfl_xor(v, 8);  v += __shfl_xor(v, 16);
        if (lrow == 0)
          part_out[(long)(bz * N_ + row) * 8 + bx * 2 + wc] = v;
      }
    return;
  }

  const float* bias = (bz == 1) ? b1 : (bz == 2) ? b2 : b0;
  float bcol[2];
  #pragma unroll
  for (int n = 0; n < 2; n++)
    bcol[n] = bias[colBase + wc * 64 + n * 32 + lrow];

  float* Cb = C + (long)bz * sC;
  short* Cdst = (MODE == 4 && bz) ? Clo : Chi;

  #pragma unroll
  for (int m = 0; m < 2; m++) {
    #pragma unroll
    for (int r = 0; r < 16; r++) {
      const int row = rowBase + wr * 64 + m * 32 + (r & 3) + 8 * (r >> 2) + 4 * lk;
      float g = 1.f;
      if (MODE == 2) {
        const float4 p0 = *(const float4*)&part_in[(long)row * 8];
        const float4 p1 = *(const float4*)&part_in[(long)row * 8 + 4];
        g = 1.f + (p0.x + p0.y + p0.z + p0.w + p1.x + p1.y + p1.z + p1.w)
                  * (1.f / 512.f);
      }
      #pragma unroll
      for (int n = 0; n < 2; n++) {
        const int col = colBase + wc * 64 + n * 32 + lrow;
        const float val = acc[m][n][r] * g + bcol[n];
        if (MODE == 4) {
          Cdst[tiled_off(row, col)] = bf16_rn(val);
        } else {
          Cb[(long)row * D_ + col] = val;
        }
      }
    }
  }
}

// =====================================================================
// KV prep: K RMSNorm->bf16 swizzled [g][h][m][64]; V transposed bf16
// tiles [g][h][tile][d][32kv], chunk-swizzled. Both linear per 4KB tile
// for coalesced global_load_lds in attention.
// =====================================================================
__global__ __launch_bounds__(256) void kvprep(
    const float* __restrict__ kf, const float* __restrict__ vf,
    const float* __restrict__ knw, short* __restrict__ Knb,
    short* __restrict__ Vtb)
{
  const int tile = blockIdx.x, h = blockIdx.y, g = blockIdx.z;
  const int t = threadIdx.x;
  // ---- K ----
  const int skv = t >> 3, sg = t & 7;
  const int m  = tile * 32 + skv;
  const int bb = g * NI_ + (m >> 9), nn = m & (N_ - 1);
  const float* kp = kf + ((long)(bb * N_ + nn)) * D_ + h * HD_ + sg * 8;
  float k8[8];
  *(float4*)&k8[0] = *(const float4*)&kp[0];
  *(float4*)&k8[4] = *(const float4*)&kp[4];
  float ks2 = 0.f;
  #pragma unroll
  for (int j = 0; j < 8; j++) ks2 += k8[j] * k8[j];
  ks2 += __shfl_xor(ks2, 1);
  ks2 += __shfl_xor(ks2, 2);
  ks2 += __shfl_xor(ks2, 4);
  const float kr = rsqrtf(ks2 * (1.f / 64.f) + 1e-6f);
  bf16x8 kb;
  #pragma unroll
  for (int j = 0; j < 8; j++) kb[j] = bf16_rn(k8[j] * kr * knw[sg * 8 + j]);
  *(bf16x8*)&Knb[((long)(g * H_ + h) * KVLEN + m) * 64 + ((sg ^ (m & 7)) * 8)] = kb;
  // ---- V ----
  const int vkv = t & 31, vg = t >> 5;
  const int m2  = tile * 32 + vkv;
  const int bb2 = g * NI_ + (m2 >> 9), nn2 = m2 & (N_ - 1);
  const float* vp = vf + ((long)(bb2 * N_ + nn2)) * D_ + h * HD_ + vg * 8;
  float v8[8];
  *(float4*)&v8[0] = *(const float4*)&vp[0];
  *(float4*)&v8[4] = *(const float4*)&vp[4];
  const long vbase = ((long)(g * H_ + h) * 64 + tile) * 2048;
  #pragma unroll
  for (int e = 0; e < 8; e++) {
    const int d = vg * 8 + e;
    Vtb[vbase + d * 32 + (((vkv >> 3) ^ ((d >> 1) & 3)) * 8) + (vkv & 7)] = bf16_rn(v8[e]);
  }
}

// =====================================================================
// MFMA grouped flash attention v4 — KV-SPLIT x2, XCD-swizzled.
// grid (N/128, H, B*2); bz = b*2 + s; half s covers kv [s*1024,(s+1)*1024).
// STATIC softmax max (-8): partials combine exactly (o=o0+o1, l=l0+l1).
// NEW (round 13, VALU diet — was 70% VALUBusy):
//  - P half-swap via 4x permlane32_swap (replaces 8 shfl_xor + selects);
//    verified vs old construction: swap(wd0,wd2) = {f0[0], f0[2]} etc.
//  - l computed by 2 ones-MFMAs on the P fragments (replaces 16 VALU
//    adds + end shfl); lacc[r] is indexed by q=crow(r,hi), same as oacc.
//    Numerator & denominator now share the SAME bf16-rounded P.
// =====================================================================
__global__ __launch_bounds__(256) void attn3(
    const float* __restrict__ q, const short* __restrict__ Knb,
    const short* __restrict__ Vtb, const float* __restrict__ qnw,
    float* __restrict__ opart, float* __restrict__ lpart)
{
  int qb, h, bz;
  xcd_swizzle(qb, h, bz);
  const int b  = bz >> 1, s = bz & 1;
  const int g  = b >> 2;
  const int t  = threadIdx.x;
  const int w  = t >> 6;
  const int lane = t & 63;
  const int l31 = lane & 31, hi = lane >> 5;

  __shared__ short Kt[2][2048];
  __shared__ short Vt[2][2048];

  // ---- Q: load + RMSNorm + B-operand frags ----
  const int qrow = qb * 128 + w * 32 + l31;
  const float* qp = q + ((long)b * N_ + qrow) * D_ + h * HD_ + hi * 8;
  float qv[4][8];
  float ss = 0.f;
  #pragma unroll
  for (int c = 0; c < 4; c++) {
    *(float4*)&qv[c][0] = *(const float4*)&qp[c * 16];
    *(float4*)&qv[c][4] = *(const float4*)&qp[c * 16 + 4];
    #pragma unroll
    for (int j = 0; j < 8; j++) ss += qv[c][j] * qv[c][j];
  }
  ss += __shfl_xor(ss, 32);
  const float qr = rsqrtf(ss * (1.f / 64.f) + 1e-6f);
  bf16x8 qf[4];
  #pragma unroll
  for (int c = 0; c < 4; c++)
    #pragma unroll
    for (int j = 0; j < 8; j++)
      qf[c][j] = bf16_rn(qv[c][j] * qr * qnw[c * 16 + hi * 8 + j]);

  const short* Kg = Knb + (long)(g * H_ + h) * KVLEN * 64 + (long)s * 32 * 2048;
  const short* Vg = Vtb + (long)(g * H_ + h) * 64 * 2048 + (long)s * 32 * 2048;

  auto stage = [&](int buf, int i) {
    GLOAD16(Kg + (long)i * 2048 + t * 8, &Kt[buf][w * 512]);
    GLOAD16(Vg + (long)i * 2048 + t * 8, &Vt[buf][w * 512]);
  };

  const bf16x8 vones = { (short)0x3F80, (short)0x3F80, (short)0x3F80, (short)0x3F80,
                         (short)0x3F80, (short)0x3F80, (short)0x3F80, (short)0x3F80 };

  f32x16 oacc[2] = {};
  f32x16 lacc = {};

  stage(0, 0);
  for (int i = 0; i < 32; ++i) {
    const int buf = i & 1;
    if (i + 1 < 32) {
      stage(buf ^ 1, i + 1);
      asm volatile("s_waitcnt vmcnt(2)" ::: "memory");
    } else {
      asm volatile("s_waitcnt vmcnt(0)" ::: "memory");
    }
    __builtin_amdgcn_s_barrier();
    __builtin_amdgcn_sched_barrier(0);

    // ---- QK^T: scores[kv][q] ----
    f32x16 sc = {};
    #pragma unroll
    for (int c = 0; c < 4; c++) {
      bf16x8 kfr = *(const bf16x8*)&Kt[buf][l31 * 64 + (((2 * c + hi) * 8) ^ ((l31 & 7) << 3))];
      sc = mfma_bf16(kfr, qf[c], sc);
    }
    // ---- softmax, static max: p = exp2(s*0.125*log2e - 8*log2e) ----
    float p[16];
    #pragma unroll
    for (int r = 0; r < 16; r++)
      p[r] = exp2f(fmaf(sc[r], 0.1803368801111244f, -11.541560327111961f));
    // ---- pack P pairs to bf16 (cvt_pk), half-swap via permlane32 ----
    unsigned wd[8];
    #pragma unroll
    for (int i2 = 0; i2 < 8; i2++)
      asm("v_cvt_pk_bf16_f32 %0, %1, %2" : "=v"(wd[i2]) : "v"(p[2 * i2]), "v"(p[2 * i2 + 1]));
    u32x2 r0 = __builtin_amdgcn_permlane32_swap(wd[0], wd[2], false, false);
    u32x2 r1 = __builtin_amdgcn_permlane32_swap(wd[1], wd[3], false, false);
    u32x2 r2 = __builtin_amdgcn_permlane32_swap(wd[4], wd[6], false, false);
    u32x2 r3 = __builtin_amdgcn_permlane32_swap(wd[5], wd[7], false, false);
    int4 f0 = { (int)r0.x, (int)r1.x, (int)r0.y, (int)r1.y };
    int4 f1 = { (int)r2.x, (int)r3.x, (int)r2.y, (int)r3.y };
    // ---- l via ones-MFMA (matrix pipe, not VALU) ----
    lacc = mfma_bf16(__builtin_bit_cast(bf16x8, f0), vones, lacc);
    lacc = mfma_bf16(__builtin_bit_cast(bf16x8, f1), vones, lacc);
    // ---- PV ----
    #pragma unroll
    for (int n = 0; n < 2; n++) {
      const int d = n * 32 + l31;
      const int fd = (d >> 1) & 3;
      bf16x8 v0 = *(const bf16x8*)&Vt[buf][d * 32 + ((hi ^ fd) * 8)];
      bf16x8 v1 = *(const bf16x8*)&Vt[buf][d * 32 + (((2 | hi) ^ fd) * 8)];
      oacc[n] = mfma_bf16(__builtin_bit_cast(bf16x8, f0), v0, oacc[n]);
      oacc[n] = mfma_bf16(__builtin_bit_cast(bf16x8, f1), v1, oacc[n]);
    }
    __builtin_amdgcn_s_barrier();
  }

  // ---- epilogue: write PARTIAL o (no divide) + l ----
  #pragma unroll
  for (int r = 0; r < 16; r++) {
    const int qg = qb * 128 + w * 32 + (r & 3) + 8 * (r >> 2) + 4 * hi;
    float* op = opart + ((long)s * BN_ + b * N_ + qg) * D_ + h * HD_ + l31;
    op[0]  = oacc[0][r];
    op[32] = oacc[1][r];
    if (l31 == 0)
      lpart[((long)s * BN_ + b * N_ + qg) * H_ + h] = lacc[r];
  }
}

// =====================================================================
// attn_reduce: o = (o0+o1)/(l0+l1), split2 -> tiled bf16 hi/lo.
// One block per row (256 thr x 4 floats = 1024 cols).
// =====================================================================
__global__ __launch_bounds__(256) void attn_reduce(
    const float* __restrict__ opart, const float* __restrict__ lpart,
    short* __restrict__ ohi, short* __restrict__ olo)
{
  const int row = blockIdx.x;
  const int col = threadIdx.x * 4;
  const int h   = col >> 6;
  const float l = lpart[(long)row * H_ + h] + lpart[((long)BN_ + row) * H_ + h];
  const float inv = 1.f / l;
  float4 a = *(const float4*)&opart[(long)row * D_ + col];
  float4 b = *(const float4*)&opart[((long)BN_ + row) * D_ + col];
  short hh[4], ll[4];
  split2((a.x + b.x) * inv, hh[0], ll[0]);
  split2((a.y + b.y) * inv, hh[1], ll[1]);
  split2((a.z + b.z) * inv, hh[2], ll[2]);
  split2((a.w + b.w) * inv, hh[3], ll[3]);
  const long o = tiled_off(row, col);
  *(s16x4*)&ohi[o] = *(s16x4*)hh;
  *(s16x4*)&olo[o] = *(s16x4*)ll;
}

// =====================================================================
// inst_feat: mask @ embed -> tiled bf16 (hi only; feeds plain-bf16 ik)
// =====================================================================
__global__ __launch_bounds__(256) void instfeat_split(
    const float* __restrict__ mask, const float* __restrict__ emb,
    short* __restrict__ ofh)
{
  const long idx = (long)blockIdx.x * 256 + threadIdx.x;
  const int  d4  = (int)(idx & (D_ / 4 - 1));
  const long bn  = idx >> 8;
  const float* mk = mask + bn * NI_;
  float4 acc = {0.f, 0.f, 0.f, 0.f};
  #pragma unroll
  for (int i = 0; i < NI_; i++) {
    const float mm = mk[i];
    const float4 e = *(const float4*)&emb[(long)i * D_ + d4 * 4];
    acc.x = fmaf(mm, e.x, acc.x);
    acc.y = fmaf(mm, e.y, acc.y);
    acc.z = fmaf(mm, e.z, acc.z);
    acc.w = fmaf(mm, e.w, acc.w);
  }
  short h[4];
  h[0] = bf16_rn(acc.x);  h[1] = bf16_rn(acc.y);
  h[2] = bf16_rn(acc.z);  h[3] = bf16_rn(acc.w);
  *(s16x4*)&ofh[tiled_off((int)bn, d4 * 4)] = *(s16x4*)h;
}

// =====================================================================
extern "C" void kernel_launch(void* const* d_in, const int* in_sizes, int n_in,
                              void* d_out, int out_size, void* d_ws, size_t ws_size,
                              hipStream_t stream)
{
  const float* x    = (const float*)d_in[0];
  const float* mask = (const float*)d_in[1];
  const float* Wq   = (const float*)d_in[2];
  const float* bq   = (const float*)d_in[3];
  const float* Wk   = (const float*)d_in[4];
  const float* bk   = (const float*)d_in[5];
  const float* Wv   = (const float*)d_in[6];
  const float* bv   = (const float*)d_in[7];
  const float* Wo   = (const float*)d_in[8];
  const float* bo   = (const float*)d_in[9];
  const float* Wiq  = (const float*)d_in[10];
  const float* biq  = (const float*)d_in[11];
  const float* Wik  = (const float*)d_in[12];
  const float* bik  = (const float*)d_in[13];
  const float* emb  = (const float*)d_in[14];
  const float* qnw  = (const float*)d_in[15];
  const float* knw  = (const float*)d_in[16];
  float* out = (float*)d_out;

  // Workspace layout (round-10 lesson: stay within the proven footprint;
  // part/lpart live in the dead interior of Wbig_lo).
  float* ws = (float*)d_ws;
  const size_t SZ = (size_t)BN_ * D_;
  float* qbuf = ws;                     // fp32 q (attn reads)
  float* kbuf = qbuf + SZ;              // fp32 k -> opart[0] after kvprep
  float* vbuf = kbuf + SZ;              // fp32 v -> opart[1] after kvprep
  float* opart = kbuf;                  // [2][BN][D] fp32 attn partials
  short* ohi  = (short*)(vbuf + SZ);    // attn output (tiled split bf16)
  short* olo  = ohi + SZ;
  short* xhi  = (short*)(ws + 4 * SZ);  // x tiled bf16; dead after QKV ->
  short* xlo  = xhi + SZ;               //   reused as Knb / Vtb
  short* Knb  = xhi;                    // [2][16][2048][64] bf16
  short* Vtb  = xlo;                    // [2][16][64][64][32] bf16
  short* Wbig_hi = (short*)(ws + 5 * SZ);
  short* Wbig_lo = Wbig_hi + (size_t)3 * D_ * D_;
  float* part  = (float*)(Wbig_lo + (size_t)D_ * D_);      // [BN][8]
  float* lpart = part + (size_t)BN_ * 8;                   // [2][BN][16]
  short* iqh = (short*)qbuf;            // aliases (post-attention)
  short* ifh = (short*)kbuf;            //   (post-reduce)
  short* ikh = (short*)vbuf;
  short* WiqH = Wbig_hi;                // after QKV GEMM frees Wbig
  short* WikH = Wbig_hi + (size_t)D_ * D_;
  short* WoH  = Wbig_hi + (size_t)2 * D_ * D_;
  short* WoL  = Wbig_lo;                // Wbig_lo[0:D*D] only

  const dim3 blk(256);

  // 1) QKV weight prep (hi only) + x -> tiled bf16
  wsplit3<<<dim3(16, 16, 3), blk, 0, stream>>>(Wq, Wk, Wv, Wbig_hi);
  asplit<<<(BN_ * D_ / 4) / 256, blk, 0, stream>>>(x, xhi);

  // 2) fused QKV projection (plain bf16, 1 MFMA/pair)
  mfgemm2<0, 0><<<dim3(8, 32, 3), blk, 0, stream>>>(
      xhi, nullptr, Wbig_hi, nullptr, bq, bk, bv,
      qbuf, nullptr, nullptr, 0, 8, (long)SZ, nullptr, nullptr);

  // 3) KV prep (norm K, transpose V, bf16, swizzled; group-indexed)
  kvprep<<<dim3(KVLEN / 32, H_, 2), blk, 0, stream>>>(kbuf, vbuf, knw, Knb, Vtb);

  // 4) attention, KV-split x2 -> fp32 partials (over dead kbuf/vbuf)
  attn3<<<dim3(N_ / 128, H_, B_ * 2), blk, 0, stream>>>(
      qbuf, Knb, Vtb, qnw, opart, lpart);

  // 5) gate/final weight prep (Wbig now free)
  wsplitG<<<dim3(16, 16, 3), blk, 0, stream>>>(Wiq, Wik, Wo, WiqH, WikH, WoH, WoL);

  // 6) combine partials -> tiled split bf16 o
  attn_reduce<<<BN_, blk, 0, stream>>>(opart, lpart, ohi, olo);

  // 7) inst_feat (over kbuf, free after reduce)
  instfeat_split<<<(BN_ * D_ / 4) / 256, blk, 0, stream>>>(mask, emb, ifh);

  // 8) DUAL iq & ik GEMM (plain bf16), one dispatch
  mfgemm2<4, 0><<<dim3(8, 32, 2), blk, 0, stream>>>(
      ohi, ifh, WiqH, WikH, biq, bik, nullptr,
      nullptr, iqh, ikh, 0, 0, 0, nullptr, nullptr);

  // 9) gate partials: plain bf16, FULL K per block
  mfgemm2<3, 0><<<dim3(4, 4, 8), blk, 0, stream>>>(
      iqh, nullptr, ikh, nullptr, nullptr, nullptr, nullptr,
      nullptr, nullptr, nullptr, 4, 4, 0, nullptr, part);

  // 10) final: gate(row)*(o@Wo) + bo -> d_out (split, 3-MFMA)
  mfgemm2<2, 1><<<dim3(8, 32, 1), blk, 0, stream>>>(
      ohi, olo, WoH, WoL, bo, nullptr, nullptr,
      out, nullptr, nullptr, 0, 0, 0, part, nullptr);
}

// Round 14
// 228.107 us; speedup vs baseline: 2.6181x; 1.0680x over previous
//
#include <hip/hip_runtime.h>
#include <cmath>

// Problem constants (fixed by the reference file)
#define B_   8
#define N_   512
#define D_   1024
#define H_   16
#define HD_  64
#define NI_  4
#define BN_  (B_*N_)      // 4096 rows when [B,N,*] is flattened
#define KVLEN (NI_*N_)    // 2048 keys per attention group

typedef __attribute__((ext_vector_type(8)))  short  bf16x8;   // 8 bf16 bit patterns
typedef __attribute__((ext_vector_type(8)))  __bf16 bf16x8_t; // builtin operand type
typedef __attribute__((ext_vector_type(16))) float  f32x16;
typedef __attribute__((ext_vector_type(4)))  short  s16x4;
typedef __attribute__((ext_vector_type(2)))  unsigned u32x2;

// round-to-nearest-even bf16 conversion (bit trick)
__device__ __forceinline__ short bf16_rn(float x) {
  unsigned u = __float_as_uint(x);
  unsigned r = (u + 0x7FFFu + ((u >> 16) & 1u)) >> 16;
  return (short)r;
}

// RN hi/lo split: x = hi + lo + eps, |eps| <~ 2^-18 |x|.
__device__ __forceinline__ void split2(float x, short& hi, short& lo) {
  hi = bf16_rn(x);
  float h = __uint_as_float(((unsigned)(unsigned short)hi) << 16);
  float r = x - h;              // exact (Dekker-style split)
  lo = bf16_rn(r);
}

__device__ __forceinline__ f32x16 mfma_bf16(bf16x8 a, bf16x8 b, f32x16 c) {
  return __builtin_amdgcn_mfma_f32_32x32x16_bf16(
      __builtin_bit_cast(bf16x8_t, a), __builtin_bit_cast(bf16x8_t, b), c, 0, 0, 0);
}

#define GLOAD16(gp, lp) __builtin_amdgcn_global_load_lds( \
  (const __attribute__((address_space(1))) unsigned*)(gp), \
  (__attribute__((address_space(3))) unsigned*)(lp), 16, 0, 0)

// TILED-SPLIT layout for all bf16 GEMM operands (K = 1024):
// addr(row,k) = (((row>>7)*128 + (k>>3))*128 + (row&127))*8 + (k&7).
// GEMM staging is then a LINEAR copy -> fully coalesced global_load_lds.
__device__ __forceinline__ long tiled_off(int row, int k) {
  return ((((long)(row >> 7) * 128 + (k >> 3)) * 128 + (row & 127)) * 8 + (k & 7));
}

// T1 XCD-aware block swizzle (MI355X: 8 XCDs, private L2s). Remap so each
// XCD gets a CONTIGUOUS tile range. REQUIRES nwg % 8 == 0 (all grids are).
__device__ __forceinline__ void xcd_swizzle(int& bx, int& by, int& bz) {
  const int gx = gridDim.x, gy = gridDim.y;
  const int nwg = gx * gy * gridDim.z;
  const int lin = blockIdx.x + gx * (blockIdx.y + gy * blockIdx.z);
  const int swz = (lin & 7) * (nwg >> 3) + (lin >> 3);
  bx = swz % gx;
  const int rest = swz / gx;
  by = rest % gy;
  bz = rest / gy;
}

// =====================================================================
// Fused 3-weight transpose for Wq/Wk/Wv -> [3072][1024] tiled bf16.
// =====================================================================
__global__ __launch_bounds__(256) void wsplit3(
    const float* __restrict__ W0, const float* __restrict__ W1,
    const float* __restrict__ W2, short* __restrict__ Thi)
{
  __shared__ float tile[64][65];
  const int z = blockIdx.z;
  const float* W = (z == 0) ? W0 : (z == 1) ? W1 : W2;
  const int t  = threadIdx.x;
  const int kb = blockIdx.y * 64;
  const int cb = blockIdx.x * 64;
  const int r0 = t >> 4;
  const int c4 = t & 15;
  #pragma unroll
  for (int i = 0; i < 4; i++) {
    const int r = r0 + i * 16;
    *(float4*)&tile[r][c4 * 4] = *(const float4*)&W[(long)(kb + r) * D_ + cb + c4 * 4];
  }
  __syncthreads();
  #pragma unroll
  for (int i = 0; i < 4; i++) {
    const int c = r0 + i * 16;
    short hi[4];
    #pragma unroll
    for (int e = 0; e < 4; e++)
      hi[e] = bf16_rn(tile[c4 * 4 + e][c]);
    *(s16x4*)&Thi[tiled_off(z * D_ + cb + c, kb + c4 * 4)] = *(s16x4*)hi;
  }
}

// =====================================================================
// Gate/final weight prep in ONE dispatch: z=0 Wiq, z=1 Wik, z=2 Wo —
// all hi-only now (final GEMM is SPLIT=2: o hi/lo x Wo hi).
// =====================================================================
__global__ __launch_bounds__(256) void wsplitG(
    const float* __restrict__ Wiq, const float* __restrict__ Wik,
    const float* __restrict__ Wo, short* __restrict__ WiqH,
    short* __restrict__ WikH, short* __restrict__ WoH)
{
  __shared__ float tile[64][65];
  const int z = blockIdx.z;
  const float* W = (z == 0) ? Wiq : (z == 1) ? Wik : Wo;
  short* T = (z == 0) ? WiqH : (z == 1) ? WikH : WoH;
  const int t  = threadIdx.x;
  const int kb = blockIdx.y * 64;
  const int cb = blockIdx.x * 64;
  const int r0 = t >> 4;
  const int c4 = t & 15;
  #pragma unroll
  for (int i = 0; i < 4; i++) {
    const int r = r0 + i * 16;
    *(float4*)&tile[r][c4 * 4] = *(const float4*)&W[(long)(kb + r) * D_ + cb + c4 * 4];
  }
  __syncthreads();
  #pragma unroll
  for (int i = 0; i < 4; i++) {
    const int c = r0 + i * 16;
    short hi[4];
    #pragma unroll
    for (int e = 0; e < 4; e++)
      hi[e] = bf16_rn(tile[c4 * 4 + e][c]);
    *(s16x4*)&T[tiled_off(cb + c, kb + c4 * 4)] = *(s16x4*)hi;
  }
}

// =====================================================================
// Elementwise fp32 -> tiled bf16 (hi only — QKV is plain bf16).
// =====================================================================
__global__ __launch_bounds__(256) void asplit(const float* __restrict__ in,
                                              short* __restrict__ hi)
{
  const long i4 = ((long)blockIdx.x * 256 + threadIdx.x) * 4;
  const int row = (int)(i4 >> 10);
  const int kk  = (int)(i4 & 1023);
  float4 v = *(const float4*)&in[i4];
  short h[4];
  h[0] = bf16_rn(v.x);
  h[1] = bf16_rn(v.y);
  h[2] = bf16_rn(v.z);
  h[3] = bf16_rn(v.w);
  *(s16x4*)&hi[tiled_off(row, kk)] = *(s16x4*)h;
}

// =====================================================================
// MFMA GEMM v5. Tiled bf16 operands, linear global_load_lds staging,
// double-buffered LDS, counted vmcnt, XCD-swizzled blocks.
// SPLIT=2: A hi/lo, B hi (2 MFMAs/pair: Al*Bh + Ah*Bh); waves 0-2 stage
//          {Ahi,Alo,Bhi}, wave 3 idle, vmcnt(8). 48 KB LDS.
// SPLIT=0: plain bf16 (1 MFMA/pair); waves 0,1 stage A halves, waves
//          2,3 stage B halves, vmcnt(4). 32 KB LDS.
// MODE 0: C[bz*sC + row*D + col] = A@B + bias(bz)     (QKV fused)
// MODE 2: C = gate[row]*(A@B) + bias                  (final, SPLIT=2)
// MODE 4: DUAL plain GEMM -> bf16 tiled out: bz=0: Chi=Ahi@Bhi+b0;
//         bz=1: Clo=Alo@Blo+b1                        (iq & ik)
// MODE 5: K-SPLIT raw-z GEMM (sigmoid DEFERRED to gate_finish — the
//         round-8 lesson: sigmoid must see the full K sum; splitting is
//         legal only on the raw matmul): bz = batch*2 + s, K-half s;
//         C[s][batch][row][col] = A@B (fp32, no bias), ldc = 512.
// =====================================================================
template<int MODE, int SPLIT>
__global__ __launch_bounds__(256) void mfgemm2(
    const short* __restrict__ Ahi, const short* __restrict__ Alo,
    const short* __restrict__ Bhi, const short* __restrict__ Blo,
    const float* __restrict__ b0, const float* __restrict__ b1,
    const float* __restrict__ b2,
    float* __restrict__ C, short* __restrict__ Chi, short* __restrict__ Clo,
    int aBlk, int bBlk, long sC,
    const float* __restrict__ gate_in)
{
  constexpr int NOPS = (SPLIT == 2) ? 3 : 2;
  __shared__ short lds[2][NOPS][4096];
  const int t = threadIdx.x, w = t >> 6, lane = t & 63;
  int bx, by, bz;
  xcd_swizzle(bx, by, bz);
  const int rowBase = by * 128;
  const int colBase = bx * 128;
  const int batch = (MODE == 5) ? (bz >> 1) : bz;
  const long kOff = (MODE == 5) ? (long)(bz & 1) * 65536 : 0;
  const long aoff = (long)(batch * aBlk + by) * 131072 + kOff;
  const long boff = (long)(batch * bBlk + bx) * 131072 + kOff;

  const short* Abase = (MODE == 4 && bz) ? Alo : Ahi;
  const short* Bbase = (MODE == 4 && bz) ? Blo : Bhi;

  const short* mySrc;
  int op, half;
  if (SPLIT == 2) {
    op = (w < 3) ? w : 0; half = 0;
    mySrc = (w == 0) ? Ahi + aoff : (w == 1) ? Alo + aoff : Bhi + boff;
  } else {
    op = w >> 1; half = w & 1;
    mySrc = op ? Bbase + boff : Abase + aoff;
  }

  auto stage = [&](int buf, int tt) {
    if (SPLIT == 2) {
      if (w == 3) return;   // 3 operands, wave 3 idle
      const short* g = mySrc + ((long)tt * 512 + lane) * 8;
      #pragma unroll
      for (int i = 0; i < 8; i++)
        GLOAD16(g + i * 512, &lds[buf][op][i * 512]);
    } else {
      const short* g = mySrc + ((long)tt * 512 + half * 256 + lane) * 8;
      #pragma unroll
      for (int i = 0; i < 4; i++)
        GLOAD16(g + i * 512, &lds[buf][op][(half * 256 + i * 64) * 8]);
    }
  };

  const int wr = w >> 1, wc = w & 1;
  const int lrow = lane & 31, lk = lane >> 5;

  f32x16 acc[2][2] = {};

  auto compute = [&](int buf) {
    #pragma unroll
    for (int kh = 0; kh < 2; kh++) {
      const int kq = 2 * kh + lk;
      bf16x8 ah[2], bh[2];
      #pragma unroll
      for (int m = 0; m < 2; m++)
        ah[m] = *(const bf16x8*)&lds[buf][0][(kq * 128 + wr * 64 + m * 32 + lrow) * 8];
      #pragma unroll
      for (int n = 0; n < 2; n++)
        bh[n] = *(const bf16x8*)&lds[buf][(SPLIT == 2) ? 2 : 1][(kq * 128 + wc * 64 + n * 32 + lrow) * 8];
      if (SPLIT == 2) {
        bf16x8 al[2];
        #pragma unroll
        for (int m = 0; m < 2; m++)
          al[m] = *(const bf16x8*)&lds[buf][1][(kq * 128 + wr * 64 + m * 32 + lrow) * 8];
        #pragma unroll
        for (int m = 0; m < 2; m++)
          #pragma unroll
          for (int n = 0; n < 2; n++) {
            acc[m][n] = mfma_bf16(al[m], bh[n], acc[m][n]);
            acc[m][n] = mfma_bf16(ah[m], bh[n], acc[m][n]);
          }
      } else {
        #pragma unroll
        for (int m = 0; m < 2; m++)
          #pragma unroll
          for (int n = 0; n < 2; n++)
            acc[m][n] = mfma_bf16(ah[m], bh[n], acc[m][n]);
      }
    }
  };

  const int NT = (MODE == 5) ? 16 : 32;   // K-half for MODE 5
  stage(0, 0);
  for (int tt = 0; tt < NT - 1; ++tt) {
    stage((tt + 1) & 1, tt + 1);
    if (SPLIT == 2) asm volatile("s_waitcnt vmcnt(8)" ::: "memory");
    else            asm volatile("s_waitcnt vmcnt(4)" ::: "memory");
    __builtin_amdgcn_s_barrier();
    __builtin_amdgcn_sched_barrier(0);
    compute(tt & 1);
    __builtin_amdgcn_s_barrier();
  }
  asm volatile("s_waitcnt vmcnt(0)" ::: "memory");
  __builtin_amdgcn_s_barrier();
  __builtin_amdgcn_sched_barrier(0);
  compute((NT - 1) & 1);

  // ---------------- epilogue ----------------
  if (MODE == 5) {
    float* Cz = C + (long)(bz & 1) * (8L * 512 * 512) + (long)batch * (512L * 512);
    #pragma unroll
    for (int m = 0; m < 2; m++)
      #pragma unroll
      for (int r = 0; r < 16; r++) {
        const int row = rowBase + wr * 64 + m * 32 + (r & 3) + 8 * (r >> 2) + 4 * lk;
        #pragma unroll
        for (int n = 0; n < 2; n++)
          Cz[(long)row * 512 + colBase + wc * 64 + n * 32 + lrow] = acc[m][n][r];
      }
    return;
  }

  const float* bias = (bz == 1) ? b1 : (bz == 2) ? b2 : b0;
  float bcol[2];
  #pragma unroll
  for (int n = 0; n < 2; n++)
    bcol[n] = bias[colBase + wc * 64 + n * 32 + lrow];

  float* Cb = C + (long)bz * sC;
  short* Cdst = (MODE == 4 && bz) ? Clo : Chi;

  #pragma unroll
  for (int m = 0; m < 2; m++) {
    #pragma unroll
    for (int r = 0; r < 16; r++) {
      const int row = rowBase + wr * 64 + m * 32 + (r & 3) + 8 * (r >> 2) + 4 * lk;
      float g = 1.f;
      if (MODE == 2) g = gate_in[row];
      #pragma unroll
      for (int n = 0; n < 2; n++) {
        const int col = colBase + wc * 64 + n * 32 + lrow;
        const float val = acc[m][n][r] * g + bcol[n];
        if (MODE == 4) {
          Cdst[tiled_off(row, col)] = bf16_rn(val);
        } else {
          Cb[(long)row * D_ + col] = val;
        }
      }
    }
  }
}

// =====================================================================
// gate_finish: gate[row] = 1 + mean_m sigmoid((z0+z1)*SCALE/H).
// One wave per row; lane covers 8 cols of each K-half partial.
// =====================================================================
__global__ __launch_bounds__(256) void gate_finish(
    const float* __restrict__ zp, float* __restrict__ gate)
{
  const int t = threadIdx.x, w = t >> 6, lane = t & 63;
  const int row = blockIdx.x * 4 + w;    // 0..4095 (= batch*512 + r)
  const float* z0 = zp + (long)row * 512;
  const float* z1 = zp + 8L * 512 * 512 + (long)row * 512;
  const float sc = 0.125f / 16.f;        // SCALE/H
  float4 a0 = *(const float4*)&z0[lane * 8];
  float4 a1 = *(const float4*)&z0[lane * 8 + 4];
  float4 b0 = *(const float4*)&z1[lane * 8];
  float4 b1 = *(const float4*)&z1[lane * 8 + 4];
  float s = 1.f / (1.f + __expf(-(a0.x + b0.x) * sc))
          + 1.f / (1.f + __expf(-(a0.y + b0.y) * sc))
          + 1.f / (1.f + __expf(-(a0.z + b0.z) * sc))
          + 1.f / (1.f + __expf(-(a0.w + b0.w) * sc))
          + 1.f / (1.f + __expf(-(a1.x + b1.x) * sc))
          + 1.f / (1.f + __expf(-(a1.y + b1.y) * sc))
          + 1.f / (1.f + __expf(-(a1.z + b1.z) * sc))
          + 1.f / (1.f + __expf(-(a1.w + b1.w) * sc));
  #pragma unroll
  for (int m = 1; m < 64; m <<= 1) s += __shfl_xor(s, m);
  if (lane == 0) gate[row] = 1.f + s * (1.f / 512.f);
}

// =====================================================================
// KV prep: K RMSNorm->bf16 swizzled [g][h][m][64]; V transposed bf16
// tiles [g][h][tile][d][32kv], chunk-swizzled. Both linear per 4KB tile
// for coalesced global_load_lds in attention.
// =====================================================================
__global__ __launch_bounds__(256) void kvprep(
    const float* __restrict__ kf, const float* __restrict__ vf,
    const float* __restrict__ knw, short* __restrict__ Knb,
    short* __restrict__ Vtb)
{
  const int tile = blockIdx.x, h = blockIdx.y, g = blockIdx.z;
  const int t = threadIdx.x;
  // ---- K ----
  const int skv = t >> 3, sg = t & 7;
  const int m  = tile * 32 + skv;
  const int bb = g * NI_ + (m >> 9), nn = m & (N_ - 1);
  const float* kp = kf + ((long)(bb * N_ + nn)) * D_ + h * HD_ + sg * 8;
  float k8[8];
  *(float4*)&k8[0] = *(const float4*)&kp[0];
  *(float4*)&k8[4] = *(const float4*)&kp[4];
  float ks2 = 0.f;
  #pragma unroll
  for (int j = 0; j < 8; j++) ks2 += k8[j] * k8[j];
  ks2 += __shfl_xor(ks2, 1);
  ks2 += __shfl_xor(ks2, 2);
  ks2 += __shfl_xor(ks2, 4);
  const float kr = rsqrtf(ks2 * (1.f / 64.f) + 1e-6f);
  bf16x8 kb;
  #pragma unroll
  for (int j = 0; j < 8; j++) kb[j] = bf16_rn(k8[j] * kr * knw[sg * 8 + j]);
  *(bf16x8*)&Knb[((long)(g * H_ + h) * KVLEN + m) * 64 + ((sg ^ (m & 7)) * 8)] = kb;
  // ---- V ----
  const int vkv = t & 31, vg = t >> 5;
  const int m2  = tile * 32 + vkv;
  const int bb2 = g * NI_ + (m2 >> 9), nn2 = m2 & (N_ - 1);
  const float* vp = vf + ((long)(bb2 * N_ + nn2)) * D_ + h * HD_ + vg * 8;
  float v8[8];
  *(float4*)&v8[0] = *(const float4*)&vp[0];
  *(float4*)&v8[4] = *(const float4*)&vp[4];
  const long vbase = ((long)(g * H_ + h) * 64 + tile) * 2048;
  #pragma unroll
  for (int e = 0; e < 8; e++) {
    const int d = vg * 8 + e;
    Vtb[vbase + d * 32 + (((vkv >> 3) ^ ((d >> 1) & 3)) * 8) + (vkv & 7)] = bf16_rn(v8[e]);
  }
}

// =====================================================================
// MFMA grouped flash attention v5 — KV-SPLIT x2, XCD-swizzled,
// 3-DEEP LDS pipeline (tile i's loads issued 2 compute phases early:
// ~600cy of HBM-latency cover vs ~300 at 2-deep; r13 was latency-bound).
// Scalar l restored (r13's ones-MFMA lacc cost 16 VGPR -> occupancy
// 33%->24%; permlane32_swap kept — it is VGPR-neutral).
// STATIC softmax max (-8): partials combine exactly (o=o0+o1, l=l0+l1).
// =====================================================================
__global__ __launch_bounds__(256) void attn3(
    const float* __restrict__ q, const short* __restrict__ Knb,
    const short* __restrict__ Vtb, const float* __restrict__ qnw,
    float* __restrict__ opart, float* __restrict__ lpart)
{
  int qb, h, bz;
  xcd_swizzle(qb, h, bz);
  const int b  = bz >> 1, s = bz & 1;
  const int g  = b >> 2;
  const int t  = threadIdx.x;
  const int w  = t >> 6;
  const int lane = t & 63;
  const int l31 = lane & 31, hi = lane >> 5;

  __shared__ short Kt[3][2048];
  __shared__ short Vt[3][2048];

  // ---- Q: load + RMSNorm + B-operand frags ----
  const int qrow = qb * 128 + w * 32 + l31;
  const float* qp = q + ((long)b * N_ + qrow) * D_ + h * HD_ + hi * 8;
  float qv[4][8];
  float ss = 0.f;
  #pragma unroll
  for (int c = 0; c < 4; c++) {
    *(float4*)&qv[c][0] = *(const float4*)&qp[c * 16];
    *(float4*)&qv[c][4] = *(const float4*)&qp[c * 16 + 4];
    #pragma unroll
    for (int j = 0; j < 8; j++) ss += qv[c][j] * qv[c][j];
  }
  ss += __shfl_xor(ss, 32);
  const float qr = rsqrtf(ss * (1.f / 64.f) + 1e-6f);
  bf16x8 qf[4];
  #pragma unroll
  for (int c = 0; c < 4; c++)
    #pragma unroll
    for (int j = 0; j < 8; j++)
      qf[c][j] = bf16_rn(qv[c][j] * qr * qnw[c * 16 + hi * 8 + j]);

  const short* Kg = Knb + (long)(g * H_ + h) * KVLEN * 64 + (long)s * 32 * 2048;
  const short* Vg = Vtb + (long)(g * H_ + h) * 64 * 2048 + (long)s * 32 * 2048;

  auto stage = [&](int buf, int i) {
    GLOAD16(Kg + (long)i * 2048 + t * 8, &Kt[buf][w * 512]);
    GLOAD16(Vg + (long)i * 2048 + t * 8, &Vt[buf][w * 512]);
  };

  f32x16 oacc[2] = {};
  float l = 0.f;

  stage(0, 0);
  stage(1, 1);
  int buf = 0;
  for (int i = 0; i < 32; ++i) {
    if (i + 2 < 32) {
      stage((buf + 2 >= 3) ? buf - 1 : buf + 2, i + 2);
      asm volatile("s_waitcnt vmcnt(4)" ::: "memory");
    } else if (i + 1 < 32) {
      asm volatile("s_waitcnt vmcnt(2)" ::: "memory");
    } else {
      asm volatile("s_waitcnt vmcnt(0)" ::: "memory");
    }
    __builtin_amdgcn_s_barrier();
    __builtin_amdgcn_sched_barrier(0);

    // ---- QK^T: scores[kv][q] ----
    f32x16 sc = {};
    #pragma unroll
    for (int c = 0; c < 4; c++) {
      bf16x8 kfr = *(const bf16x8*)&Kt[buf][l31 * 64 + (((2 * c + hi) * 8) ^ ((l31 & 7) << 3))];
      sc = mfma_bf16(kfr, qf[c], sc);
    }
    // ---- softmax, static max: p = exp2(s*0.125*log2e - 8*log2e) ----
    float p[16];
    #pragma unroll
    for (int r = 0; r < 16; r++) {
      p[r] = exp2f(fmaf(sc[r], 0.1803368801111244f, -11.541560327111961f));
      l += p[r];
    }
    // ---- pack P pairs to bf16 (cvt_pk), half-swap via permlane32 ----
    unsigned wd[8];
    #pragma unroll
    for (int i2 = 0; i2 < 8; i2++)
      asm("v_cvt_pk_bf16_f32 %0, %1, %2" : "=v"(wd[i2]) : "v"(p[2 * i2]), "v"(p[2 * i2 + 1]));
    u32x2 r0 = __builtin_amdgcn_permlane32_swap(wd[0], wd[2], false, false);
    u32x2 r1 = __builtin_amdgcn_permlane32_swap(wd[1], wd[3], false, false);
    u32x2 r2 = __builtin_amdgcn_permlane32_swap(wd[4], wd[6], false, false);
    u32x2 r3 = __builtin_amdgcn_permlane32_swap(wd[5], wd[7], false, false);
    int4 f0 = { (int)r0.x, (int)r1.x, (int)r0.y, (int)r1.y };
    int4 f1 = { (int)r2.x, (int)r3.x, (int)r2.y, (int)r3.y };
    // ---- PV ----
    #pragma unroll
    for (int n = 0; n < 2; n++) {
      const int d = n * 32 + l31;
      const int fd = (d >> 1) & 3;
      bf16x8 v0 = *(const bf16x8*)&Vt[buf][d * 32 + ((hi ^ fd) * 8)];
      bf16x8 v1 = *(const bf16x8*)&Vt[buf][d * 32 + (((2 | hi) ^ fd) * 8)];
      oacc[n] = mfma_bf16(__builtin_bit_cast(bf16x8, f0), v0, oacc[n]);
      oacc[n] = mfma_bf16(__builtin_bit_cast(bf16x8, f1), v1, oacc[n]);
    }
    __builtin_amdgcn_s_barrier();
    buf = (buf + 1 >= 3) ? 0 : buf + 1;
  }

  // ---- epilogue: write PARTIAL o (no divide) + l ----
  l += __shfl_xor(l, 32);
  #pragma unroll
  for (int r = 0; r < 16; r++) {
    const int qg = qb * 128 + w * 32 + (r & 3) + 8 * (r >> 2) + 4 * hi;
    float* op = opart + ((long)s * BN_ + b * N_ + qg) * D_ + h * HD_ + l31;
    op[0]  = oacc[0][r];
    op[32] = oacc[1][r];
  }
  if (hi == 0)
    lpart[((long)s * BN_ + b * N_ + qb * 128 + w * 32 + l31) * H_ + h] = l;
}

// =====================================================================
// attn_reduce: o = (o0+o1)/(l0+l1), split2 -> tiled bf16 hi/lo.
// =====================================================================
__global__ __launch_bounds__(256) void attn_reduce(
    const float* __restrict__ opart, const float* __restrict__ lpart,
    short* __restrict__ ohi, short* __restrict__ olo)
{
  const int row = blockIdx.x;
  const int col = threadIdx.x * 4;
  const int h   = col >> 6;
  const float l = lpart[(long)row * H_ + h] + lpart[((long)BN_ + row) * H_ + h];
  const float inv = 1.f / l;
  float4 a = *(const float4*)&opart[(long)row * D_ + col];
  float4 b = *(const float4*)&opart[((long)BN_ + row) * D_ + col];
  short hh[4], ll[4];
  split2((a.x + b.x) * inv, hh[0], ll[0]);
  split2((a.y + b.y) * inv, hh[1], ll[1]);
  split2((a.z + b.z) * inv, hh[2], ll[2]);
  split2((a.w + b.w) * inv, hh[3], ll[3]);
  const long o = tiled_off(row, col);
  *(s16x4*)&ohi[o] = *(s16x4*)hh;
  *(s16x4*)&olo[o] = *(s16x4*)ll;
}

// =====================================================================
// inst_feat: mask @ embed -> tiled bf16 (hi only; feeds plain-bf16 ik)
// =====================================================================
__global__ __launch_bounds__(256) void instfeat_split(
    const float* __restrict__ mask, const float* __restrict__ emb,
    short* __restrict__ ofh)
{
  const long idx = (long)blockIdx.x * 256 + threadIdx.x;
  const int  d4  = (int)(idx & (D_ / 4 - 1));
  const long bn  = idx >> 8;
  const float* mk = mask + bn * NI_;
  float4 acc = {0.f, 0.f, 0.f, 0.f};
  #pragma unroll
  for (int i = 0; i < NI_; i++) {
    const float mm = mk[i];
    const float4 e = *(const float4*)&emb[(long)i * D_ + d4 * 4];
    acc.x = fmaf(mm, e.x, acc.x);
    acc.y = fmaf(mm, e.y, acc.y);
    acc.z = fmaf(mm, e.z, acc.z);
    acc.w = fmaf(mm, e.w, acc.w);
  }
  short h[4];
  h[0] = bf16_rn(acc.x);  h[1] = bf16_rn(acc.y);
  h[2] = bf16_rn(acc.z);  h[3] = bf16_rn(acc.w);
  *(s16x4*)&ofh[tiled_off((int)bn, d4 * 4)] = *(s16x4*)h;
}

// =====================================================================
extern "C" void kernel_launch(void* const* d_in, const int* in_sizes, int n_in,
                              void* d_out, int out_size, void* d_ws, size_t ws_size,
                              hipStream_t stream)
{
  const float* x    = (const float*)d_in[0];
  const float* mask = (const float*)d_in[1];
  const float* Wq   = (const float*)d_in[2];
  const float* bq   = (const float*)d_in[3];
  const float* Wk   = (const float*)d_in[4];
  const float* bk   = (const float*)d_in[5];
  const float* Wv   = (const float*)d_in[6];
  const float* bv   = (const float*)d_in[7];
  const float* Wo   = (const float*)d_in[8];
  const float* bo   = (const float*)d_in[9];
  const float* Wiq  = (const float*)d_in[10];
  const float* biq  = (const float*)d_in[11];
  const float* Wik  = (const float*)d_in[12];
  const float* bik  = (const float*)d_in[13];
  const float* emb  = (const float*)d_in[14];
  const float* qnw  = (const float*)d_in[15];
  const float* knw  = (const float*)d_in[16];
  float* out = (float*)d_out;

  // Workspace layout (round-10 lesson: stay within the proven footprint;
  // gate/lpart live in the dead Wbig_lo interior; zpart reuses the dead
  // Knb/Vtb region after attn3).
  float* ws = (float*)d_ws;
  const size_t SZ = (size_t)BN_ * D_;
  float* qbuf = ws;                     // fp32 q (attn reads)
  float* kbuf = qbuf + SZ;              // fp32 k -> opart[0] after kvprep
  float* vbuf = kbuf + SZ;              // fp32 v -> opart[1] after kvprep
  float* opart = kbuf;                  // [2][BN][D] fp32 attn partials
  short* ohi  = (short*)(vbuf + SZ);    // attn output (tiled split bf16)
  short* olo  = ohi + SZ;
  short* xhi  = (short*)(ws + 4 * SZ);  // x tiled bf16; dead after QKV ->
  short* xlo  = xhi + SZ;               //   reused as Knb / Vtb -> zpart
  short* Knb  = xhi;                    // [2][16][2048][64] bf16
  short* Vtb  = xlo;                    // [2][16][64][64][32] bf16
  float* zpart = (float*)xhi;           // [2][8][512][512] fp32 (post-attn)
  short* Wbig_hi = (short*)(ws + 5 * SZ);
  short* Wbig_lo = Wbig_hi + (size_t)3 * D_ * D_;
  float* gate  = (float*)(Wbig_lo + (size_t)D_ * D_);   // [BN]
  float* lpart = gate + BN_;                            // [2][BN][16]
  short* iqh = (short*)qbuf;            // aliases (post-attention)
  short* ifh = (short*)kbuf;            //   (post-reduce)
  short* ikh = (short*)vbuf;
  short* WiqH = Wbig_hi;                // after QKV GEMM frees Wbig
  short* WikH = Wbig_hi + (size_t)D_ * D_;
  short* WoH  = Wbig_hi + (size_t)2 * D_ * D_;

  const dim3 blk(256);

  // 1) QKV weight prep (hi only) + x -> tiled bf16
  wsplit3<<<dim3(16, 16, 3), blk, 0, stream>>>(Wq, Wk, Wv, Wbig_hi);
  asplit<<<(BN_ * D_ / 4) / 256, blk, 0, stream>>>(x, xhi);

  // 2) fused QKV projection (plain bf16, 1 MFMA/pair)
  mfgemm2<0, 0><<<dim3(8, 32, 3), blk, 0, stream>>>(
      xhi, nullptr, Wbig_hi, nullptr, bq, bk, bv,
      qbuf, nullptr, nullptr, 0, 8, (long)SZ, nullptr);

  // 3) KV prep (norm K, transpose V, bf16, swizzled; group-indexed)
  kvprep<<<dim3(KVLEN / 32, H_, 2), blk, 0, stream>>>(kbuf, vbuf, knw, Knb, Vtb);

  // 4) attention, KV-split x2, 3-deep pipeline -> fp32 partials
  attn3<<<dim3(N_ / 128, H_, B_ * 2), blk, 0, stream>>>(
      qbuf, Knb, Vtb, qnw, opart, lpart);

  // 5) gate/final weight prep (Wbig now free; all hi-only)
  wsplitG<<<dim3(16, 16, 3), blk, 0, stream>>>(Wiq, Wik, Wo, WiqH, WikH, WoH);

  // 6) combine partials -> tiled split bf16 o
  attn_reduce<<<BN_, blk, 0, stream>>>(opart, lpart, ohi, olo);

  // 7) inst_feat (over kbuf, free after reduce)
  instfeat_split<<<(BN_ * D_ / 4) / 256, blk, 0, stream>>>(mask, emb, ifh);

  // 8) DUAL iq & ik GEMM (plain bf16), one dispatch
  mfgemm2<4, 0><<<dim3(8, 32, 2), blk, 0, stream>>>(
      ohi, ifh, WiqH, WikH, biq, bik, nullptr,
      nullptr, iqh, ikh, 0, 0, 0, nullptr);

  // 9a) raw z = IQ@IK^T, K-split x2 (sigmoid deferred -> legal), 1 blk/CU
  mfgemm2<5, 0><<<dim3(4, 4, 16), blk, 0, stream>>>(
      iqh, nullptr, ikh, nullptr, nullptr, nullptr, nullptr,
      zpart, nullptr, nullptr, 4, 4, 0, nullptr);

  // 9b) gate[row] = 1 + mean sigmoid((z0+z1)*sc)
  gate_finish<<<BN_ / 4, blk, 0, stream>>>(zpart, gate);

  // 10) final: gate[row]*(o@Wo) + bo -> d_out (SPLIT=2: o hi/lo x Wo hi)
  mfgemm2<2, 2><<<dim3(8, 32, 1), blk, 0, stream>>>(
      ohi, olo, WoH, nullptr, bo, nullptr, nullptr,
      out, nullptr, nullptr, 0, 0, 0, gate);
}

// Round 15
// 216.717 us; speedup vs baseline: 2.7557x; 1.0526x over previous
//
#include <hip/hip_runtime.h>
#include <cmath>

// Problem constants (fixed by the reference file)
#define B_   8
#define N_   512
#define D_   1024
#define H_   16
#define HD_  64
#define NI_  4
#define BN_  (B_*N_)      // 4096 rows when [B,N,*] is flattened
#define KVLEN (NI_*N_)    // 2048 keys per attention group

typedef __attribute__((ext_vector_type(8)))  short  bf16x8;   // 8 bf16 bit patterns
typedef __attribute__((ext_vector_type(8)))  __bf16 bf16x8_t; // builtin operand type
typedef __attribute__((ext_vector_type(16))) float  f32x16;
typedef __attribute__((ext_vector_type(4)))  short  s16x4;
typedef __attribute__((ext_vector_type(2)))  unsigned u32x2;

// round-to-nearest-even bf16 conversion (bit trick)
__device__ __forceinline__ short bf16_rn(float x) {
  unsigned u = __float_as_uint(x);
  unsigned r = (u + 0x7FFFu + ((u >> 16) & 1u)) >> 16;
  return (short)r;
}

// RN hi/lo split: x = hi + lo + eps, |eps| <~ 2^-18 |x|.
__device__ __forceinline__ void split2(float x, short& hi, short& lo) {
  hi = bf16_rn(x);
  float h = __uint_as_float(((unsigned)(unsigned short)hi) << 16);
  float r = x - h;              // exact (Dekker-style split)
  lo = bf16_rn(r);
}

__device__ __forceinline__ f32x16 mfma_bf16(bf16x8 a, bf16x8 b, f32x16 c) {
  return __builtin_amdgcn_mfma_f32_32x32x16_bf16(
      __builtin_bit_cast(bf16x8_t, a), __builtin_bit_cast(bf16x8_t, b), c, 0, 0, 0);
}

#define GLOAD16(gp, lp) __builtin_amdgcn_global_load_lds( \
  (const __attribute__((address_space(1))) unsigned*)(gp), \
  (__attribute__((address_space(3))) unsigned*)(lp), 16, 0, 0)

// TILED-SPLIT layout for all bf16 GEMM operands (K = 1024):
// addr(row,k) = (((row>>7)*128 + (k>>3))*128 + (row&127))*8 + (k&7).
// GEMM staging is then a LINEAR copy -> fully coalesced global_load_lds.
__device__ __forceinline__ long tiled_off(int row, int k) {
  return ((((long)(row >> 7) * 128 + (k >> 3)) * 128 + (row & 127)) * 8 + (k & 7));
}

// T1 XCD-aware block swizzle (MI355X: 8 XCDs, private L2s). Remap so each
// XCD gets a CONTIGUOUS tile range. REQUIRES nwg % 8 == 0 (all grids are).
__device__ __forceinline__ void xcd_swizzle(int& bx, int& by, int& bz) {
  const int gx = gridDim.x, gy = gridDim.y;
  const int nwg = gx * gy * gridDim.z;
  const int lin = blockIdx.x + gx * (blockIdx.y + gy * blockIdx.z);
  const int swz = (lin & 7) * (nwg >> 3) + (lin >> 3);
  bx = swz % gx;
  const int rest = swz / gx;
  by = rest % gy;
  bz = rest / gy;
}

// =====================================================================
// ALL weight prep in ONE dispatch (z=0..5): Wq/Wk/Wv -> QKVh (combined
// [3072][1024] tiled, rows z*D+c); Wiq/Wik/Wo -> Gateh[(z-3)*D*D]
// (each its own [1024][1024] tiled space). All hi-only bf16.
// =====================================================================
__global__ __launch_bounds__(256) void wsplitAll(
    const float* __restrict__ Wq, const float* __restrict__ Wk,
    const float* __restrict__ Wv, const float* __restrict__ Wiq,
    const float* __restrict__ Wik, const float* __restrict__ Wo,
    short* __restrict__ QKVh, short* __restrict__ Gateh)
{
  __shared__ float tile[64][65];
  const int z = blockIdx.z;
  const float* W = (z == 0) ? Wq : (z == 1) ? Wk : (z == 2) ? Wv
                 : (z == 3) ? Wiq : (z == 4) ? Wik : Wo;
  const int t  = threadIdx.x;
  const int kb = blockIdx.y * 64;
  const int cb = blockIdx.x * 64;
  const int r0 = t >> 4;
  const int c4 = t & 15;
  #pragma unroll
  for (int i = 0; i < 4; i++) {
    const int r = r0 + i * 16;
    *(float4*)&tile[r][c4 * 4] = *(const float4*)&W[(long)(kb + r) * D_ + cb + c4 * 4];
  }
  __syncthreads();
  #pragma unroll
  for (int i = 0; i < 4; i++) {
    const int c = r0 + i * 16;
    short hi[4];
    #pragma unroll
    for (int e = 0; e < 4; e++)
      hi[e] = bf16_rn(tile[c4 * 4 + e][c]);
    if (z < 3) {
      *(s16x4*)&QKVh[tiled_off(z * D_ + cb + c, kb + c4 * 4)] = *(s16x4*)hi;
    } else {
      *(s16x4*)&Gateh[(long)(z - 3) * D_ * D_ + tiled_off(cb + c, kb + c4 * 4)] = *(s16x4*)hi;
    }
  }
}

// =====================================================================
// Elementwise fp32 -> tiled bf16 (hi only — QKV is plain bf16).
// =====================================================================
__global__ __launch_bounds__(256) void asplit(const float* __restrict__ in,
                                              short* __restrict__ hi)
{
  const long i4 = ((long)blockIdx.x * 256 + threadIdx.x) * 4;
  const int row = (int)(i4 >> 10);
  const int kk  = (int)(i4 & 1023);
  float4 v = *(const float4*)&in[i4];
  short h[4];
  h[0] = bf16_rn(v.x);
  h[1] = bf16_rn(v.y);
  h[2] = bf16_rn(v.z);
  h[3] = bf16_rn(v.w);
  *(s16x4*)&hi[tiled_off(row, kk)] = *(s16x4*)h;
}

// =====================================================================
// MFMA GEMM v5. Tiled bf16 operands, linear global_load_lds staging,
// double-buffered LDS, counted vmcnt, XCD-swizzled blocks.
// SPLIT=2: A hi/lo, B hi (2 MFMAs/pair); waves 0-2 stage {Ahi,Alo,Bhi},
//          wave 3 idle, vmcnt(8). 48 KB LDS.
// SPLIT=0: plain bf16 (1 MFMA/pair); waves 0,1 stage A halves, waves
//          2,3 stage B halves, vmcnt(4). 32 KB LDS.
// MODE 0: C[bz*sC + row*D + col] = A@B + bias(bz)     (QKV fused)
// MODE 2: C = gate[row]*(A@B) + bias                  (final, SPLIT=2)
// MODE 4: DUAL plain GEMM -> bf16 tiled out: bz=0: Chi=Ahi@Bhi+b0;
//         bz=1: Clo=Alo@Blo+b1                        (iq & ik)
// MODE 5: K-SPLIT raw-z GEMM (sigmoid DEFERRED to gate_finish — the
//         round-8 lesson: sigmoid must see the full K sum): bz =
//         batch*2 + s; C[s][batch][row][col] = A@B fp32, ldc = 512.
// =====================================================================
template<int MODE, int SPLIT>
__global__ __launch_bounds__(256) void mfgemm2(
    const short* __restrict__ Ahi, const short* __restrict__ Alo,
    const short* __restrict__ Bhi, const short* __restrict__ Blo,
    const float* __restrict__ b0, const float* __restrict__ b1,
    const float* __restrict__ b2,
    float* __restrict__ C, short* __restrict__ Chi, short* __restrict__ Clo,
    int aBlk, int bBlk, long sC,
    const float* __restrict__ gate_in)
{
  constexpr int NOPS = (SPLIT == 2) ? 3 : 2;
  __shared__ short lds[2][NOPS][4096];
  const int t = threadIdx.x, w = t >> 6, lane = t & 63;
  int bx, by, bz;
  xcd_swizzle(bx, by, bz);
  const int rowBase = by * 128;
  const int colBase = bx * 128;
  const int batch = (MODE == 5) ? (bz >> 1) : bz;
  const long kOff = (MODE == 5) ? (long)(bz & 1) * 65536 : 0;
  const long aoff = (long)(batch * aBlk + by) * 131072 + kOff;
  const long boff = (long)(batch * bBlk + bx) * 131072 + kOff;

  const short* Abase = (MODE == 4 && bz) ? Alo : Ahi;
  const short* Bbase = (MODE == 4 && bz) ? Blo : Bhi;

  const short* mySrc;
  int op, half;
  if (SPLIT == 2) {
    op = (w < 3) ? w : 0; half = 0;
    mySrc = (w == 0) ? Ahi + aoff : (w == 1) ? Alo + aoff : Bhi + boff;
  } else {
    op = w >> 1; half = w & 1;
    mySrc = op ? Bbase + boff : Abase + aoff;
  }

  auto stage = [&](int buf, int tt) {
    if (SPLIT == 2) {
      if (w == 3) return;   // 3 operands, wave 3 idle
      const short* g = mySrc + ((long)tt * 512 + lane) * 8;
      #pragma unroll
      for (int i = 0; i < 8; i++)
        GLOAD16(g + i * 512, &lds[buf][op][i * 512]);
    } else {
      const short* g = mySrc + ((long)tt * 512 + half * 256 + lane) * 8;
      #pragma unroll
      for (int i = 0; i < 4; i++)
        GLOAD16(g + i * 512, &lds[buf][op][(half * 256 + i * 64) * 8]);
    }
  };

  const int wr = w >> 1, wc = w & 1;
  const int lrow = lane & 31, lk = lane >> 5;

  f32x16 acc[2][2] = {};

  auto compute = [&](int buf) {
    #pragma unroll
    for (int kh = 0; kh < 2; kh++) {
      const int kq = 2 * kh + lk;
      bf16x8 ah[2], bh[2];
      #pragma unroll
      for (int m = 0; m < 2; m++)
        ah[m] = *(const bf16x8*)&lds[buf][0][(kq * 128 + wr * 64 + m * 32 + lrow) * 8];
      #pragma unroll
      for (int n = 0; n < 2; n++)
        bh[n] = *(const bf16x8*)&lds[buf][(SPLIT == 2) ? 2 : 1][(kq * 128 + wc * 64 + n * 32 + lrow) * 8];
      if (SPLIT == 2) {
        bf16x8 al[2];
        #pragma unroll
        for (int m = 0; m < 2; m++)
          al[m] = *(const bf16x8*)&lds[buf][1][(kq * 128 + wr * 64 + m * 32 + lrow) * 8];
        #pragma unroll
        for (int m = 0; m < 2; m++)
          #pragma unroll
          for (int n = 0; n < 2; n++) {
            acc[m][n] = mfma_bf16(al[m], bh[n], acc[m][n]);
            acc[m][n] = mfma_bf16(ah[m], bh[n], acc[m][n]);
          }
      } else {
        #pragma unroll
        for (int m = 0; m < 2; m++)
          #pragma unroll
          for (int n = 0; n < 2; n++)
            acc[m][n] = mfma_bf16(ah[m], bh[n], acc[m][n]);
      }
    }
  };

  const int NT = (MODE == 5) ? 16 : 32;   // K-half for MODE 5
  stage(0, 0);
  for (int tt = 0; tt < NT - 1; ++tt) {
    stage((tt + 1) & 1, tt + 1);
    if (SPLIT == 2) asm volatile("s_waitcnt vmcnt(8)" ::: "memory");
    else            asm volatile("s_waitcnt vmcnt(4)" ::: "memory");
    __builtin_amdgcn_s_barrier();
    __builtin_amdgcn_sched_barrier(0);
    compute(tt & 1);
    __builtin_amdgcn_s_barrier();
  }
  asm volatile("s_waitcnt vmcnt(0)" ::: "memory");
  __builtin_amdgcn_s_barrier();
  __builtin_amdgcn_sched_barrier(0);
  compute((NT - 1) & 1);

  // ---------------- epilogue ----------------
  if (MODE == 5) {
    float* Cz = C + (long)(bz & 1) * (8L * 512 * 512) + (long)batch * (512L * 512);
    #pragma unroll
    for (int m = 0; m < 2; m++)
      #pragma unroll
      for (int r = 0; r < 16; r++) {
        const int row = rowBase + wr * 64 + m * 32 + (r & 3) + 8 * (r >> 2) + 4 * lk;
        #pragma unroll
        for (int n = 0; n < 2; n++)
          Cz[(long)row * 512 + colBase + wc * 64 + n * 32 + lrow] = acc[m][n][r];
      }
    return;
  }

  const float* bias = (bz == 1) ? b1 : (bz == 2) ? b2 : b0;
  float bcol[2];
  #pragma unroll
  for (int n = 0; n < 2; n++)
    bcol[n] = bias[colBase + wc * 64 + n * 32 + lrow];

  float* Cb = C + (long)bz * sC;
  short* Cdst = (MODE == 4 && bz) ? Clo : Chi;

  #pragma unroll
  for (int m = 0; m < 2; m++) {
    #pragma unroll
    for (int r = 0; r < 16; r++) {
      const int row = rowBase + wr * 64 + m * 32 + (r & 3) + 8 * (r >> 2) + 4 * lk;
      float g = 1.f;
      if (MODE == 2) g = gate_in[row];
      #pragma unroll
      for (int n = 0; n < 2; n++) {
        const int col = colBase + wc * 64 + n * 32 + lrow;
        const float val = acc[m][n][r] * g + bcol[n];
        if (MODE == 4) {
          Cdst[tiled_off(row, col)] = bf16_rn(val);
        } else {
          Cb[(long)row * D_ + col] = val;
        }
      }
    }
  }
}

// =====================================================================
// gate_finish: gate[row] = 1 + mean_m sigmoid((z0+z1)*SCALE/H).
// One wave per row; lane covers 8 cols of each K-half partial.
// =====================================================================
__global__ __launch_bounds__(256) void gate_finish(
    const float* __restrict__ zp, float* __restrict__ gate)
{
  const int t = threadIdx.x, w = t >> 6, lane = t & 63;
  const int row = blockIdx.x * 4 + w;    // 0..4095
  const float* z0 = zp + (long)row * 512;
  const float* z1 = zp + 8L * 512 * 512 + (long)row * 512;
  const float sc = 0.125f / 16.f;        // SCALE/H
  float4 a0 = *(const float4*)&z0[lane * 8];
  float4 a1 = *(const float4*)&z0[lane * 8 + 4];
  float4 b0 = *(const float4*)&z1[lane * 8];
  float4 b1 = *(const float4*)&z1[lane * 8 + 4];
  float s = 1.f / (1.f + __expf(-(a0.x + b0.x) * sc))
          + 1.f / (1.f + __expf(-(a0.y + b0.y) * sc))
          + 1.f / (1.f + __expf(-(a0.z + b0.z) * sc))
          + 1.f / (1.f + __expf(-(a0.w + b0.w) * sc))
          + 1.f / (1.f + __expf(-(a1.x + b1.x) * sc))
          + 1.f / (1.f + __expf(-(a1.y + b1.y) * sc))
          + 1.f / (1.f + __expf(-(a1.z + b1.z) * sc))
          + 1.f / (1.f + __expf(-(a1.w + b1.w) * sc));
  #pragma unroll
  for (int m = 1; m < 64; m <<= 1) s += __shfl_xor(s, m);
  if (lane == 0) gate[row] = 1.f + s * (1.f / 512.f);
}

// =====================================================================
// KV prep: K RMSNorm->bf16 swizzled [g][h][m][64]; V transposed bf16
// tiles [g][h][tile][d][32kv], chunk-swizzled. Both linear per 4KB tile
// for coalesced global_load_lds in attention.
// =====================================================================
__global__ __launch_bounds__(256) void kvprep(
    const float* __restrict__ kf, const float* __restrict__ vf,
    const float* __restrict__ knw, short* __restrict__ Knb,
    short* __restrict__ Vtb)
{
  const int tile = blockIdx.x, h = blockIdx.y, g = blockIdx.z;
  const int t = threadIdx.x;
  // ---- K ----
  const int skv = t >> 3, sg = t & 7;
  const int m  = tile * 32 + skv;
  const int bb = g * NI_ + (m >> 9), nn = m & (N_ - 1);
  const float* kp = kf + ((long)(bb * N_ + nn)) * D_ + h * HD_ + sg * 8;
  float k8[8];
  *(float4*)&k8[0] = *(const float4*)&kp[0];
  *(float4*)&k8[4] = *(const float4*)&kp[4];
  float ks2 = 0.f;
  #pragma unroll
  for (int j = 0; j < 8; j++) ks2 += k8[j] * k8[j];
  ks2 += __shfl_xor(ks2, 1);
  ks2 += __shfl_xor(ks2, 2);
  ks2 += __shfl_xor(ks2, 4);
  const float kr = rsqrtf(ks2 * (1.f / 64.f) + 1e-6f);
  bf16x8 kb;
  #pragma unroll
  for (int j = 0; j < 8; j++) kb[j] = bf16_rn(k8[j] * kr * knw[sg * 8 + j]);
  *(bf16x8*)&Knb[((long)(g * H_ + h) * KVLEN + m) * 64 + ((sg ^ (m & 7)) * 8)] = kb;
  // ---- V ----
  const int vkv = t & 31, vg = t >> 5;
  const int m2  = tile * 32 + vkv;
  const int bb2 = g * NI_ + (m2 >> 9), nn2 = m2 & (N_ - 1);
  const float* vp = vf + ((long)(bb2 * N_ + nn2)) * D_ + h * HD_ + vg * 8;
  float v8[8];
  *(float4*)&v8[0] = *(const float4*)&vp[0];
  *(float4*)&v8[4] = *(const float4*)&vp[4];
  const long vbase = ((long)(g * H_ + h) * 64 + tile) * 2048;
  #pragma unroll
  for (int e = 0; e < 8; e++) {
    const int d = vg * 8 + e;
    Vtb[vbase + d * 32 + (((vkv >> 3) ^ ((d >> 1) & 3)) * 8) + (vkv & 7)] = bf16_rn(v8[e]);
  }
}

// =====================================================================
// MFMA grouped flash attention v6 — round-12 structure restored
// (2-deep double-buffer, scalar l, VGPR<=64 -> ~33% occupancy; r13/r14
// showed pipeline depth/ones-MFMA lose to occupancy at this structure)
// + permlane32_swap P-half exchange (VGPR-neutral VALU cut).
// KV-SPLIT x2, XCD-swizzled. STATIC softmax max (-8): partials combine
// exactly (o=o0+o1, l=l0+l1).
// =====================================================================
__global__ __launch_bounds__(256) void attn3(
    const float* __restrict__ q, const short* __restrict__ Knb,
    const short* __restrict__ Vtb, const float* __restrict__ qnw,
    float* __restrict__ opart, float* __restrict__ lpart)
{
  int qb, h, bz;
  xcd_swizzle(qb, h, bz);
  const int b  = bz >> 1, s = bz & 1;
  const int g  = b >> 2;
  const int t  = threadIdx.x;
  const int w  = t >> 6;
  const int lane = t & 63;
  const int l31 = lane & 31, hi = lane >> 5;

  __shared__ short Kt[2][2048];
  __shared__ short Vt[2][2048];

  // ---- Q: load + RMSNorm + B-operand frags ----
  const int qrow = qb * 128 + w * 32 + l31;
  const float* qp = q + ((long)b * N_ + qrow) * D_ + h * HD_ + hi * 8;
  float qv[4][8];
  float ss = 0.f;
  #pragma unroll
  for (int c = 0; c < 4; c++) {
    *(float4*)&qv[c][0] = *(const float4*)&qp[c * 16];
    *(float4*)&qv[c][4] = *(const float4*)&qp[c * 16 + 4];
    #pragma unroll
    for (int j = 0; j < 8; j++) ss += qv[c][j] * qv[c][j];
  }
  ss += __shfl_xor(ss, 32);
  const float qr = rsqrtf(ss * (1.f / 64.f) + 1e-6f);
  bf16x8 qf[4];
  #pragma unroll
  for (int c = 0; c < 4; c++)
    #pragma unroll
    for (int j = 0; j < 8; j++)
      qf[c][j] = bf16_rn(qv[c][j] * qr * qnw[c * 16 + hi * 8 + j]);

  const short* Kg = Knb + (long)(g * H_ + h) * KVLEN * 64 + (long)s * 32 * 2048;
  const short* Vg = Vtb + (long)(g * H_ + h) * 64 * 2048 + (long)s * 32 * 2048;

  auto stage = [&](int buf, int i) {
    GLOAD16(Kg + (long)i * 2048 + t * 8, &Kt[buf][w * 512]);
    GLOAD16(Vg + (long)i * 2048 + t * 8, &Vt[buf][w * 512]);
  };

  f32x16 oacc[2] = {};
  float l = 0.f;

  stage(0, 0);
  for (int i = 0; i < 32; ++i) {
    const int buf = i & 1;
    if (i + 1 < 32) {
      stage(buf ^ 1, i + 1);
      asm volatile("s_waitcnt vmcnt(2)" ::: "memory");
    } else {
      asm volatile("s_waitcnt vmcnt(0)" ::: "memory");
    }
    __builtin_amdgcn_s_barrier();
    __builtin_amdgcn_sched_barrier(0);

    // ---- QK^T: scores[kv][q] ----
    f32x16 sc = {};
    #pragma unroll
    for (int c = 0; c < 4; c++) {
      bf16x8 kfr = *(const bf16x8*)&Kt[buf][l31 * 64 + (((2 * c + hi) * 8) ^ ((l31 & 7) << 3))];
      sc = mfma_bf16(kfr, qf[c], sc);
    }
    // ---- softmax, static max: p = exp2(s*0.125*log2e - 8*log2e) ----
    float p[16];
    #pragma unroll
    for (int r = 0; r < 16; r++) {
      p[r] = exp2f(fmaf(sc[r], 0.1803368801111244f, -11.541560327111961f));
      l += p[r];
    }
    // ---- pack P pairs to bf16 (cvt_pk), half-swap via permlane32 ----
    unsigned wd[8];
    #pragma unroll
    for (int i2 = 0; i2 < 8; i2++)
      asm("v_cvt_pk_bf16_f32 %0, %1, %2" : "=v"(wd[i2]) : "v"(p[2 * i2]), "v"(p[2 * i2 + 1]));
    u32x2 r0 = __builtin_amdgcn_permlane32_swap(wd[0], wd[2], false, false);
    u32x2 r1 = __builtin_amdgcn_permlane32_swap(wd[1], wd[3], false, false);
    u32x2 r2 = __builtin_amdgcn_permlane32_swap(wd[4], wd[6], false, false);
    u32x2 r3 = __builtin_amdgcn_permlane32_swap(wd[5], wd[7], false, false);
    int4 f0 = { (int)r0.x, (int)r1.x, (int)r0.y, (int)r1.y };
    int4 f1 = { (int)r2.x, (int)r3.x, (int)r2.y, (int)r3.y };
    // ---- PV ----
    #pragma unroll
    for (int n = 0; n < 2; n++) {
      const int d = n * 32 + l31;
      const int fd = (d >> 1) & 3;
      bf16x8 v0 = *(const bf16x8*)&Vt[buf][d * 32 + ((hi ^ fd) * 8)];
      bf16x8 v1 = *(const bf16x8*)&Vt[buf][d * 32 + (((2 | hi) ^ fd) * 8)];
      oacc[n] = mfma_bf16(__builtin_bit_cast(bf16x8, f0), v0, oacc[n]);
      oacc[n] = mfma_bf16(__builtin_bit_cast(bf16x8, f1), v1, oacc[n]);
    }
    __builtin_amdgcn_s_barrier();
  }

  // ---- epilogue: write PARTIAL o (no divide) + l ----
  l += __shfl_xor(l, 32);
  #pragma unroll
  for (int r = 0; r < 16; r++) {
    const int qg = qb * 128 + w * 32 + (r & 3) + 8 * (r >> 2) + 4 * hi;
    float* op = opart + ((long)s * BN_ + b * N_ + qg) * D_ + h * HD_ + l31;
    op[0]  = oacc[0][r];
    op[32] = oacc[1][r];
  }
  if (hi == 0)
    lpart[((long)s * BN_ + b * N_ + qb * 128 + w * 32 + l31) * H_ + h] = l;
}

// =====================================================================
// reduce_if — FUSED attn_reduce + instfeat (identical index space:
// block = row; instfeat's ifh moved to qbuf's free second half so the
// fusion can't race with opart reads).
//  part A: o = (o0+o1)/(l0+l1), split2 -> tiled bf16 hi/lo
//  part B: inst_feat[row] = mask[row]@embed -> tiled bf16 (hi)
// =====================================================================
__global__ __launch_bounds__(256) void reduce_if(
    const float* __restrict__ opart, const float* __restrict__ lpart,
    const float* __restrict__ mask, const float* __restrict__ emb,
    short* __restrict__ ohi, short* __restrict__ olo,
    short* __restrict__ ofh)
{
  const int row = blockIdx.x;
  const int col = threadIdx.x * 4;
  const int h   = col >> 6;
  // ---- A: attention partial combine ----
  const float l = lpart[(long)row * H_ + h] + lpart[((long)BN_ + row) * H_ + h];
  const float inv = 1.f / l;
  float4 a = *(const float4*)&opart[(long)row * D_ + col];
  float4 b = *(const float4*)&opart[((long)BN_ + row) * D_ + col];
  short hh[4], ll[4];
  split2((a.x + b.x) * inv, hh[0], ll[0]);
  split2((a.y + b.y) * inv, hh[1], ll[1]);
  split2((a.z + b.z) * inv, hh[2], ll[2]);
  split2((a.w + b.w) * inv, hh[3], ll[3]);
  const long o = tiled_off(row, col);
  *(s16x4*)&ohi[o] = *(s16x4*)hh;
  *(s16x4*)&olo[o] = *(s16x4*)ll;
  // ---- B: inst_feat ----
  const float* mk = mask + (long)row * NI_;
  float4 acc = {0.f, 0.f, 0.f, 0.f};
  #pragma unroll
  for (int i = 0; i < NI_; i++) {
    const float mm = mk[i];
    const float4 e = *(const float4*)&emb[(long)i * D_ + col];
    acc.x = fmaf(mm, e.x, acc.x);
    acc.y = fmaf(mm, e.y, acc.y);
    acc.z = fmaf(mm, e.z, acc.z);
    acc.w = fmaf(mm, e.w, acc.w);
  }
  short fh[4];
  fh[0] = bf16_rn(acc.x);  fh[1] = bf16_rn(acc.y);
  fh[2] = bf16_rn(acc.z);  fh[3] = bf16_rn(acc.w);
  *(s16x4*)&ofh[o] = *(s16x4*)fh;
}

// =====================================================================
extern "C" void kernel_launch(void* const* d_in, const int* in_sizes, int n_in,
                              void* d_out, int out_size, void* d_ws, size_t ws_size,
                              hipStream_t stream)
{
  const float* x    = (const float*)d_in[0];
  const float* mask = (const float*)d_in[1];
  const float* Wq   = (const float*)d_in[2];
  const float* bq   = (const float*)d_in[3];
  const float* Wk   = (const float*)d_in[4];
  const float* bk   = (const float*)d_in[5];
  const float* Wv   = (const float*)d_in[6];
  const float* bv   = (const float*)d_in[7];
  const float* Wo   = (const float*)d_in[8];
  const float* bo   = (const float*)d_in[9];
  const float* Wiq  = (const float*)d_in[10];
  const float* biq  = (const float*)d_in[11];
  const float* Wik  = (const float*)d_in[12];
  const float* bik  = (const float*)d_in[13];
  const float* emb  = (const float*)d_in[14];
  const float* qnw  = (const float*)d_in[15];
  const float* knw  = (const float*)d_in[16];
  float* out = (float*)d_out;

  // Workspace (within the round-9-proven footprint). Lifetime audit:
  //  qbuf: fp32 q (w:2 r:4) -> iqh (first half, w:8 r:9a) + ifh (second
  //        half, w:6 r:8)   [ifh moved here so reduce_if can't race opart]
  //  kbuf/vbuf: fp32 k,v (w:2 r:3) -> opart[2 planes] (w:4 r:6)
  //        -> ikh over vbuf (w:8 r:9a)
  //  ohi/olo: tiled split-bf16 o (w:6 r:8,10)
  //  xhi/xlo: x tiled bf16 (w:1(asplit) r:2) -> Knb/Vtb (w:3 r:4)
  //        -> zpart (w:9a r:9b)
  //  Wbig_hi: QKV weights (w:1 r:2) -> gate + lpart (w:9b/4 r:10/6)
  //  Wbig_lo: gate/final weights (w:1 r:8,10)
  float* ws = (float*)d_ws;
  const size_t SZ = (size_t)BN_ * D_;
  float* qbuf = ws;
  float* kbuf = qbuf + SZ;
  float* vbuf = kbuf + SZ;
  float* opart = kbuf;                  // [2][BN][D] fp32 attn partials
  short* ohi  = (short*)(vbuf + SZ);
  short* olo  = ohi + SZ;
  short* xhi  = (short*)(ws + 4 * SZ);
  short* xlo  = xhi + SZ;
  short* Knb  = xhi;                    // [2][16][2048][64] bf16
  short* Vtb  = xlo;                    // [2][16][64][64][32] bf16
  float* zpart = (float*)xhi;           // [2][8][512][512] fp32 (post-attn)
  short* Wbig_hi = (short*)(ws + 5 * SZ);
  short* Wbig_lo = Wbig_hi + (size_t)3 * D_ * D_;
  float* gate  = (float*)Wbig_hi;                       // [BN] (post-QKV)
  float* lpart = gate + BN_;                            // [2][BN][16]
  short* iqh = (short*)qbuf;
  short* ifh = (short*)qbuf + SZ;       // second half of qbuf
  short* ikh = (short*)vbuf;
  short* WiqH = Wbig_lo;
  short* WikH = Wbig_lo + (size_t)D_ * D_;
  short* WoH  = Wbig_lo + (size_t)2 * D_ * D_;

  const dim3 blk(256);

  // 1) ALL weight prep (one dispatch) + x -> tiled bf16
  wsplitAll<<<dim3(16, 16, 6), blk, 0, stream>>>(
      Wq, Wk, Wv, Wiq, Wik, Wo, Wbig_hi, Wbig_lo);
  asplit<<<(BN_ * D_ / 4) / 256, blk, 0, stream>>>(x, xhi);

  // 2) fused QKV projection (plain bf16, 1 MFMA/pair)
  mfgemm2<0, 0><<<dim3(8, 32, 3), blk, 0, stream>>>(
      xhi, nullptr, Wbig_hi, nullptr, bq, bk, bv,
      qbuf, nullptr, nullptr, 0, 8, (long)SZ, nullptr);

  // 3) KV prep (norm K, transpose V, bf16, swizzled; group-indexed)
  kvprep<<<dim3(KVLEN / 32, H_, 2), blk, 0, stream>>>(kbuf, vbuf, knw, Knb, Vtb);

  // 4) attention, KV-split x2 -> fp32 partials (over dead kbuf/vbuf)
  attn3<<<dim3(N_ / 128, H_, B_ * 2), blk, 0, stream>>>(
      qbuf, Knb, Vtb, qnw, opart, lpart);

  // 5) combine partials -> tiled split bf16 o; inst_feat fused in
  reduce_if<<<BN_, blk, 0, stream>>>(opart, lpart, mask, emb, ohi, olo, ifh);

  // 6) DUAL iq & ik GEMM (plain bf16), one dispatch
  mfgemm2<4, 0><<<dim3(8, 32, 2), blk, 0, stream>>>(
      ohi, ifh, WiqH, WikH, biq, bik, nullptr,
      nullptr, iqh, ikh, 0, 0, 0, nullptr);

  // 7) raw z = IQ@IK^T, K-split x2 (sigmoid deferred -> legal)
  mfgemm2<5, 0><<<dim3(4, 4, 16), blk, 0, stream>>>(
      iqh, nullptr, ikh, nullptr, nullptr, nullptr, nullptr,
      zpart, nullptr, nullptr, 4, 4, 0, nullptr);

  // 8) gate[row] = 1 + mean sigmoid((z0+z1)*sc)
  gate_finish<<<BN_ / 4, blk, 0, stream>>>(zpart, gate);

  // 9) final: gate[row]*(o@Wo) + bo -> d_out (SPLIT=2: o hi/lo x Wo hi)
  mfgemm2<2, 2><<<dim3(8, 32, 1), blk, 0, stream>>>(
      ohi, olo, WoH, nullptr, bo, nullptr, nullptr,
      out, nullptr, nullptr, 0, 0, 0, gate);
}